// Round 8
// baseline (473.533 us; speedup 1.0000x reference)
//
#include <hip/hip_runtime.h>
#include <math.h>

// ---------------------------------------------------------------------------
// 2-layer GAT encoder. CSR-by-dst gather aggregation (atomic-free).
// Round-8 changes:
//  * k4/k8 were capped at 50% occupancy by __launch_bounds__(256,4) while
//    latency-bound (39% measured). VGPR=64 and LDS 18.4KB allow 8 blocks/CU:
//    __launch_bounds__(256,8) doubles the resident wave pool.
//  * CSR slot assignment folded into k_deg (rank[e] = atomicAdd(deg[d],1));
//    k3_scatter is now atomic-free (cursor array deleted).
// ---------------------------------------------------------------------------

__device__ __forceinline__ float leaky02(float x) { return x > 0.f ? x : 0.2f * x; }
__device__ __forceinline__ float eluf(float x) { return x > 0.f ? x : expm1f(x); }
__device__ __forceinline__ float waveReduceSum(float v) {
#pragma unroll
    for (int off = 32; off; off >>= 1) v += __shfl_xor(v, off, 64);
    return v;
}
__device__ __forceinline__ unsigned short f2bf(float f) {
    unsigned u = __float_as_uint(f);
    u += 0x7FFFu + ((u >> 16) & 1u);
    return (unsigned short)(u >> 16);
}
__device__ __forceinline__ float bf2f(unsigned short h) {
    return __uint_as_float((unsigned)h << 16);
}

// ---------------- CSR construction ----------------

// deg histogram + per-edge rank (slot within its dst segment).
__global__ void k_deg(const int* __restrict__ dst, int* __restrict__ deg,
                      int* __restrict__ rank, int e_cnt) {
    int e = blockIdx.x * blockDim.x + threadIdx.x;
    if (e < e_cnt) rank[e] = atomicAdd(&deg[dst[e]], 1);
}

__global__ void k_scan_bsums(const int* __restrict__ deg, int* __restrict__ bsum, int n) {
    __shared__ int part[4];
    int i = blockIdx.x * 256 + threadIdx.x;
    int v = (i < n) ? deg[i] : 0;
    int w = v;
#pragma unroll
    for (int off = 32; off; off >>= 1) w += __shfl_xor(w, off, 64);
    if ((threadIdx.x & 63) == 0) part[threadIdx.x >> 6] = w;
    __syncthreads();
    if (threadIdx.x == 0) bsum[blockIdx.x] = part[0] + part[1] + part[2] + part[3];
}

__global__ void k_scan_bofs(const int* __restrict__ bsum, int* __restrict__ bofs, int nb) {
    __shared__ int s[256];
    int t = threadIdx.x;
    int v = (t < nb) ? bsum[t] : 0;
    s[t] = v;
    __syncthreads();
#pragma unroll
    for (int d = 1; d < 256; d <<= 1) {
        int add = (t >= d) ? s[t - d] : 0;
        __syncthreads();
        s[t] += add;
        __syncthreads();
    }
    bofs[t] = s[t] - v;  // exclusive
}

__global__ void k_scan_final(const int* __restrict__ deg, const int* __restrict__ bofs,
                             int* __restrict__ off, int n, int e_cnt) {
    __shared__ int s[256];
    int t = threadIdx.x;
    int i = blockIdx.x * 256 + t;
    int v = (i < n) ? deg[i] : 0;
    s[t] = v;
    __syncthreads();
#pragma unroll
    for (int d = 1; d < 256; d <<= 1) {
        int add = (t >= d) ? s[t - d] : 0;
        __syncthreads();
        s[t] += add;
        __syncthreads();
    }
    int o = bofs[blockIdx.x] + s[t] - v;
    if (i < n) off[i] = o;
    if (i == 0) off[n] = e_cnt;
}

// ---------------- Layer 1 ----------------

// K1: h1b (bf16, [N,256], channel c = 4*lane+j); a_src1/a_dst1 [N,4] fp32.
__global__ void k1_gemm1(const float* __restrict__ x, const float* __restrict__ W1,
                         const float* __restrict__ attS, const float* __restrict__ attD,
                         unsigned short* __restrict__ h1b, float* __restrict__ a_src1,
                         float* __restrict__ a_dst1, int n_nodes) {
    __shared__ float W1s[16 * 256];
    for (int i = threadIdx.x; i < 16 * 256; i += 256) W1s[i] = W1[i];
    __syncthreads();
    const int wave = threadIdx.x >> 6, lane = threadIdx.x & 63;
    const float4 aS = ((const float4*)attS)[lane];
    const float4 aD = ((const float4*)attD)[lane];
    for (int n = blockIdx.x * 4 + wave; n < n_nodes; n += gridDim.x * 4) {
        float xv = x[(size_t)n * 16 + (lane & 15)];
        float v0 = 0.f, v1 = 0.f, v2 = 0.f, v3 = 0.f;
#pragma unroll
        for (int k = 0; k < 16; ++k) {
            float xk = __shfl(xv, k, 64);
            const float* w = W1s + k * 256 + 4 * lane;
            v0 += xk * w[0]; v1 += xk * w[1]; v2 += xk * w[2]; v3 += xk * w[3];
        }
        ushort4 q;
        q.x = f2bf(v0); q.y = f2bf(v1); q.z = f2bf(v2); q.w = f2bf(v3);
        ((ushort4*)(h1b + (size_t)n * 256))[lane] = q;
        float ps = v0 * aS.x + v1 * aS.y + v2 * aS.z + v3 * aS.w;
        float pd = v0 * aD.x + v1 * aD.y + v2 * aD.z + v3 * aD.w;
#pragma unroll
        for (int off = 1; off < 16; off <<= 1) {
            ps += __shfl_xor(ps, off, 64);
            pd += __shfl_xor(pd, off, 64);
        }
        if ((lane & 15) == 0) {
            a_src1[n * 4 + (lane >> 4)] = ps;
            a_dst1[n * 4 + (lane >> 4)] = pd;
        }
    }
}

// K3: per-edge exp (4 heads) + atomic-free scatter into CSR slot off[d]+rank[e].
__global__ void k3_scatter(const int* __restrict__ src, const int* __restrict__ dst,
                           const float* __restrict__ a_src1, const float* __restrict__ a_dst1,
                           const int* __restrict__ off, const int* __restrict__ rank,
                           int* __restrict__ csr_src, float4* __restrict__ csr_ex, int e_cnt) {
    int e = blockIdx.x * blockDim.x + threadIdx.x;
    if (e >= e_cnt) return;
    int s = src[e], d = dst[e];
    float4 as = *(const float4*)(a_src1 + (size_t)s * 4);
    float4 ad = *(const float4*)(a_dst1 + (size_t)d * 4);
    float4 ex;
    ex.x = expf(leaky02(as.x + ad.x));
    ex.y = expf(leaky02(as.y + ad.y));
    ex.z = expf(leaky02(as.z + ad.z));
    ex.w = expf(leaky02(as.w + ad.w));
    int pos = off[d] + rank[e];
    csr_src[pos] = s;
    csr_ex[pos] = ex;
}

// K4: fused layer-1 softmax-gather + head-mean + b1 + ELU + GEMM2 + L2 scores.
// Wave per dst node; lane owns channels 4l..4l+3 (head = lane>>4).
__global__ void __launch_bounds__(256, 8)
k4_agg1(const int* __restrict__ off, const int* __restrict__ csr_src,
        const float4* __restrict__ csr_ex, const unsigned short* __restrict__ h1b,
        const float* __restrict__ a_src1, const float* __restrict__ a_dst1,
        const float* __restrict__ b1, const float* __restrict__ W2,
        const float* __restrict__ attS2, const float* __restrict__ attD2,
        unsigned short* __restrict__ h2b, float* __restrict__ a_src2,
        float* __restrict__ a_dst2, int n_nodes) {
    __shared__ float W2s[64 * 64];
    __shared__ float as2s[64], ad2s[64];
    __shared__ int   sS[4][16];   // per-wave chunk src ids
    __shared__ float eS[4][64];   // per-wave chunk exp4, [edge*4 + head]
    for (int i = threadIdx.x; i < 64 * 64; i += 256) W2s[i] = W2[i];
    if (threadIdx.x < 64) {
        as2s[threadIdx.x] = attS2[threadIdx.x];
        ad2s[threadIdx.x] = attD2[threadIdx.x];
    }
    __syncthreads();
    const int wave = threadIdx.x >> 6, lane = threadIdx.x & 63;
    const int head = lane >> 4;
    const float4 b1v = ((const float4*)b1)[lane & 15];
    for (int n = blockIdx.x * 4 + wave; n < n_nodes; n += gridDim.x * 4) {
        int beg = off[n], end = off[n + 1];
        float4 as = *(const float4*)(a_src1 + (size_t)n * 4);
        float4 ad = *(const float4*)(a_dst1 + (size_t)n * 4);
        float adh = head == 0 ? ad.x : head == 1 ? ad.y : head == 2 ? ad.z : ad.w;
        float ash = head == 0 ? as.x : head == 1 ? as.y : head == 2 ? as.z : as.w;
        float se = expf(leaky02(ash + adh));
        ushort4 qs = ((const ushort4*)(h1b + (size_t)n * 256))[lane];
        float den = se;
        float a0 = se * bf2f(qs.x), a1 = se * bf2f(qs.y);
        float a2 = se * bf2f(qs.z), a3 = se * bf2f(qs.w);
        for (int base = beg; base < end; base += 16) {
            int m = end - base; if (m > 16) m = 16;
            if (lane < m) {
                sS[wave][lane] = csr_src[base + lane];
                ((float4*)eS[wave])[lane] = csr_ex[base + lane];
            }
            int i = 0;
            for (; i + 4 <= m; i += 4) {
                int s0 = sS[wave][i];
                int s1 = sS[wave][i + 1];
                int s2 = sS[wave][i + 2];
                int s3 = sS[wave][i + 3];
                ushort4 q0 = ((const ushort4*)(h1b + (size_t)s0 * 256))[lane];
                ushort4 q1 = ((const ushort4*)(h1b + (size_t)s1 * 256))[lane];
                ushort4 q2 = ((const ushort4*)(h1b + (size_t)s2 * 256))[lane];
                ushort4 q3 = ((const ushort4*)(h1b + (size_t)s3 * 256))[lane];
                float e0 = eS[wave][4 * i + head];
                float e1 = eS[wave][4 * (i + 1) + head];
                float e2 = eS[wave][4 * (i + 2) + head];
                float e3 = eS[wave][4 * (i + 3) + head];
                a0 += e0 * bf2f(q0.x) + e1 * bf2f(q1.x) + e2 * bf2f(q2.x) + e3 * bf2f(q3.x);
                a1 += e0 * bf2f(q0.y) + e1 * bf2f(q1.y) + e2 * bf2f(q2.y) + e3 * bf2f(q3.y);
                a2 += e0 * bf2f(q0.z) + e1 * bf2f(q1.z) + e2 * bf2f(q2.z) + e3 * bf2f(q3.z);
                a3 += e0 * bf2f(q0.w) + e1 * bf2f(q1.w) + e2 * bf2f(q2.w) + e3 * bf2f(q3.w);
                den += e0 + e1 + e2 + e3;
            }
            for (; i < m; ++i) {
                int s = sS[wave][i];
                float eh = eS[wave][4 * i + head];
                ushort4 q = ((const ushort4*)(h1b + (size_t)s * 256))[lane];
                a0 += eh * bf2f(q.x); a1 += eh * bf2f(q.y);
                a2 += eh * bf2f(q.z); a3 += eh * bf2f(q.w);
                den += eh;
            }
        }
        float inv = 1.f / (den + 1e-16f);
        float t0 = a0 * inv, t1 = a1 * inv, t2 = a2 * inv, t3 = a3 * inv;
        t0 += __shfl_xor(t0, 16, 64); t0 += __shfl_xor(t0, 32, 64);
        t1 += __shfl_xor(t1, 16, 64); t1 += __shfl_xor(t1, 32, 64);
        t2 += __shfl_xor(t2, 16, 64); t2 += __shfl_xor(t2, 32, 64);
        t3 += __shfl_xor(t3, 16, 64); t3 += __shfl_xor(t3, 32, 64);
        float x20 = eluf(0.25f * t0 + b1v.x);
        float x21 = eluf(0.25f * t1 + b1v.y);
        float x22 = eluf(0.25f * t2 + b1v.z);
        float x23 = eluf(0.25f * t3 + b1v.w);
        float g = 0.f;
#pragma unroll
        for (int qq = 0; qq < 16; ++qq) {
            float xk0 = __shfl(x20, qq, 64);
            float xk1 = __shfl(x21, qq, 64);
            float xk2 = __shfl(x22, qq, 64);
            float xk3 = __shfl(x23, qq, 64);
            const float* w = W2s + (4 * qq) * 64 + lane;
            g += xk0 * w[0] + xk1 * w[64] + xk2 * w[128] + xk3 * w[192];
        }
        h2b[(size_t)n * 64 + lane] = f2bf(g);
        float ps = waveReduceSum(g * as2s[lane]);
        float pd = waveReduceSum(g * ad2s[lane]);
        if (lane == 0) {
            a_src2[n] = ps;
            a_dst2[n] = pd;
        }
    }
}

// ---------------- Layer 2 ----------------

// K8: fused layer-2 softmax-gather + self message + b2 + ELU -> out.
__global__ void __launch_bounds__(256, 8)
k8_agg2(const int* __restrict__ off, const int* __restrict__ csr_src,
        const unsigned short* __restrict__ h2b,
        const float* __restrict__ a_src2, const float* __restrict__ a_dst2,
        const float* __restrict__ b2, float* __restrict__ out, int n_nodes) {
    __shared__ float b2s[64];
    __shared__ int   sS[4][64];
    __shared__ float eS[4][64];
    if (threadIdx.x < 64) b2s[threadIdx.x] = b2[threadIdx.x];
    __syncthreads();
    const int wave = threadIdx.x >> 6, lane = threadIdx.x & 63;
    for (int n = blockIdx.x * 4 + wave; n < n_nodes; n += gridDim.x * 4) {
        int beg = off[n], end = off[n + 1];
        float adn = a_dst2[n];
        float se = expf(leaky02(a_src2[n] + adn));
        float den = se;
        float acc = se * bf2f(h2b[(size_t)n * 64 + lane]);
        for (int base = beg; base < end; base += 64) {
            int m = end - base; if (m > 64) m = 64;
            if (lane < m) {
                int s = csr_src[base + lane];
                sS[wave][lane] = s;
                eS[wave][lane] = expf(leaky02(a_src2[s] + adn));
            }
            int i = 0;
            for (; i + 4 <= m; i += 4) {
                int s0 = sS[wave][i];
                int s1 = sS[wave][i + 1];
                int s2 = sS[wave][i + 2];
                int s3 = sS[wave][i + 3];
                float q0 = bf2f(h2b[(size_t)s0 * 64 + lane]);
                float q1 = bf2f(h2b[(size_t)s1 * 64 + lane]);
                float q2 = bf2f(h2b[(size_t)s2 * 64 + lane]);
                float q3 = bf2f(h2b[(size_t)s3 * 64 + lane]);
                float e0 = eS[wave][i];
                float e1 = eS[wave][i + 1];
                float e2 = eS[wave][i + 2];
                float e3 = eS[wave][i + 3];
                acc += e0 * q0 + e1 * q1 + e2 * q2 + e3 * q3;
                den += e0 + e1 + e2 + e3;
            }
            for (; i < m; ++i) {
                int s = sS[wave][i];
                float eh = eS[wave][i];
                acc += eh * bf2f(h2b[(size_t)s * 64 + lane]);
                den += eh;
            }
        }
        out[(size_t)n * 64 + lane] = eluf(acc / (den + 1e-16f) + b2s[lane]);
    }
}

extern "C" void kernel_launch(void* const* d_in, const int* in_sizes, int n_in,
                              void* d_out, int out_size, void* d_ws, size_t ws_size,
                              hipStream_t stream) {
    const float* x   = (const float*)d_in[0];
    const int*   ei  = (const int*)d_in[1];
    const float* W1  = (const float*)d_in[2];
    const float* as1 = (const float*)d_in[3];
    const float* ad1 = (const float*)d_in[4];
    const float* b1  = (const float*)d_in[5];
    const float* W2  = (const float*)d_in[6];
    const float* as2 = (const float*)d_in[7];
    const float* ad2 = (const float*)d_in[8];
    const float* b2  = (const float*)d_in[9];
    float* out = (float*)d_out;

    const int n = in_sizes[0] / 16;   // 50000
    const int e = in_sizes[1] / 2;    // 400000
    const int* src = ei;
    const int* dst = ei + e;
    const int nb = (n + 255) / 256;

    float* ws = (float*)d_ws;
    size_t o = 0;
    unsigned short* h1b = (unsigned short*)(ws + o); o += (size_t)n * 128;  // [N,256] bf16
    float4* csr_ex  = (float4*)(ws + o); o += (size_t)e * 4;
    float*  a_src1  = ws + o; o += (size_t)n * 4;
    float*  a_dst1  = ws + o; o += (size_t)n * 4;
    unsigned short* h2b = (unsigned short*)(ws + o); o += (size_t)n * 32;   // [N,64] bf16
    float*  a_src2  = ws + o; o += (size_t)n;
    float*  a_dst2  = ws + o; o += (size_t)n;
    int*    csr_src = (int*)(ws + o); o += (size_t)e;
    int*    rank    = (int*)(ws + o); o += (size_t)e;
    int*    deg     = (int*)(ws + o); o += (size_t)n;
    int*    off     = (int*)(ws + o); o += (size_t)(n + 4);
    int*    bsum    = (int*)(ws + o); o += 256;
    int*    bofs    = (int*)(ws + o); o += 256;

    hipMemsetAsync(deg, 0, (size_t)n * sizeof(int), stream);

    // CSR build (structure only)
    k_deg<<<(e + 255) / 256, 256, 0, stream>>>(dst, deg, rank, e);
    k_scan_bsums<<<nb, 256, 0, stream>>>(deg, bsum, n);
    k_scan_bofs<<<1, 256, 0, stream>>>(bsum, bofs, nb);
    k_scan_final<<<nb, 256, 0, stream>>>(deg, bofs, off, n, e);

    // Layer 1
    k1_gemm1<<<(n + 3) / 4, 256, 0, stream>>>(x, W1, as1, ad1, h1b, a_src1, a_dst1, n);
    k3_scatter<<<(e + 255) / 256, 256, 0, stream>>>(src, dst, a_src1, a_dst1, off, rank,
                                                    csr_src, csr_ex, e);
    k4_agg1<<<(n + 3) / 4, 256, 0, stream>>>(off, csr_src, csr_ex, h1b, a_src1, a_dst1,
                                             b1, W2, as2, ad2, h2b, a_src2, a_dst2, n);

    // Layer 2
    k8_agg2<<<(n + 3) / 4, 256, 0, stream>>>(off, csr_src, h2b, a_src2, a_dst2, b2, out, n);
}

// Round 9
// 313.639 us; speedup vs baseline: 1.5098x; 1.5098x over previous
//
#include <hip/hip_runtime.h>
#include <math.h>

// ---------------------------------------------------------------------------
// 2-layer GAT encoder. CSR-by-dst gather aggregation (atomic-free).
// Round-9 changes:
//  * Revert round-8's __launch_bounds__(256,8): it forced VGPR=32 and caused
//    true scratch spilling (WRITE 830 MB, dur 305us). Back to (256,4)
//    where VGPR=64 and k4's 32MB WRITE == producer dirty-line evictions
//    (no spill).
//  * MLP x2: inner gather loops unrolled x8 (was x4) in k4 and k8 —
//    8 independent row gathers in flight per wave against the L3-resident
//    h1b/h2b working sets (latency-bound regime).
//  * Keep round-8's atomic-free k3 (rank computed in k_deg).
// ---------------------------------------------------------------------------

__device__ __forceinline__ float leaky02(float x) { return x > 0.f ? x : 0.2f * x; }
__device__ __forceinline__ float eluf(float x) { return x > 0.f ? x : expm1f(x); }
__device__ __forceinline__ float waveReduceSum(float v) {
#pragma unroll
    for (int off = 32; off; off >>= 1) v += __shfl_xor(v, off, 64);
    return v;
}
__device__ __forceinline__ unsigned short f2bf(float f) {
    unsigned u = __float_as_uint(f);
    u += 0x7FFFu + ((u >> 16) & 1u);
    return (unsigned short)(u >> 16);
}
__device__ __forceinline__ float bf2f(unsigned short h) {
    return __uint_as_float((unsigned)h << 16);
}

// ---------------- CSR construction ----------------

// deg histogram + per-edge rank (slot within its dst segment).
__global__ void k_deg(const int* __restrict__ dst, int* __restrict__ deg,
                      int* __restrict__ rank, int e_cnt) {
    int e = blockIdx.x * blockDim.x + threadIdx.x;
    if (e < e_cnt) rank[e] = atomicAdd(&deg[dst[e]], 1);
}

__global__ void k_scan_bsums(const int* __restrict__ deg, int* __restrict__ bsum, int n) {
    __shared__ int part[4];
    int i = blockIdx.x * 256 + threadIdx.x;
    int v = (i < n) ? deg[i] : 0;
    int w = v;
#pragma unroll
    for (int off = 32; off; off >>= 1) w += __shfl_xor(w, off, 64);
    if ((threadIdx.x & 63) == 0) part[threadIdx.x >> 6] = w;
    __syncthreads();
    if (threadIdx.x == 0) bsum[blockIdx.x] = part[0] + part[1] + part[2] + part[3];
}

__global__ void k_scan_bofs(const int* __restrict__ bsum, int* __restrict__ bofs, int nb) {
    __shared__ int s[256];
    int t = threadIdx.x;
    int v = (t < nb) ? bsum[t] : 0;
    s[t] = v;
    __syncthreads();
#pragma unroll
    for (int d = 1; d < 256; d <<= 1) {
        int add = (t >= d) ? s[t - d] : 0;
        __syncthreads();
        s[t] += add;
        __syncthreads();
    }
    bofs[t] = s[t] - v;  // exclusive
}

__global__ void k_scan_final(const int* __restrict__ deg, const int* __restrict__ bofs,
                             int* __restrict__ off, int n, int e_cnt) {
    __shared__ int s[256];
    int t = threadIdx.x;
    int i = blockIdx.x * 256 + t;
    int v = (i < n) ? deg[i] : 0;
    s[t] = v;
    __syncthreads();
#pragma unroll
    for (int d = 1; d < 256; d <<= 1) {
        int add = (t >= d) ? s[t - d] : 0;
        __syncthreads();
        s[t] += add;
        __syncthreads();
    }
    int o = bofs[blockIdx.x] + s[t] - v;
    if (i < n) off[i] = o;
    if (i == 0) off[n] = e_cnt;
}

// ---------------- Layer 1 ----------------

// K1: h1b (bf16, [N,256], channel c = 4*lane+j); a_src1/a_dst1 [N,4] fp32.
__global__ void k1_gemm1(const float* __restrict__ x, const float* __restrict__ W1,
                         const float* __restrict__ attS, const float* __restrict__ attD,
                         unsigned short* __restrict__ h1b, float* __restrict__ a_src1,
                         float* __restrict__ a_dst1, int n_nodes) {
    __shared__ float W1s[16 * 256];
    for (int i = threadIdx.x; i < 16 * 256; i += 256) W1s[i] = W1[i];
    __syncthreads();
    const int wave = threadIdx.x >> 6, lane = threadIdx.x & 63;
    const float4 aS = ((const float4*)attS)[lane];
    const float4 aD = ((const float4*)attD)[lane];
    for (int n = blockIdx.x * 4 + wave; n < n_nodes; n += gridDim.x * 4) {
        float xv = x[(size_t)n * 16 + (lane & 15)];
        float v0 = 0.f, v1 = 0.f, v2 = 0.f, v3 = 0.f;
#pragma unroll
        for (int k = 0; k < 16; ++k) {
            float xk = __shfl(xv, k, 64);
            const float* w = W1s + k * 256 + 4 * lane;
            v0 += xk * w[0]; v1 += xk * w[1]; v2 += xk * w[2]; v3 += xk * w[3];
        }
        ushort4 q;
        q.x = f2bf(v0); q.y = f2bf(v1); q.z = f2bf(v2); q.w = f2bf(v3);
        ((ushort4*)(h1b + (size_t)n * 256))[lane] = q;
        float ps = v0 * aS.x + v1 * aS.y + v2 * aS.z + v3 * aS.w;
        float pd = v0 * aD.x + v1 * aD.y + v2 * aD.z + v3 * aD.w;
#pragma unroll
        for (int off = 1; off < 16; off <<= 1) {
            ps += __shfl_xor(ps, off, 64);
            pd += __shfl_xor(pd, off, 64);
        }
        if ((lane & 15) == 0) {
            a_src1[n * 4 + (lane >> 4)] = ps;
            a_dst1[n * 4 + (lane >> 4)] = pd;
        }
    }
}

// K3: per-edge exp (4 heads) + atomic-free scatter into CSR slot off[d]+rank[e].
__global__ void k3_scatter(const int* __restrict__ src, const int* __restrict__ dst,
                           const float* __restrict__ a_src1, const float* __restrict__ a_dst1,
                           const int* __restrict__ off, const int* __restrict__ rank,
                           int* __restrict__ csr_src, float4* __restrict__ csr_ex, int e_cnt) {
    int e = blockIdx.x * blockDim.x + threadIdx.x;
    if (e >= e_cnt) return;
    int s = src[e], d = dst[e];
    float4 as = *(const float4*)(a_src1 + (size_t)s * 4);
    float4 ad = *(const float4*)(a_dst1 + (size_t)d * 4);
    float4 ex;
    ex.x = expf(leaky02(as.x + ad.x));
    ex.y = expf(leaky02(as.y + ad.y));
    ex.z = expf(leaky02(as.z + ad.z));
    ex.w = expf(leaky02(as.w + ad.w));
    int pos = off[d] + rank[e];
    csr_src[pos] = s;
    csr_ex[pos] = ex;
}

// K4: fused layer-1 softmax-gather + head-mean + b1 + ELU + GEMM2 + L2 scores.
// Wave per dst node; lane owns channels 4l..4l+3 (head = lane>>4).
// Chunked (16 edges): coalesced LDS preload; inner loop unrolled x8.
__global__ void __launch_bounds__(256, 4)
k4_agg1(const int* __restrict__ off, const int* __restrict__ csr_src,
        const float4* __restrict__ csr_ex, const unsigned short* __restrict__ h1b,
        const float* __restrict__ a_src1, const float* __restrict__ a_dst1,
        const float* __restrict__ b1, const float* __restrict__ W2,
        const float* __restrict__ attS2, const float* __restrict__ attD2,
        unsigned short* __restrict__ h2b, float* __restrict__ a_src2,
        float* __restrict__ a_dst2, int n_nodes) {
    __shared__ float W2s[64 * 64];
    __shared__ float as2s[64], ad2s[64];
    __shared__ int   sS[4][16];   // per-wave chunk src ids
    __shared__ float eS[4][64];   // per-wave chunk exp4, [edge*4 + head]
    for (int i = threadIdx.x; i < 64 * 64; i += 256) W2s[i] = W2[i];
    if (threadIdx.x < 64) {
        as2s[threadIdx.x] = attS2[threadIdx.x];
        ad2s[threadIdx.x] = attD2[threadIdx.x];
    }
    __syncthreads();
    const int wave = threadIdx.x >> 6, lane = threadIdx.x & 63;
    const int head = lane >> 4;
    const float4 b1v = ((const float4*)b1)[lane & 15];
    for (int n = blockIdx.x * 4 + wave; n < n_nodes; n += gridDim.x * 4) {
        int beg = off[n], end = off[n + 1];
        float4 as = *(const float4*)(a_src1 + (size_t)n * 4);
        float4 ad = *(const float4*)(a_dst1 + (size_t)n * 4);
        float adh = head == 0 ? ad.x : head == 1 ? ad.y : head == 2 ? ad.z : ad.w;
        float ash = head == 0 ? as.x : head == 1 ? as.y : head == 2 ? as.z : as.w;
        float se = expf(leaky02(ash + adh));
        ushort4 qs = ((const ushort4*)(h1b + (size_t)n * 256))[lane];
        float den = se;
        float a0 = se * bf2f(qs.x), a1 = se * bf2f(qs.y);
        float a2 = se * bf2f(qs.z), a3 = se * bf2f(qs.w);
        for (int base = beg; base < end; base += 16) {
            int m = end - base; if (m > 16) m = 16;
            if (lane < m) {
                sS[wave][lane] = csr_src[base + lane];
                ((float4*)eS[wave])[lane] = csr_ex[base + lane];
            }
            int i = 0;
            for (; i + 8 <= m; i += 8) {
                int s0 = sS[wave][i];
                int s1 = sS[wave][i + 1];
                int s2 = sS[wave][i + 2];
                int s3 = sS[wave][i + 3];
                int s4 = sS[wave][i + 4];
                int s5 = sS[wave][i + 5];
                int s6 = sS[wave][i + 6];
                int s7 = sS[wave][i + 7];
                ushort4 q0 = ((const ushort4*)(h1b + (size_t)s0 * 256))[lane];
                ushort4 q1 = ((const ushort4*)(h1b + (size_t)s1 * 256))[lane];
                ushort4 q2 = ((const ushort4*)(h1b + (size_t)s2 * 256))[lane];
                ushort4 q3 = ((const ushort4*)(h1b + (size_t)s3 * 256))[lane];
                ushort4 q4 = ((const ushort4*)(h1b + (size_t)s4 * 256))[lane];
                ushort4 q5 = ((const ushort4*)(h1b + (size_t)s5 * 256))[lane];
                ushort4 q6 = ((const ushort4*)(h1b + (size_t)s6 * 256))[lane];
                ushort4 q7 = ((const ushort4*)(h1b + (size_t)s7 * 256))[lane];
                float e0 = eS[wave][4 * i + head];
                float e1 = eS[wave][4 * (i + 1) + head];
                float e2 = eS[wave][4 * (i + 2) + head];
                float e3 = eS[wave][4 * (i + 3) + head];
                float e4 = eS[wave][4 * (i + 4) + head];
                float e5 = eS[wave][4 * (i + 5) + head];
                float e6 = eS[wave][4 * (i + 6) + head];
                float e7 = eS[wave][4 * (i + 7) + head];
                a0 += e0 * bf2f(q0.x) + e1 * bf2f(q1.x) + e2 * bf2f(q2.x) + e3 * bf2f(q3.x)
                    + e4 * bf2f(q4.x) + e5 * bf2f(q5.x) + e6 * bf2f(q6.x) + e7 * bf2f(q7.x);
                a1 += e0 * bf2f(q0.y) + e1 * bf2f(q1.y) + e2 * bf2f(q2.y) + e3 * bf2f(q3.y)
                    + e4 * bf2f(q4.y) + e5 * bf2f(q5.y) + e6 * bf2f(q6.y) + e7 * bf2f(q7.y);
                a2 += e0 * bf2f(q0.z) + e1 * bf2f(q1.z) + e2 * bf2f(q2.z) + e3 * bf2f(q3.z)
                    + e4 * bf2f(q4.z) + e5 * bf2f(q5.z) + e6 * bf2f(q6.z) + e7 * bf2f(q7.z);
                a3 += e0 * bf2f(q0.w) + e1 * bf2f(q1.w) + e2 * bf2f(q2.w) + e3 * bf2f(q3.w)
                    + e4 * bf2f(q4.w) + e5 * bf2f(q5.w) + e6 * bf2f(q6.w) + e7 * bf2f(q7.w);
                den += e0 + e1 + e2 + e3 + e4 + e5 + e6 + e7;
            }
            for (; i + 4 <= m; i += 4) {
                int s0 = sS[wave][i];
                int s1 = sS[wave][i + 1];
                int s2 = sS[wave][i + 2];
                int s3 = sS[wave][i + 3];
                ushort4 q0 = ((const ushort4*)(h1b + (size_t)s0 * 256))[lane];
                ushort4 q1 = ((const ushort4*)(h1b + (size_t)s1 * 256))[lane];
                ushort4 q2 = ((const ushort4*)(h1b + (size_t)s2 * 256))[lane];
                ushort4 q3 = ((const ushort4*)(h1b + (size_t)s3 * 256))[lane];
                float e0 = eS[wave][4 * i + head];
                float e1 = eS[wave][4 * (i + 1) + head];
                float e2 = eS[wave][4 * (i + 2) + head];
                float e3 = eS[wave][4 * (i + 3) + head];
                a0 += e0 * bf2f(q0.x) + e1 * bf2f(q1.x) + e2 * bf2f(q2.x) + e3 * bf2f(q3.x);
                a1 += e0 * bf2f(q0.y) + e1 * bf2f(q1.y) + e2 * bf2f(q2.y) + e3 * bf2f(q3.y);
                a2 += e0 * bf2f(q0.z) + e1 * bf2f(q1.z) + e2 * bf2f(q2.z) + e3 * bf2f(q3.z);
                a3 += e0 * bf2f(q0.w) + e1 * bf2f(q1.w) + e2 * bf2f(q2.w) + e3 * bf2f(q3.w);
                den += e0 + e1 + e2 + e3;
            }
            for (; i < m; ++i) {
                int s = sS[wave][i];
                float eh = eS[wave][4 * i + head];
                ushort4 q = ((const ushort4*)(h1b + (size_t)s * 256))[lane];
                a0 += eh * bf2f(q.x); a1 += eh * bf2f(q.y);
                a2 += eh * bf2f(q.z); a3 += eh * bf2f(q.w);
                den += eh;
            }
        }
        float inv = 1.f / (den + 1e-16f);
        float t0 = a0 * inv, t1 = a1 * inv, t2 = a2 * inv, t3 = a3 * inv;
        t0 += __shfl_xor(t0, 16, 64); t0 += __shfl_xor(t0, 32, 64);
        t1 += __shfl_xor(t1, 16, 64); t1 += __shfl_xor(t1, 32, 64);
        t2 += __shfl_xor(t2, 16, 64); t2 += __shfl_xor(t2, 32, 64);
        t3 += __shfl_xor(t3, 16, 64); t3 += __shfl_xor(t3, 32, 64);
        float x20 = eluf(0.25f * t0 + b1v.x);
        float x21 = eluf(0.25f * t1 + b1v.y);
        float x22 = eluf(0.25f * t2 + b1v.z);
        float x23 = eluf(0.25f * t3 + b1v.w);
        float g = 0.f;
#pragma unroll
        for (int qq = 0; qq < 16; ++qq) {
            float xk0 = __shfl(x20, qq, 64);
            float xk1 = __shfl(x21, qq, 64);
            float xk2 = __shfl(x22, qq, 64);
            float xk3 = __shfl(x23, qq, 64);
            const float* w = W2s + (4 * qq) * 64 + lane;
            g += xk0 * w[0] + xk1 * w[64] + xk2 * w[128] + xk3 * w[192];
        }
        h2b[(size_t)n * 64 + lane] = f2bf(g);
        float ps = waveReduceSum(g * as2s[lane]);
        float pd = waveReduceSum(g * ad2s[lane]);
        if (lane == 0) {
            a_src2[n] = ps;
            a_dst2[n] = pd;
        }
    }
}

// ---------------- Layer 2 ----------------

// K8: fused layer-2 softmax-gather + self message + b2 + ELU -> out.
// Chunked (64 edges): coalesced LDS preload; inner loop unrolled x8.
__global__ void __launch_bounds__(256, 4)
k8_agg2(const int* __restrict__ off, const int* __restrict__ csr_src,
        const unsigned short* __restrict__ h2b,
        const float* __restrict__ a_src2, const float* __restrict__ a_dst2,
        const float* __restrict__ b2, float* __restrict__ out, int n_nodes) {
    __shared__ float b2s[64];
    __shared__ int   sS[4][64];
    __shared__ float eS[4][64];
    if (threadIdx.x < 64) b2s[threadIdx.x] = b2[threadIdx.x];
    __syncthreads();
    const int wave = threadIdx.x >> 6, lane = threadIdx.x & 63;
    for (int n = blockIdx.x * 4 + wave; n < n_nodes; n += gridDim.x * 4) {
        int beg = off[n], end = off[n + 1];
        float adn = a_dst2[n];
        float se = expf(leaky02(a_src2[n] + adn));
        float den = se;
        float acc = se * bf2f(h2b[(size_t)n * 64 + lane]);
        for (int base = beg; base < end; base += 64) {
            int m = end - base; if (m > 64) m = 64;
            if (lane < m) {
                int s = csr_src[base + lane];
                sS[wave][lane] = s;
                eS[wave][lane] = expf(leaky02(a_src2[s] + adn));
            }
            int i = 0;
            for (; i + 8 <= m; i += 8) {
                int s0 = sS[wave][i];
                int s1 = sS[wave][i + 1];
                int s2 = sS[wave][i + 2];
                int s3 = sS[wave][i + 3];
                int s4 = sS[wave][i + 4];
                int s5 = sS[wave][i + 5];
                int s6 = sS[wave][i + 6];
                int s7 = sS[wave][i + 7];
                float q0 = bf2f(h2b[(size_t)s0 * 64 + lane]);
                float q1 = bf2f(h2b[(size_t)s1 * 64 + lane]);
                float q2 = bf2f(h2b[(size_t)s2 * 64 + lane]);
                float q3 = bf2f(h2b[(size_t)s3 * 64 + lane]);
                float q4 = bf2f(h2b[(size_t)s4 * 64 + lane]);
                float q5 = bf2f(h2b[(size_t)s5 * 64 + lane]);
                float q6 = bf2f(h2b[(size_t)s6 * 64 + lane]);
                float q7 = bf2f(h2b[(size_t)s7 * 64 + lane]);
                float e0 = eS[wave][i];
                float e1 = eS[wave][i + 1];
                float e2 = eS[wave][i + 2];
                float e3 = eS[wave][i + 3];
                float e4 = eS[wave][i + 4];
                float e5 = eS[wave][i + 5];
                float e6 = eS[wave][i + 6];
                float e7 = eS[wave][i + 7];
                acc += e0 * q0 + e1 * q1 + e2 * q2 + e3 * q3
                     + e4 * q4 + e5 * q5 + e6 * q6 + e7 * q7;
                den += e0 + e1 + e2 + e3 + e4 + e5 + e6 + e7;
            }
            for (; i + 4 <= m; i += 4) {
                int s0 = sS[wave][i];
                int s1 = sS[wave][i + 1];
                int s2 = sS[wave][i + 2];
                int s3 = sS[wave][i + 3];
                float q0 = bf2f(h2b[(size_t)s0 * 64 + lane]);
                float q1 = bf2f(h2b[(size_t)s1 * 64 + lane]);
                float q2 = bf2f(h2b[(size_t)s2 * 64 + lane]);
                float q3 = bf2f(h2b[(size_t)s3 * 64 + lane]);
                float e0 = eS[wave][i];
                float e1 = eS[wave][i + 1];
                float e2 = eS[wave][i + 2];
                float e3 = eS[wave][i + 3];
                acc += e0 * q0 + e1 * q1 + e2 * q2 + e3 * q3;
                den += e0 + e1 + e2 + e3;
            }
            for (; i < m; ++i) {
                int s = sS[wave][i];
                float eh = eS[wave][i];
                acc += eh * bf2f(h2b[(size_t)s * 64 + lane]);
                den += eh;
            }
        }
        out[(size_t)n * 64 + lane] = eluf(acc / (den + 1e-16f) + b2s[lane]);
    }
}

extern "C" void kernel_launch(void* const* d_in, const int* in_sizes, int n_in,
                              void* d_out, int out_size, void* d_ws, size_t ws_size,
                              hipStream_t stream) {
    const float* x   = (const float*)d_in[0];
    const int*   ei  = (const int*)d_in[1];
    const float* W1  = (const float*)d_in[2];
    const float* as1 = (const float*)d_in[3];
    const float* ad1 = (const float*)d_in[4];
    const float* b1  = (const float*)d_in[5];
    const float* W2  = (const float*)d_in[6];
    const float* as2 = (const float*)d_in[7];
    const float* ad2 = (const float*)d_in[8];
    const float* b2  = (const float*)d_in[9];
    float* out = (float*)d_out;

    const int n = in_sizes[0] / 16;   // 50000
    const int e = in_sizes[1] / 2;    // 400000
    const int* src = ei;
    const int* dst = ei + e;
    const int nb = (n + 255) / 256;

    float* ws = (float*)d_ws;
    size_t o = 0;
    unsigned short* h1b = (unsigned short*)(ws + o); o += (size_t)n * 128;  // [N,256] bf16
    float4* csr_ex  = (float4*)(ws + o); o += (size_t)e * 4;
    float*  a_src1  = ws + o; o += (size_t)n * 4;
    float*  a_dst1  = ws + o; o += (size_t)n * 4;
    unsigned short* h2b = (unsigned short*)(ws + o); o += (size_t)n * 32;   // [N,64] bf16
    float*  a_src2  = ws + o; o += (size_t)n;
    float*  a_dst2  = ws + o; o += (size_t)n;
    int*    csr_src = (int*)(ws + o); o += (size_t)e;
    int*    rank    = (int*)(ws + o); o += (size_t)e;
    int*    deg     = (int*)(ws + o); o += (size_t)n;
    int*    off     = (int*)(ws + o); o += (size_t)(n + 4);
    int*    bsum    = (int*)(ws + o); o += 256;
    int*    bofs    = (int*)(ws + o); o += 256;

    hipMemsetAsync(deg, 0, (size_t)n * sizeof(int), stream);

    // CSR build (structure only)
    k_deg<<<(e + 255) / 256, 256, 0, stream>>>(dst, deg, rank, e);
    k_scan_bsums<<<nb, 256, 0, stream>>>(deg, bsum, n);
    k_scan_bofs<<<1, 256, 0, stream>>>(bsum, bofs, nb);
    k_scan_final<<<nb, 256, 0, stream>>>(deg, bofs, off, n, e);

    // Layer 1
    k1_gemm1<<<(n + 3) / 4, 256, 0, stream>>>(x, W1, as1, ad1, h1b, a_src1, a_dst1, n);
    k3_scatter<<<(e + 255) / 256, 256, 0, stream>>>(src, dst, a_src1, a_dst1, off, rank,
                                                    csr_src, csr_ex, e);
    k4_agg1<<<(n + 3) / 4, 256, 0, stream>>>(off, csr_src, csr_ex, h1b, a_src1, a_dst1,
                                             b1, W2, as2, ad2, h2b, a_src2, a_dst2, n);

    // Layer 2
    k8_agg2<<<(n + 3) / 4, 256, 0, stream>>>(off, csr_src, h2b, a_src2, a_dst2, b2, out, n);
}

// Round 10
// 276.861 us; speedup vs baseline: 1.7104x; 1.1328x over previous
//
#include <hip/hip_runtime.h>
#include <math.h>

// ---------------------------------------------------------------------------
// 2-layer GAT encoder. CSR-by-dst gather aggregation (atomic-free).
// Round-10 change:
//  * k4 split into k4a (pure gather/softmax/mean/ELU -> x2 [N,64] fp32) and
//    k4b (dense GEMM2 + layer-2 scores). Rounds 4-9 showed the allocator
//    pins k4 at 64 VGPRs and spills the combined gather+epilogue live set
//    (x8 unroll: 205MB scratch writes). Separated, each kernel's live set
//    fits: k4a keeps the x8-unrolled gather loop with only 5 accumulators
//    live; k4b is a small dense GEMM.
// ---------------------------------------------------------------------------

__device__ __forceinline__ float leaky02(float x) { return x > 0.f ? x : 0.2f * x; }
__device__ __forceinline__ float eluf(float x) { return x > 0.f ? x : expm1f(x); }
__device__ __forceinline__ float waveReduceSum(float v) {
#pragma unroll
    for (int off = 32; off; off >>= 1) v += __shfl_xor(v, off, 64);
    return v;
}
__device__ __forceinline__ unsigned short f2bf(float f) {
    unsigned u = __float_as_uint(f);
    u += 0x7FFFu + ((u >> 16) & 1u);
    return (unsigned short)(u >> 16);
}
__device__ __forceinline__ float bf2f(unsigned short h) {
    return __uint_as_float((unsigned)h << 16);
}

// ---------------- CSR construction ----------------

__global__ void k_deg(const int* __restrict__ dst, int* __restrict__ deg,
                      int* __restrict__ rank, int e_cnt) {
    int e = blockIdx.x * blockDim.x + threadIdx.x;
    if (e < e_cnt) rank[e] = atomicAdd(&deg[dst[e]], 1);
}

__global__ void k_scan_bsums(const int* __restrict__ deg, int* __restrict__ bsum, int n) {
    __shared__ int part[4];
    int i = blockIdx.x * 256 + threadIdx.x;
    int v = (i < n) ? deg[i] : 0;
    int w = v;
#pragma unroll
    for (int off = 32; off; off >>= 1) w += __shfl_xor(w, off, 64);
    if ((threadIdx.x & 63) == 0) part[threadIdx.x >> 6] = w;
    __syncthreads();
    if (threadIdx.x == 0) bsum[blockIdx.x] = part[0] + part[1] + part[2] + part[3];
}

__global__ void k_scan_bofs(const int* __restrict__ bsum, int* __restrict__ bofs, int nb) {
    __shared__ int s[256];
    int t = threadIdx.x;
    int v = (t < nb) ? bsum[t] : 0;
    s[t] = v;
    __syncthreads();
#pragma unroll
    for (int d = 1; d < 256; d <<= 1) {
        int add = (t >= d) ? s[t - d] : 0;
        __syncthreads();
        s[t] += add;
        __syncthreads();
    }
    bofs[t] = s[t] - v;  // exclusive
}

__global__ void k_scan_final(const int* __restrict__ deg, const int* __restrict__ bofs,
                             int* __restrict__ off, int n, int e_cnt) {
    __shared__ int s[256];
    int t = threadIdx.x;
    int i = blockIdx.x * 256 + t;
    int v = (i < n) ? deg[i] : 0;
    s[t] = v;
    __syncthreads();
#pragma unroll
    for (int d = 1; d < 256; d <<= 1) {
        int add = (t >= d) ? s[t - d] : 0;
        __syncthreads();
        s[t] += add;
        __syncthreads();
    }
    int o = bofs[blockIdx.x] + s[t] - v;
    if (i < n) off[i] = o;
    if (i == 0) off[n] = e_cnt;
}

// ---------------- Layer 1 ----------------

// K1: h1b (bf16, [N,256], channel c = 4*lane+j); a_src1/a_dst1 [N,4] fp32.
__global__ void k1_gemm1(const float* __restrict__ x, const float* __restrict__ W1,
                         const float* __restrict__ attS, const float* __restrict__ attD,
                         unsigned short* __restrict__ h1b, float* __restrict__ a_src1,
                         float* __restrict__ a_dst1, int n_nodes) {
    __shared__ float W1s[16 * 256];
    for (int i = threadIdx.x; i < 16 * 256; i += 256) W1s[i] = W1[i];
    __syncthreads();
    const int wave = threadIdx.x >> 6, lane = threadIdx.x & 63;
    const float4 aS = ((const float4*)attS)[lane];
    const float4 aD = ((const float4*)attD)[lane];
    for (int n = blockIdx.x * 4 + wave; n < n_nodes; n += gridDim.x * 4) {
        float xv = x[(size_t)n * 16 + (lane & 15)];
        float v0 = 0.f, v1 = 0.f, v2 = 0.f, v3 = 0.f;
#pragma unroll
        for (int k = 0; k < 16; ++k) {
            float xk = __shfl(xv, k, 64);
            const float* w = W1s + k * 256 + 4 * lane;
            v0 += xk * w[0]; v1 += xk * w[1]; v2 += xk * w[2]; v3 += xk * w[3];
        }
        ushort4 q;
        q.x = f2bf(v0); q.y = f2bf(v1); q.z = f2bf(v2); q.w = f2bf(v3);
        ((ushort4*)(h1b + (size_t)n * 256))[lane] = q;
        float ps = v0 * aS.x + v1 * aS.y + v2 * aS.z + v3 * aS.w;
        float pd = v0 * aD.x + v1 * aD.y + v2 * aD.z + v3 * aD.w;
#pragma unroll
        for (int off = 1; off < 16; off <<= 1) {
            ps += __shfl_xor(ps, off, 64);
            pd += __shfl_xor(pd, off, 64);
        }
        if ((lane & 15) == 0) {
            a_src1[n * 4 + (lane >> 4)] = ps;
            a_dst1[n * 4 + (lane >> 4)] = pd;
        }
    }
}

// K3: per-edge exp (4 heads) + atomic-free scatter into CSR slot off[d]+rank[e].
__global__ void k3_scatter(const int* __restrict__ src, const int* __restrict__ dst,
                           const float* __restrict__ a_src1, const float* __restrict__ a_dst1,
                           const int* __restrict__ off, const int* __restrict__ rank,
                           int* __restrict__ csr_src, float4* __restrict__ csr_ex, int e_cnt) {
    int e = blockIdx.x * blockDim.x + threadIdx.x;
    if (e >= e_cnt) return;
    int s = src[e], d = dst[e];
    float4 as = *(const float4*)(a_src1 + (size_t)s * 4);
    float4 ad = *(const float4*)(a_dst1 + (size_t)d * 4);
    float4 ex;
    ex.x = expf(leaky02(as.x + ad.x));
    ex.y = expf(leaky02(as.y + ad.y));
    ex.z = expf(leaky02(as.z + ad.z));
    ex.w = expf(leaky02(as.w + ad.w));
    int pos = off[d] + rank[e];
    csr_src[pos] = s;
    csr_ex[pos] = ex;
}

// K4a: layer-1 softmax-gather + head-mean + b1 + ELU -> x2 [N,64] fp32.
// Wave per dst node; lane owns channels 4l..4l+3 (head = lane>>4).
// Minimal live set: x8-unrolled gather fits without spill.
__global__ void __launch_bounds__(256, 4)
k4a_agg1(const int* __restrict__ off, const int* __restrict__ csr_src,
         const float4* __restrict__ csr_ex, const unsigned short* __restrict__ h1b,
         const float* __restrict__ a_src1, const float* __restrict__ a_dst1,
         const float* __restrict__ b1, float4* __restrict__ x2v4, int n_nodes) {
    __shared__ int   sS[4][16];   // per-wave chunk src ids
    __shared__ float eS[4][64];   // per-wave chunk exp4, [edge*4 + head]
    const int wave = threadIdx.x >> 6, lane = threadIdx.x & 63;
    const int head = lane >> 4;
    const float4 b1v = ((const float4*)b1)[lane & 15];
    for (int n = blockIdx.x * 4 + wave; n < n_nodes; n += gridDim.x * 4) {
        int beg = off[n], end = off[n + 1];
        float4 as = *(const float4*)(a_src1 + (size_t)n * 4);
        float4 ad = *(const float4*)(a_dst1 + (size_t)n * 4);
        float adh = head == 0 ? ad.x : head == 1 ? ad.y : head == 2 ? ad.z : ad.w;
        float ash = head == 0 ? as.x : head == 1 ? as.y : head == 2 ? as.z : as.w;
        float se = expf(leaky02(ash + adh));
        ushort4 qs = ((const ushort4*)(h1b + (size_t)n * 256))[lane];
        float den = se;
        float a0 = se * bf2f(qs.x), a1 = se * bf2f(qs.y);
        float a2 = se * bf2f(qs.z), a3 = se * bf2f(qs.w);
        for (int base = beg; base < end; base += 16) {
            int m = end - base; if (m > 16) m = 16;
            if (lane < m) {
                sS[wave][lane] = csr_src[base + lane];
                ((float4*)eS[wave])[lane] = csr_ex[base + lane];
            }
            int i = 0;
            for (; i + 8 <= m; i += 8) {
                int s0 = sS[wave][i];
                int s1 = sS[wave][i + 1];
                int s2 = sS[wave][i + 2];
                int s3 = sS[wave][i + 3];
                int s4 = sS[wave][i + 4];
                int s5 = sS[wave][i + 5];
                int s6 = sS[wave][i + 6];
                int s7 = sS[wave][i + 7];
                ushort4 q0 = ((const ushort4*)(h1b + (size_t)s0 * 256))[lane];
                ushort4 q1 = ((const ushort4*)(h1b + (size_t)s1 * 256))[lane];
                ushort4 q2 = ((const ushort4*)(h1b + (size_t)s2 * 256))[lane];
                ushort4 q3 = ((const ushort4*)(h1b + (size_t)s3 * 256))[lane];
                ushort4 q4 = ((const ushort4*)(h1b + (size_t)s4 * 256))[lane];
                ushort4 q5 = ((const ushort4*)(h1b + (size_t)s5 * 256))[lane];
                ushort4 q6 = ((const ushort4*)(h1b + (size_t)s6 * 256))[lane];
                ushort4 q7 = ((const ushort4*)(h1b + (size_t)s7 * 256))[lane];
                float e0 = eS[wave][4 * i + head];
                float e1 = eS[wave][4 * (i + 1) + head];
                float e2 = eS[wave][4 * (i + 2) + head];
                float e3 = eS[wave][4 * (i + 3) + head];
                float e4 = eS[wave][4 * (i + 4) + head];
                float e5 = eS[wave][4 * (i + 5) + head];
                float e6 = eS[wave][4 * (i + 6) + head];
                float e7 = eS[wave][4 * (i + 7) + head];
                a0 += e0 * bf2f(q0.x) + e1 * bf2f(q1.x) + e2 * bf2f(q2.x) + e3 * bf2f(q3.x)
                    + e4 * bf2f(q4.x) + e5 * bf2f(q5.x) + e6 * bf2f(q6.x) + e7 * bf2f(q7.x);
                a1 += e0 * bf2f(q0.y) + e1 * bf2f(q1.y) + e2 * bf2f(q2.y) + e3 * bf2f(q3.y)
                    + e4 * bf2f(q4.y) + e5 * bf2f(q5.y) + e6 * bf2f(q6.y) + e7 * bf2f(q7.y);
                a2 += e0 * bf2f(q0.z) + e1 * bf2f(q1.z) + e2 * bf2f(q2.z) + e3 * bf2f(q3.z)
                    + e4 * bf2f(q4.z) + e5 * bf2f(q5.z) + e6 * bf2f(q6.z) + e7 * bf2f(q7.z);
                a3 += e0 * bf2f(q0.w) + e1 * bf2f(q1.w) + e2 * bf2f(q2.w) + e3 * bf2f(q3.w)
                    + e4 * bf2f(q4.w) + e5 * bf2f(q5.w) + e6 * bf2f(q6.w) + e7 * bf2f(q7.w);
                den += e0 + e1 + e2 + e3 + e4 + e5 + e6 + e7;
            }
            for (; i + 4 <= m; i += 4) {
                int s0 = sS[wave][i];
                int s1 = sS[wave][i + 1];
                int s2 = sS[wave][i + 2];
                int s3 = sS[wave][i + 3];
                ushort4 q0 = ((const ushort4*)(h1b + (size_t)s0 * 256))[lane];
                ushort4 q1 = ((const ushort4*)(h1b + (size_t)s1 * 256))[lane];
                ushort4 q2 = ((const ushort4*)(h1b + (size_t)s2 * 256))[lane];
                ushort4 q3 = ((const ushort4*)(h1b + (size_t)s3 * 256))[lane];
                float e0 = eS[wave][4 * i + head];
                float e1 = eS[wave][4 * (i + 1) + head];
                float e2 = eS[wave][4 * (i + 2) + head];
                float e3 = eS[wave][4 * (i + 3) + head];
                a0 += e0 * bf2f(q0.x) + e1 * bf2f(q1.x) + e2 * bf2f(q2.x) + e3 * bf2f(q3.x);
                a1 += e0 * bf2f(q0.y) + e1 * bf2f(q1.y) + e2 * bf2f(q2.y) + e3 * bf2f(q3.y);
                a2 += e0 * bf2f(q0.z) + e1 * bf2f(q1.z) + e2 * bf2f(q2.z) + e3 * bf2f(q3.z);
                a3 += e0 * bf2f(q0.w) + e1 * bf2f(q1.w) + e2 * bf2f(q2.w) + e3 * bf2f(q3.w);
                den += e0 + e1 + e2 + e3;
            }
            for (; i < m; ++i) {
                int s = sS[wave][i];
                float eh = eS[wave][4 * i + head];
                ushort4 q = ((const ushort4*)(h1b + (size_t)s * 256))[lane];
                a0 += eh * bf2f(q.x); a1 += eh * bf2f(q.y);
                a2 += eh * bf2f(q.z); a3 += eh * bf2f(q.w);
                den += eh;
            }
        }
        float inv = 1.f / (den + 1e-16f);
        float t0 = a0 * inv, t1 = a1 * inv, t2 = a2 * inv, t3 = a3 * inv;
        // sum 4 heads: lanes {l, l^16, l^32, l^48} hold the same channel slot
        t0 += __shfl_xor(t0, 16, 64); t0 += __shfl_xor(t0, 32, 64);
        t1 += __shfl_xor(t1, 16, 64); t1 += __shfl_xor(t1, 32, 64);
        t2 += __shfl_xor(t2, 16, 64); t2 += __shfl_xor(t2, 32, 64);
        t3 += __shfl_xor(t3, 16, 64); t3 += __shfl_xor(t3, 32, 64);
        if (lane < 16) {
            float4 xo;
            xo.x = eluf(0.25f * t0 + b1v.x);
            xo.y = eluf(0.25f * t1 + b1v.y);
            xo.z = eluf(0.25f * t2 + b1v.z);
            xo.w = eluf(0.25f * t3 + b1v.w);
            x2v4[(size_t)n * 16 + lane] = xo;
        }
    }
}

// K4b: dense GEMM2 (x2 [N,64] @ W2 [64,64]) + layer-2 scores.
// Wave per node; lane = output channel.
__global__ void k4b_gemm2(const float4* __restrict__ x2v4, const float* __restrict__ W2,
                          const float* __restrict__ attS2, const float* __restrict__ attD2,
                          unsigned short* __restrict__ h2b, float* __restrict__ a_src2,
                          float* __restrict__ a_dst2, int n_nodes) {
    __shared__ float W2s[64 * 64];
    __shared__ float as2s[64], ad2s[64];
    for (int i = threadIdx.x; i < 64 * 64; i += 256) W2s[i] = W2[i];
    if (threadIdx.x < 64) {
        as2s[threadIdx.x] = attS2[threadIdx.x];
        ad2s[threadIdx.x] = attD2[threadIdx.x];
    }
    __syncthreads();
    const int wave = threadIdx.x >> 6, lane = threadIdx.x & 63;
    for (int n = blockIdx.x * 4 + wave; n < n_nodes; n += gridDim.x * 4) {
        float4 xv = x2v4[(size_t)n * 16 + (lane & 15)];
        float g = 0.f;
#pragma unroll
        for (int qq = 0; qq < 16; ++qq) {
            float xk0 = __shfl(xv.x, qq, 64);
            float xk1 = __shfl(xv.y, qq, 64);
            float xk2 = __shfl(xv.z, qq, 64);
            float xk3 = __shfl(xv.w, qq, 64);
            const float* w = W2s + (4 * qq) * 64 + lane;
            g += xk0 * w[0] + xk1 * w[64] + xk2 * w[128] + xk3 * w[192];
        }
        h2b[(size_t)n * 64 + lane] = f2bf(g);
        float ps = waveReduceSum(g * as2s[lane]);
        float pd = waveReduceSum(g * ad2s[lane]);
        if (lane == 0) {
            a_src2[n] = ps;
            a_dst2[n] = pd;
        }
    }
}

// ---------------- Layer 2 ----------------

// K8: fused layer-2 softmax-gather + self message + b2 + ELU -> out.
__global__ void __launch_bounds__(256, 4)
k8_agg2(const int* __restrict__ off, const int* __restrict__ csr_src,
        const unsigned short* __restrict__ h2b,
        const float* __restrict__ a_src2, const float* __restrict__ a_dst2,
        const float* __restrict__ b2, float* __restrict__ out, int n_nodes) {
    __shared__ float b2s[64];
    __shared__ int   sS[4][64];
    __shared__ float eS[4][64];
    if (threadIdx.x < 64) b2s[threadIdx.x] = b2[threadIdx.x];
    __syncthreads();
    const int wave = threadIdx.x >> 6, lane = threadIdx.x & 63;
    for (int n = blockIdx.x * 4 + wave; n < n_nodes; n += gridDim.x * 4) {
        int beg = off[n], end = off[n + 1];
        float adn = a_dst2[n];
        float se = expf(leaky02(a_src2[n] + adn));
        float den = se;
        float acc = se * bf2f(h2b[(size_t)n * 64 + lane]);
        for (int base = beg; base < end; base += 64) {
            int m = end - base; if (m > 64) m = 64;
            if (lane < m) {
                int s = csr_src[base + lane];
                sS[wave][lane] = s;
                eS[wave][lane] = expf(leaky02(a_src2[s] + adn));
            }
            int i = 0;
            for (; i + 8 <= m; i += 8) {
                int s0 = sS[wave][i];
                int s1 = sS[wave][i + 1];
                int s2 = sS[wave][i + 2];
                int s3 = sS[wave][i + 3];
                int s4 = sS[wave][i + 4];
                int s5 = sS[wave][i + 5];
                int s6 = sS[wave][i + 6];
                int s7 = sS[wave][i + 7];
                float q0 = bf2f(h2b[(size_t)s0 * 64 + lane]);
                float q1 = bf2f(h2b[(size_t)s1 * 64 + lane]);
                float q2 = bf2f(h2b[(size_t)s2 * 64 + lane]);
                float q3 = bf2f(h2b[(size_t)s3 * 64 + lane]);
                float q4 = bf2f(h2b[(size_t)s4 * 64 + lane]);
                float q5 = bf2f(h2b[(size_t)s5 * 64 + lane]);
                float q6 = bf2f(h2b[(size_t)s6 * 64 + lane]);
                float q7 = bf2f(h2b[(size_t)s7 * 64 + lane]);
                float e0 = eS[wave][i];
                float e1 = eS[wave][i + 1];
                float e2 = eS[wave][i + 2];
                float e3 = eS[wave][i + 3];
                float e4 = eS[wave][i + 4];
                float e5 = eS[wave][i + 5];
                float e6 = eS[wave][i + 6];
                float e7 = eS[wave][i + 7];
                acc += e0 * q0 + e1 * q1 + e2 * q2 + e3 * q3
                     + e4 * q4 + e5 * q5 + e6 * q6 + e7 * q7;
                den += e0 + e1 + e2 + e3 + e4 + e5 + e6 + e7;
            }
            for (; i + 4 <= m; i += 4) {
                int s0 = sS[wave][i];
                int s1 = sS[wave][i + 1];
                int s2 = sS[wave][i + 2];
                int s3 = sS[wave][i + 3];
                float q0 = bf2f(h2b[(size_t)s0 * 64 + lane]);
                float q1 = bf2f(h2b[(size_t)s1 * 64 + lane]);
                float q2 = bf2f(h2b[(size_t)s2 * 64 + lane]);
                float q3 = bf2f(h2b[(size_t)s3 * 64 + lane]);
                float e0 = eS[wave][i];
                float e1 = eS[wave][i + 1];
                float e2 = eS[wave][i + 2];
                float e3 = eS[wave][i + 3];
                acc += e0 * q0 + e1 * q1 + e2 * q2 + e3 * q3;
                den += e0 + e1 + e2 + e3;
            }
            for (; i < m; ++i) {
                int s = sS[wave][i];
                float eh = eS[wave][i];
                acc += eh * bf2f(h2b[(size_t)s * 64 + lane]);
                den += eh;
            }
        }
        out[(size_t)n * 64 + lane] = eluf(acc / (den + 1e-16f) + b2s[lane]);
    }
}

extern "C" void kernel_launch(void* const* d_in, const int* in_sizes, int n_in,
                              void* d_out, int out_size, void* d_ws, size_t ws_size,
                              hipStream_t stream) {
    const float* x   = (const float*)d_in[0];
    const int*   ei  = (const int*)d_in[1];
    const float* W1  = (const float*)d_in[2];
    const float* as1 = (const float*)d_in[3];
    const float* ad1 = (const float*)d_in[4];
    const float* b1  = (const float*)d_in[5];
    const float* W2  = (const float*)d_in[6];
    const float* as2 = (const float*)d_in[7];
    const float* ad2 = (const float*)d_in[8];
    const float* b2  = (const float*)d_in[9];
    float* out = (float*)d_out;

    const int n = in_sizes[0] / 16;   // 50000
    const int e = in_sizes[1] / 2;    // 400000
    const int* src = ei;
    const int* dst = ei + e;
    const int nb = (n + 255) / 256;

    float* ws = (float*)d_ws;
    size_t o = 0;
    unsigned short* h1b = (unsigned short*)(ws + o); o += (size_t)n * 128;  // [N,256] bf16
    float4* csr_ex  = (float4*)(ws + o); o += (size_t)e * 4;
    float4* x2v4    = (float4*)(ws + o); o += (size_t)n * 64;               // [N,64] fp32
    float*  a_src1  = ws + o; o += (size_t)n * 4;
    float*  a_dst1  = ws + o; o += (size_t)n * 4;
    unsigned short* h2b = (unsigned short*)(ws + o); o += (size_t)n * 32;   // [N,64] bf16
    float*  a_src2  = ws + o; o += (size_t)n;
    float*  a_dst2  = ws + o; o += (size_t)n;
    int*    csr_src = (int*)(ws + o); o += (size_t)e;
    int*    rank    = (int*)(ws + o); o += (size_t)e;
    int*    deg     = (int*)(ws + o); o += (size_t)n;
    int*    off     = (int*)(ws + o); o += (size_t)(n + 4);
    int*    bsum    = (int*)(ws + o); o += 256;
    int*    bofs    = (int*)(ws + o); o += 256;

    hipMemsetAsync(deg, 0, (size_t)n * sizeof(int), stream);

    // CSR build (structure only)
    k_deg<<<(e + 255) / 256, 256, 0, stream>>>(dst, deg, rank, e);
    k_scan_bsums<<<nb, 256, 0, stream>>>(deg, bsum, n);
    k_scan_bofs<<<1, 256, 0, stream>>>(bsum, bofs, nb);
    k_scan_final<<<nb, 256, 0, stream>>>(deg, bofs, off, n, e);

    // Layer 1
    k1_gemm1<<<(n + 3) / 4, 256, 0, stream>>>(x, W1, as1, ad1, h1b, a_src1, a_dst1, n);
    k3_scatter<<<(e + 255) / 256, 256, 0, stream>>>(src, dst, a_src1, a_dst1, off, rank,
                                                    csr_src, csr_ex, e);
    k4a_agg1<<<(n + 3) / 4, 256, 0, stream>>>(off, csr_src, csr_ex, h1b, a_src1, a_dst1,
                                              b1, x2v4, n);
    k4b_gemm2<<<(n + 3) / 4, 256, 0, stream>>>(x2v4, W2, as2, ad2, h2b, a_src2, a_dst2, n);

    // Layer 2
    k8_agg2<<<(n + 3) / 4, 256, 0, stream>>>(off, csr_src, h2b, a_src2, a_dst2, b2, out, n);
}

// Round 11
// 226.371 us; speedup vs baseline: 2.0918x; 1.2230x over previous
//
#include <hip/hip_runtime.h>
#include <math.h>

// ---------------------------------------------------------------------------
// 2-layer GAT encoder. CSR-by-dst gather aggregation (atomic-free).
// Round-11 change:
//  * k4b was LDS-pipe-bound (64 bpermute + 64 LDS reads per node ~ 740
//    cyc/node == measured 68us). Replaced with MFMA GEMM: x2 stored bf16 by
//    k4a, W2 transposed+cast to bf16 once, each wave does 2x
//    mfma_f32_16x16x32_bf16 per 16-node tile (B fragment in registers, no
//    LDS in the main path). Scores from fp32 accumulators.
// ---------------------------------------------------------------------------

typedef __attribute__((ext_vector_type(8))) short s8v;   // 8 bf16 (4 VGPRs)
typedef __attribute__((ext_vector_type(4))) float f4v;   // 4 fp32 acc

__device__ __forceinline__ float leaky02(float x) { return x > 0.f ? x : 0.2f * x; }
__device__ __forceinline__ float eluf(float x) { return x > 0.f ? x : expm1f(x); }
__device__ __forceinline__ unsigned short f2bf(float f) {
    unsigned u = __float_as_uint(f);
    u += 0x7FFFu + ((u >> 16) & 1u);
    return (unsigned short)(u >> 16);
}
__device__ __forceinline__ float bf2f(unsigned short h) {
    return __uint_as_float((unsigned)h << 16);
}

// ---------------- CSR construction ----------------

__global__ void k_deg(const int* __restrict__ dst, int* __restrict__ deg,
                      int* __restrict__ rank, int e_cnt) {
    int e = blockIdx.x * blockDim.x + threadIdx.x;
    if (e < e_cnt) rank[e] = atomicAdd(&deg[dst[e]], 1);
}

__global__ void k_scan_bsums(const int* __restrict__ deg, int* __restrict__ bsum, int n) {
    __shared__ int part[4];
    int i = blockIdx.x * 256 + threadIdx.x;
    int v = (i < n) ? deg[i] : 0;
    int w = v;
#pragma unroll
    for (int off = 32; off; off >>= 1) w += __shfl_xor(w, off, 64);
    if ((threadIdx.x & 63) == 0) part[threadIdx.x >> 6] = w;
    __syncthreads();
    if (threadIdx.x == 0) bsum[blockIdx.x] = part[0] + part[1] + part[2] + part[3];
}

__global__ void k_scan_bofs(const int* __restrict__ bsum, int* __restrict__ bofs, int nb) {
    __shared__ int s[256];
    int t = threadIdx.x;
    int v = (t < nb) ? bsum[t] : 0;
    s[t] = v;
    __syncthreads();
#pragma unroll
    for (int d = 1; d < 256; d <<= 1) {
        int add = (t >= d) ? s[t - d] : 0;
        __syncthreads();
        s[t] += add;
        __syncthreads();
    }
    bofs[t] = s[t] - v;  // exclusive
}

__global__ void k_scan_final(const int* __restrict__ deg, const int* __restrict__ bofs,
                             int* __restrict__ off, int n, int e_cnt) {
    __shared__ int s[256];
    int t = threadIdx.x;
    int i = blockIdx.x * 256 + t;
    int v = (i < n) ? deg[i] : 0;
    s[t] = v;
    __syncthreads();
#pragma unroll
    for (int d = 1; d < 256; d <<= 1) {
        int add = (t >= d) ? s[t - d] : 0;
        __syncthreads();
        s[t] += add;
        __syncthreads();
    }
    int o = bofs[blockIdx.x] + s[t] - v;
    if (i < n) off[i] = o;
    if (i == 0) off[n] = e_cnt;
}

// ---------------- Layer 1 ----------------

// K1: h1b (bf16, [N,256], channel c = 4*lane+j); a_src1/a_dst1 [N,4] fp32.
__global__ void k1_gemm1(const float* __restrict__ x, const float* __restrict__ W1,
                         const float* __restrict__ attS, const float* __restrict__ attD,
                         unsigned short* __restrict__ h1b, float* __restrict__ a_src1,
                         float* __restrict__ a_dst1, int n_nodes) {
    __shared__ float W1s[16 * 256];
    for (int i = threadIdx.x; i < 16 * 256; i += 256) W1s[i] = W1[i];
    __syncthreads();
    const int wave = threadIdx.x >> 6, lane = threadIdx.x & 63;
    const float4 aS = ((const float4*)attS)[lane];
    const float4 aD = ((const float4*)attD)[lane];
    for (int n = blockIdx.x * 4 + wave; n < n_nodes; n += gridDim.x * 4) {
        float xv = x[(size_t)n * 16 + (lane & 15)];
        float v0 = 0.f, v1 = 0.f, v2 = 0.f, v3 = 0.f;
#pragma unroll
        for (int k = 0; k < 16; ++k) {
            float xk = __shfl(xv, k, 64);
            const float* w = W1s + k * 256 + 4 * lane;
            v0 += xk * w[0]; v1 += xk * w[1]; v2 += xk * w[2]; v3 += xk * w[3];
        }
        ushort4 q;
        q.x = f2bf(v0); q.y = f2bf(v1); q.z = f2bf(v2); q.w = f2bf(v3);
        ((ushort4*)(h1b + (size_t)n * 256))[lane] = q;
        float ps = v0 * aS.x + v1 * aS.y + v2 * aS.z + v3 * aS.w;
        float pd = v0 * aD.x + v1 * aD.y + v2 * aD.z + v3 * aD.w;
#pragma unroll
        for (int off = 1; off < 16; off <<= 1) {
            ps += __shfl_xor(ps, off, 64);
            pd += __shfl_xor(pd, off, 64);
        }
        if ((lane & 15) == 0) {
            a_src1[n * 4 + (lane >> 4)] = ps;
            a_dst1[n * 4 + (lane >> 4)] = pd;
        }
    }
}

// K3: per-edge exp (4 heads) + atomic-free scatter into CSR slot off[d]+rank[e].
__global__ void k3_scatter(const int* __restrict__ src, const int* __restrict__ dst,
                           const float* __restrict__ a_src1, const float* __restrict__ a_dst1,
                           const int* __restrict__ off, const int* __restrict__ rank,
                           int* __restrict__ csr_src, float4* __restrict__ csr_ex, int e_cnt) {
    int e = blockIdx.x * blockDim.x + threadIdx.x;
    if (e >= e_cnt) return;
    int s = src[e], d = dst[e];
    float4 as = *(const float4*)(a_src1 + (size_t)s * 4);
    float4 ad = *(const float4*)(a_dst1 + (size_t)d * 4);
    float4 ex;
    ex.x = expf(leaky02(as.x + ad.x));
    ex.y = expf(leaky02(as.y + ad.y));
    ex.z = expf(leaky02(as.z + ad.z));
    ex.w = expf(leaky02(as.w + ad.w));
    int pos = off[d] + rank[e];
    csr_src[pos] = s;
    csr_ex[pos] = ex;
}

// K4a: layer-1 softmax-gather + head-mean + b1 + ELU -> x2b [N,64] bf16.
__global__ void __launch_bounds__(256, 4)
k4a_agg1(const int* __restrict__ off, const int* __restrict__ csr_src,
         const float4* __restrict__ csr_ex, const unsigned short* __restrict__ h1b,
         const float* __restrict__ a_src1, const float* __restrict__ a_dst1,
         const float* __restrict__ b1, unsigned short* __restrict__ x2b, int n_nodes) {
    __shared__ int   sS[4][16];   // per-wave chunk src ids
    __shared__ float eS[4][64];   // per-wave chunk exp4, [edge*4 + head]
    const int wave = threadIdx.x >> 6, lane = threadIdx.x & 63;
    const int head = lane >> 4;
    const float4 b1v = ((const float4*)b1)[lane & 15];
    for (int n = blockIdx.x * 4 + wave; n < n_nodes; n += gridDim.x * 4) {
        int beg = off[n], end = off[n + 1];
        float4 as = *(const float4*)(a_src1 + (size_t)n * 4);
        float4 ad = *(const float4*)(a_dst1 + (size_t)n * 4);
        float adh = head == 0 ? ad.x : head == 1 ? ad.y : head == 2 ? ad.z : ad.w;
        float ash = head == 0 ? as.x : head == 1 ? as.y : head == 2 ? as.z : as.w;
        float se = expf(leaky02(ash + adh));
        ushort4 qs = ((const ushort4*)(h1b + (size_t)n * 256))[lane];
        float den = se;
        float a0 = se * bf2f(qs.x), a1 = se * bf2f(qs.y);
        float a2 = se * bf2f(qs.z), a3 = se * bf2f(qs.w);
        for (int base = beg; base < end; base += 16) {
            int m = end - base; if (m > 16) m = 16;
            if (lane < m) {
                sS[wave][lane] = csr_src[base + lane];
                ((float4*)eS[wave])[lane] = csr_ex[base + lane];
            }
            int i = 0;
            for (; i + 8 <= m; i += 8) {
                int s0 = sS[wave][i];
                int s1 = sS[wave][i + 1];
                int s2 = sS[wave][i + 2];
                int s3 = sS[wave][i + 3];
                int s4 = sS[wave][i + 4];
                int s5 = sS[wave][i + 5];
                int s6 = sS[wave][i + 6];
                int s7 = sS[wave][i + 7];
                ushort4 q0 = ((const ushort4*)(h1b + (size_t)s0 * 256))[lane];
                ushort4 q1 = ((const ushort4*)(h1b + (size_t)s1 * 256))[lane];
                ushort4 q2 = ((const ushort4*)(h1b + (size_t)s2 * 256))[lane];
                ushort4 q3 = ((const ushort4*)(h1b + (size_t)s3 * 256))[lane];
                ushort4 q4 = ((const ushort4*)(h1b + (size_t)s4 * 256))[lane];
                ushort4 q5 = ((const ushort4*)(h1b + (size_t)s5 * 256))[lane];
                ushort4 q6 = ((const ushort4*)(h1b + (size_t)s6 * 256))[lane];
                ushort4 q7 = ((const ushort4*)(h1b + (size_t)s7 * 256))[lane];
                float e0 = eS[wave][4 * i + head];
                float e1 = eS[wave][4 * (i + 1) + head];
                float e2 = eS[wave][4 * (i + 2) + head];
                float e3 = eS[wave][4 * (i + 3) + head];
                float e4 = eS[wave][4 * (i + 4) + head];
                float e5 = eS[wave][4 * (i + 5) + head];
                float e6 = eS[wave][4 * (i + 6) + head];
                float e7 = eS[wave][4 * (i + 7) + head];
                a0 += e0 * bf2f(q0.x) + e1 * bf2f(q1.x) + e2 * bf2f(q2.x) + e3 * bf2f(q3.x)
                    + e4 * bf2f(q4.x) + e5 * bf2f(q5.x) + e6 * bf2f(q6.x) + e7 * bf2f(q7.x);
                a1 += e0 * bf2f(q0.y) + e1 * bf2f(q1.y) + e2 * bf2f(q2.y) + e3 * bf2f(q3.y)
                    + e4 * bf2f(q4.y) + e5 * bf2f(q5.y) + e6 * bf2f(q6.y) + e7 * bf2f(q7.y);
                a2 += e0 * bf2f(q0.z) + e1 * bf2f(q1.z) + e2 * bf2f(q2.z) + e3 * bf2f(q3.z)
                    + e4 * bf2f(q4.z) + e5 * bf2f(q5.z) + e6 * bf2f(q6.z) + e7 * bf2f(q7.z);
                a3 += e0 * bf2f(q0.w) + e1 * bf2f(q1.w) + e2 * bf2f(q2.w) + e3 * bf2f(q3.w)
                    + e4 * bf2f(q4.w) + e5 * bf2f(q5.w) + e6 * bf2f(q6.w) + e7 * bf2f(q7.w);
                den += e0 + e1 + e2 + e3 + e4 + e5 + e6 + e7;
            }
            for (; i + 4 <= m; i += 4) {
                int s0 = sS[wave][i];
                int s1 = sS[wave][i + 1];
                int s2 = sS[wave][i + 2];
                int s3 = sS[wave][i + 3];
                ushort4 q0 = ((const ushort4*)(h1b + (size_t)s0 * 256))[lane];
                ushort4 q1 = ((const ushort4*)(h1b + (size_t)s1 * 256))[lane];
                ushort4 q2 = ((const ushort4*)(h1b + (size_t)s2 * 256))[lane];
                ushort4 q3 = ((const ushort4*)(h1b + (size_t)s3 * 256))[lane];
                float e0 = eS[wave][4 * i + head];
                float e1 = eS[wave][4 * (i + 1) + head];
                float e2 = eS[wave][4 * (i + 2) + head];
                float e3 = eS[wave][4 * (i + 3) + head];
                a0 += e0 * bf2f(q0.x) + e1 * bf2f(q1.x) + e2 * bf2f(q2.x) + e3 * bf2f(q3.x);
                a1 += e0 * bf2f(q0.y) + e1 * bf2f(q1.y) + e2 * bf2f(q2.y) + e3 * bf2f(q3.y);
                a2 += e0 * bf2f(q0.z) + e1 * bf2f(q1.z) + e2 * bf2f(q2.z) + e3 * bf2f(q3.z);
                a3 += e0 * bf2f(q0.w) + e1 * bf2f(q1.w) + e2 * bf2f(q2.w) + e3 * bf2f(q3.w);
                den += e0 + e1 + e2 + e3;
            }
            for (; i < m; ++i) {
                int s = sS[wave][i];
                float eh = eS[wave][4 * i + head];
                ushort4 q = ((const ushort4*)(h1b + (size_t)s * 256))[lane];
                a0 += eh * bf2f(q.x); a1 += eh * bf2f(q.y);
                a2 += eh * bf2f(q.z); a3 += eh * bf2f(q.w);
                den += eh;
            }
        }
        float inv = 1.f / (den + 1e-16f);
        float t0 = a0 * inv, t1 = a1 * inv, t2 = a2 * inv, t3 = a3 * inv;
        t0 += __shfl_xor(t0, 16, 64); t0 += __shfl_xor(t0, 32, 64);
        t1 += __shfl_xor(t1, 16, 64); t1 += __shfl_xor(t1, 32, 64);
        t2 += __shfl_xor(t2, 16, 64); t2 += __shfl_xor(t2, 32, 64);
        t3 += __shfl_xor(t3, 16, 64); t3 += __shfl_xor(t3, 32, 64);
        if (lane < 16) {
            ushort4 xo;
            xo.x = f2bf(eluf(0.25f * t0 + b1v.x));
            xo.y = f2bf(eluf(0.25f * t1 + b1v.y));
            xo.z = f2bf(eluf(0.25f * t2 + b1v.z));
            xo.w = f2bf(eluf(0.25f * t3 + b1v.w));
            ((ushort4*)(x2b + (size_t)n * 64))[lane] = xo;
        }
    }
}

// W2 [64][64] fp32 row-major (k,c) -> W2T bf16 [c][k].
__global__ void k_w2t(const float* __restrict__ W2, unsigned short* __restrict__ w2tb) {
    int i = blockIdx.x * 256 + threadIdx.x;
    if (i >= 64 * 64) return;
    int c = i >> 6, k = i & 63;
    w2tb[c * 64 + k] = f2bf(W2[k * 64 + c]);
}

// K4b: MFMA GEMM2 (h2 = x2 @ W2) + layer-2 scores.
// Block = 16 nodes; wave w owns channels 16w..16w+15 (B fragment in regs).
// A layout: A[m=lane&15][k=quad*8+j]; D layout: col=lane&15, row=quad*4+reg.
__global__ void __launch_bounds__(256)
k4b_gemm2(const unsigned short* __restrict__ x2b, const unsigned short* __restrict__ w2tb,
          const float* __restrict__ attS2, const float* __restrict__ attD2,
          unsigned short* __restrict__ h2b, float* __restrict__ a_src2,
          float* __restrict__ a_dst2, int n_nodes) {
    __shared__ float psS[4][16], pdS[4][16];
    const int wave = threadIdx.x >> 6, lane = threadIdx.x & 63;
    const int quad = lane >> 4, l16 = lane & 15;
    const int c = wave * 16 + l16;  // output channel for D col
    // B fragment: B[k=quad*8+j][n=c] == W2T[c][quad*8+j]
    const s8v b0 = *(const s8v*)(w2tb + c * 64 + quad * 8);
    const s8v b1f = *(const s8v*)(w2tb + c * 64 + 32 + quad * 8);
    const float attS_c = attS2[c], attD_c = attD2[c];
    const int base = blockIdx.x * 16;
    int arow = base + l16; if (arow >= n_nodes) arow = n_nodes - 1;
    const s8v a0 = *(const s8v*)(x2b + (size_t)arow * 64 + quad * 8);
    const s8v a1f = *(const s8v*)(x2b + (size_t)arow * 64 + 32 + quad * 8);
    f4v acc = {0.f, 0.f, 0.f, 0.f};
    acc = __builtin_amdgcn_mfma_f32_16x16x32_bf16(a0, b0, acc, 0, 0, 0);
    acc = __builtin_amdgcn_mfma_f32_16x16x32_bf16(a1f, b1f, acc, 0, 0, 0);
    // store h2 + score partials (node = base + quad*4 + r, channel = c)
    float pS[4], pD[4];
#pragma unroll
    for (int r = 0; r < 4; ++r) {
        int node = base + quad * 4 + r;
        if (node < n_nodes) h2b[(size_t)node * 64 + c] = f2bf(acc[r]);
        pS[r] = acc[r] * attS_c;
        pD[r] = acc[r] * attD_c;
    }
    // reduce over the 16 lanes of each quad (xor masks touch only l16 bits)
#pragma unroll
    for (int mask = 1; mask < 16; mask <<= 1) {
#pragma unroll
        for (int r = 0; r < 4; ++r) {
            pS[r] += __shfl_xor(pS[r], mask, 64);
            pD[r] += __shfl_xor(pD[r], mask, 64);
        }
    }
    if (l16 == 0) {
#pragma unroll
        for (int r = 0; r < 4; ++r) {
            psS[wave][quad * 4 + r] = pS[r];
            pdS[wave][quad * 4 + r] = pD[r];
        }
    }
    __syncthreads();
    if (threadIdx.x < 16) {
        int node = base + threadIdx.x;
        if (node < n_nodes) {
            a_src2[node] = psS[0][threadIdx.x] + psS[1][threadIdx.x] +
                           psS[2][threadIdx.x] + psS[3][threadIdx.x];
            a_dst2[node] = pdS[0][threadIdx.x] + pdS[1][threadIdx.x] +
                           pdS[2][threadIdx.x] + pdS[3][threadIdx.x];
        }
    }
}

// ---------------- Layer 2 ----------------

// K8: fused layer-2 softmax-gather + self message + b2 + ELU -> out.
__global__ void __launch_bounds__(256, 4)
k8_agg2(const int* __restrict__ off, const int* __restrict__ csr_src,
        const unsigned short* __restrict__ h2b,
        const float* __restrict__ a_src2, const float* __restrict__ a_dst2,
        const float* __restrict__ b2, float* __restrict__ out, int n_nodes) {
    __shared__ float b2s[64];
    __shared__ int   sS[4][64];
    __shared__ float eS[4][64];
    if (threadIdx.x < 64) b2s[threadIdx.x] = b2[threadIdx.x];
    __syncthreads();
    const int wave = threadIdx.x >> 6, lane = threadIdx.x & 63;
    for (int n = blockIdx.x * 4 + wave; n < n_nodes; n += gridDim.x * 4) {
        int beg = off[n], end = off[n + 1];
        float adn = a_dst2[n];
        float se = expf(leaky02(a_src2[n] + adn));
        float den = se;
        float acc = se * bf2f(h2b[(size_t)n * 64 + lane]);
        for (int base = beg; base < end; base += 64) {
            int m = end - base; if (m > 64) m = 64;
            if (lane < m) {
                int s = csr_src[base + lane];
                sS[wave][lane] = s;
                eS[wave][lane] = expf(leaky02(a_src2[s] + adn));
            }
            int i = 0;
            for (; i + 8 <= m; i += 8) {
                int s0 = sS[wave][i];
                int s1 = sS[wave][i + 1];
                int s2 = sS[wave][i + 2];
                int s3 = sS[wave][i + 3];
                int s4 = sS[wave][i + 4];
                int s5 = sS[wave][i + 5];
                int s6 = sS[wave][i + 6];
                int s7 = sS[wave][i + 7];
                float q0 = bf2f(h2b[(size_t)s0 * 64 + lane]);
                float q1 = bf2f(h2b[(size_t)s1 * 64 + lane]);
                float q2 = bf2f(h2b[(size_t)s2 * 64 + lane]);
                float q3 = bf2f(h2b[(size_t)s3 * 64 + lane]);
                float q4 = bf2f(h2b[(size_t)s4 * 64 + lane]);
                float q5 = bf2f(h2b[(size_t)s5 * 64 + lane]);
                float q6 = bf2f(h2b[(size_t)s6 * 64 + lane]);
                float q7 = bf2f(h2b[(size_t)s7 * 64 + lane]);
                float e0 = eS[wave][i];
                float e1 = eS[wave][i + 1];
                float e2 = eS[wave][i + 2];
                float e3 = eS[wave][i + 3];
                float e4 = eS[wave][i + 4];
                float e5 = eS[wave][i + 5];
                float e6 = eS[wave][i + 6];
                float e7 = eS[wave][i + 7];
                acc += e0 * q0 + e1 * q1 + e2 * q2 + e3 * q3
                     + e4 * q4 + e5 * q5 + e6 * q6 + e7 * q7;
                den += e0 + e1 + e2 + e3 + e4 + e5 + e6 + e7;
            }
            for (; i + 4 <= m; i += 4) {
                int s0 = sS[wave][i];
                int s1 = sS[wave][i + 1];
                int s2 = sS[wave][i + 2];
                int s3 = sS[wave][i + 3];
                float q0 = bf2f(h2b[(size_t)s0 * 64 + lane]);
                float q1 = bf2f(h2b[(size_t)s1 * 64 + lane]);
                float q2 = bf2f(h2b[(size_t)s2 * 64 + lane]);
                float q3 = bf2f(h2b[(size_t)s3 * 64 + lane]);
                float e0 = eS[wave][i];
                float e1 = eS[wave][i + 1];
                float e2 = eS[wave][i + 2];
                float e3 = eS[wave][i + 3];
                acc += e0 * q0 + e1 * q1 + e2 * q2 + e3 * q3;
                den += e0 + e1 + e2 + e3;
            }
            for (; i < m; ++i) {
                int s = sS[wave][i];
                float eh = eS[wave][i];
                acc += eh * bf2f(h2b[(size_t)s * 64 + lane]);
                den += eh;
            }
        }
        out[(size_t)n * 64 + lane] = eluf(acc / (den + 1e-16f) + b2s[lane]);
    }
}

extern "C" void kernel_launch(void* const* d_in, const int* in_sizes, int n_in,
                              void* d_out, int out_size, void* d_ws, size_t ws_size,
                              hipStream_t stream) {
    const float* x   = (const float*)d_in[0];
    const int*   ei  = (const int*)d_in[1];
    const float* W1  = (const float*)d_in[2];
    const float* as1 = (const float*)d_in[3];
    const float* ad1 = (const float*)d_in[4];
    const float* b1  = (const float*)d_in[5];
    const float* W2  = (const float*)d_in[6];
    const float* as2 = (const float*)d_in[7];
    const float* ad2 = (const float*)d_in[8];
    const float* b2  = (const float*)d_in[9];
    float* out = (float*)d_out;

    const int n = in_sizes[0] / 16;   // 50000
    const int e = in_sizes[1] / 2;    // 400000
    const int* src = ei;
    const int* dst = ei + e;
    const int nb = (n + 255) / 256;

    float* ws = (float*)d_ws;
    size_t o = 0;
    unsigned short* h1b = (unsigned short*)(ws + o); o += (size_t)n * 128;  // [N,256] bf16
    float4* csr_ex  = (float4*)(ws + o); o += (size_t)e * 4;
    unsigned short* x2b = (unsigned short*)(ws + o); o += (size_t)n * 32;   // [N,64] bf16
    unsigned short* w2tb = (unsigned short*)(ws + o); o += 2048;            // [64,64] bf16
    float*  a_src1  = ws + o; o += (size_t)n * 4;
    float*  a_dst1  = ws + o; o += (size_t)n * 4;
    unsigned short* h2b = (unsigned short*)(ws + o); o += (size_t)n * 32;   // [N,64] bf16
    float*  a_src2  = ws + o; o += (size_t)n;
    float*  a_dst2  = ws + o; o += (size_t)n;
    int*    csr_src = (int*)(ws + o); o += (size_t)e;
    int*    rank    = (int*)(ws + o); o += (size_t)e;
    int*    deg     = (int*)(ws + o); o += (size_t)n;
    int*    off     = (int*)(ws + o); o += (size_t)(n + 4);
    int*    bsum    = (int*)(ws + o); o += 256;
    int*    bofs    = (int*)(ws + o); o += 256;

    hipMemsetAsync(deg, 0, (size_t)n * sizeof(int), stream);

    // CSR build (structure only)
    k_deg<<<(e + 255) / 256, 256, 0, stream>>>(dst, deg, rank, e);
    k_scan_bsums<<<nb, 256, 0, stream>>>(deg, bsum, n);
    k_scan_bofs<<<1, 256, 0, stream>>>(bsum, bofs, nb);
    k_scan_final<<<nb, 256, 0, stream>>>(deg, bofs, off, n, e);

    // Layer 1
    k1_gemm1<<<(n + 3) / 4, 256, 0, stream>>>(x, W1, as1, ad1, h1b, a_src1, a_dst1, n);
    k3_scatter<<<(e + 255) / 256, 256, 0, stream>>>(src, dst, a_src1, a_dst1, off, rank,
                                                    csr_src, csr_ex, e);
    k4a_agg1<<<(n + 3) / 4, 256, 0, stream>>>(off, csr_src, csr_ex, h1b, a_src1, a_dst1,
                                              b1, x2b, n);
    k_w2t<<<16, 256, 0, stream>>>(W2, w2tb);
    k4b_gemm2<<<(n + 15) / 16, 256, 0, stream>>>(x2b, w2tb, as2, ad2, h2b, a_src2, a_dst2, n);

    // Layer 2
    k8_agg2<<<(n + 3) / 4, 256, 0, stream>>>(off, csr_src, h2b, a_src2, a_dst2, b2, out, n);
}

// Round 12
// 203.826 us; speedup vs baseline: 2.3232x; 1.1106x over previous
//
#include <hip/hip_runtime.h>
#include <math.h>

// ---------------------------------------------------------------------------
// 2-layer GAT encoder. CSR-by-dst gather aggregation (atomic-free).
// Round-12 change:
//  * k1 (46us) was DS-pipe/serial bound (48 shfl/node). Replaced with MFMA:
//    h1 = x @ W1 via mfma_f32_16x16x32_bf16, K=16 zero-padded to 32 (reuses
//    the layout verified by k4b). Wave w == head w, so per-head scores
//    reduce with 4 shfl masks per 16 nodes. W1T/W2T prepped bf16 by k_prep.
// ---------------------------------------------------------------------------

typedef __attribute__((ext_vector_type(8))) short s8v;   // 8 bf16 (4 VGPRs)
typedef __attribute__((ext_vector_type(4))) float f4v;   // 4 fp32 acc

__device__ __forceinline__ float leaky02(float x) { return x > 0.f ? x : 0.2f * x; }
__device__ __forceinline__ float eluf(float x) { return x > 0.f ? x : expm1f(x); }
__device__ __forceinline__ unsigned short f2bf(float f) {
    unsigned u = __float_as_uint(f);
    u += 0x7FFFu + ((u >> 16) & 1u);
    return (unsigned short)(u >> 16);
}
__device__ __forceinline__ float bf2f(unsigned short h) {
    return __uint_as_float((unsigned)h << 16);
}

// ---------------- CSR construction ----------------

__global__ void k_deg(const int* __restrict__ dst, int* __restrict__ deg,
                      int* __restrict__ rank, int e_cnt) {
    int e = blockIdx.x * blockDim.x + threadIdx.x;
    if (e < e_cnt) rank[e] = atomicAdd(&deg[dst[e]], 1);
}

__global__ void k_scan_bsums(const int* __restrict__ deg, int* __restrict__ bsum, int n) {
    __shared__ int part[4];
    int i = blockIdx.x * 256 + threadIdx.x;
    int v = (i < n) ? deg[i] : 0;
    int w = v;
#pragma unroll
    for (int off = 32; off; off >>= 1) w += __shfl_xor(w, off, 64);
    if ((threadIdx.x & 63) == 0) part[threadIdx.x >> 6] = w;
    __syncthreads();
    if (threadIdx.x == 0) bsum[blockIdx.x] = part[0] + part[1] + part[2] + part[3];
}

__global__ void k_scan_bofs(const int* __restrict__ bsum, int* __restrict__ bofs, int nb) {
    __shared__ int s[256];
    int t = threadIdx.x;
    int v = (t < nb) ? bsum[t] : 0;
    s[t] = v;
    __syncthreads();
#pragma unroll
    for (int d = 1; d < 256; d <<= 1) {
        int add = (t >= d) ? s[t - d] : 0;
        __syncthreads();
        s[t] += add;
        __syncthreads();
    }
    bofs[t] = s[t] - v;  // exclusive
}

__global__ void k_scan_final(const int* __restrict__ deg, const int* __restrict__ bofs,
                             int* __restrict__ off, int n, int e_cnt) {
    __shared__ int s[256];
    int t = threadIdx.x;
    int i = blockIdx.x * 256 + t;
    int v = (i < n) ? deg[i] : 0;
    s[t] = v;
    __syncthreads();
#pragma unroll
    for (int d = 1; d < 256; d <<= 1) {
        int add = (t >= d) ? s[t - d] : 0;
        __syncthreads();
        s[t] += add;
        __syncthreads();
    }
    int o = bofs[blockIdx.x] + s[t] - v;
    if (i < n) off[i] = o;
    if (i == 0) off[n] = e_cnt;
}

// Prep: W1T bf16 [256][32] (K zero-padded 16->32), W2T bf16 [64][64].
__global__ void k_prep(const float* __restrict__ W1, const float* __restrict__ W2,
                       unsigned short* __restrict__ w1tb, unsigned short* __restrict__ w2tb) {
    int i = blockIdx.x * 256 + threadIdx.x;
    if (i < 4096) {
        int c = i >> 6, k = i & 63;
        w2tb[c * 64 + k] = f2bf(W2[k * 64 + c]);
    }
    if (i < 8192) {
        int c = i >> 5, k = i & 31;
        w1tb[c * 32 + k] = (k < 16) ? f2bf(W1[k * 256 + c]) : (unsigned short)0;
    }
}

// ---------------- Layer 1 ----------------

// K1m: MFMA GEMM1: h1b[N,256] bf16 + per-head scores a_src1/a_dst1.
// Block = 16 nodes; wave w = head w = channels 64w..64w+63.
// A[m=l16][k=quad*8+j] (zero for k>=16); D: col=l16 (channel), row=quad*4+r.
__global__ void __launch_bounds__(256)
k1m_gemm1(const float* __restrict__ x, const unsigned short* __restrict__ w1tb,
          const float* __restrict__ attS, const float* __restrict__ attD,
          unsigned short* __restrict__ h1b, float* __restrict__ a_src1,
          float* __restrict__ a_dst1, int n_nodes) {
    const int wave = threadIdx.x >> 6, lane = threadIdx.x & 63;
    const int quad = lane >> 4, l16 = lane & 15;
    const int base = blockIdx.x * 16;
    s8v a = {0, 0, 0, 0, 0, 0, 0, 0};
    if (quad < 2) {
        int arow = base + l16; if (arow >= n_nodes) arow = n_nodes - 1;
        const float4* xr = (const float4*)(x + (size_t)arow * 16 + quad * 8);
        float4 x0 = xr[0], x1 = xr[1];
        a[0] = (short)f2bf(x0.x); a[1] = (short)f2bf(x0.y);
        a[2] = (short)f2bf(x0.z); a[3] = (short)f2bf(x0.w);
        a[4] = (short)f2bf(x1.x); a[5] = (short)f2bf(x1.y);
        a[6] = (short)f2bf(x1.z); a[7] = (short)f2bf(x1.w);
    }
    float pS[4] = {0.f, 0.f, 0.f, 0.f}, pD[4] = {0.f, 0.f, 0.f, 0.f};
#pragma unroll
    for (int i = 0; i < 4; ++i) {
        int c = wave * 64 + i * 16 + l16;
        s8v b = *(const s8v*)(w1tb + c * 32 + quad * 8);
        f4v acc = {0.f, 0.f, 0.f, 0.f};
        acc = __builtin_amdgcn_mfma_f32_16x16x32_bf16(a, b, acc, 0, 0, 0);
        float aS = attS[c], aD = attD[c];
#pragma unroll
        for (int r = 0; r < 4; ++r) {
            int node = base + quad * 4 + r;
            if (node < n_nodes) h1b[(size_t)node * 256 + c] = f2bf(acc[r]);
            pS[r] += acc[r] * aS;
            pD[r] += acc[r] * aD;
        }
    }
#pragma unroll
    for (int mask = 1; mask < 16; mask <<= 1) {
#pragma unroll
        for (int r = 0; r < 4; ++r) {
            pS[r] += __shfl_xor(pS[r], mask, 64);
            pD[r] += __shfl_xor(pD[r], mask, 64);
        }
    }
    if (l16 == 0) {
#pragma unroll
        for (int r = 0; r < 4; ++r) {
            int node = base + quad * 4 + r;
            if (node < n_nodes) {
                a_src1[node * 4 + wave] = pS[r];
                a_dst1[node * 4 + wave] = pD[r];
            }
        }
    }
}

// K3: per-edge exp (4 heads) + atomic-free scatter into CSR slot off[d]+rank[e].
__global__ void k3_scatter(const int* __restrict__ src, const int* __restrict__ dst,
                           const float* __restrict__ a_src1, const float* __restrict__ a_dst1,
                           const int* __restrict__ off, const int* __restrict__ rank,
                           int* __restrict__ csr_src, float4* __restrict__ csr_ex, int e_cnt) {
    int e = blockIdx.x * blockDim.x + threadIdx.x;
    if (e >= e_cnt) return;
    int s = src[e], d = dst[e];
    float4 as = *(const float4*)(a_src1 + (size_t)s * 4);
    float4 ad = *(const float4*)(a_dst1 + (size_t)d * 4);
    float4 ex;
    ex.x = expf(leaky02(as.x + ad.x));
    ex.y = expf(leaky02(as.y + ad.y));
    ex.z = expf(leaky02(as.z + ad.z));
    ex.w = expf(leaky02(as.w + ad.w));
    int pos = off[d] + rank[e];
    csr_src[pos] = s;
    csr_ex[pos] = ex;
}

// K4a: layer-1 softmax-gather + head-mean + b1 + ELU -> x2b [N,64] bf16.
__global__ void __launch_bounds__(256, 4)
k4a_agg1(const int* __restrict__ off, const int* __restrict__ csr_src,
         const float4* __restrict__ csr_ex, const unsigned short* __restrict__ h1b,
         const float* __restrict__ a_src1, const float* __restrict__ a_dst1,
         const float* __restrict__ b1, unsigned short* __restrict__ x2b, int n_nodes) {
    __shared__ int   sS[4][16];   // per-wave chunk src ids
    __shared__ float eS[4][64];   // per-wave chunk exp4, [edge*4 + head]
    const int wave = threadIdx.x >> 6, lane = threadIdx.x & 63;
    const int head = lane >> 4;
    const float4 b1v = ((const float4*)b1)[lane & 15];
    for (int n = blockIdx.x * 4 + wave; n < n_nodes; n += gridDim.x * 4) {
        int beg = off[n], end = off[n + 1];
        float4 as = *(const float4*)(a_src1 + (size_t)n * 4);
        float4 ad = *(const float4*)(a_dst1 + (size_t)n * 4);
        float adh = head == 0 ? ad.x : head == 1 ? ad.y : head == 2 ? ad.z : ad.w;
        float ash = head == 0 ? as.x : head == 1 ? as.y : head == 2 ? as.z : as.w;
        float se = expf(leaky02(ash + adh));
        ushort4 qs = ((const ushort4*)(h1b + (size_t)n * 256))[lane];
        float den = se;
        float a0 = se * bf2f(qs.x), a1 = se * bf2f(qs.y);
        float a2 = se * bf2f(qs.z), a3 = se * bf2f(qs.w);
        for (int base = beg; base < end; base += 16) {
            int m = end - base; if (m > 16) m = 16;
            if (lane < m) {
                sS[wave][lane] = csr_src[base + lane];
                ((float4*)eS[wave])[lane] = csr_ex[base + lane];
            }
            int i = 0;
            for (; i + 8 <= m; i += 8) {
                int s0 = sS[wave][i];
                int s1 = sS[wave][i + 1];
                int s2 = sS[wave][i + 2];
                int s3 = sS[wave][i + 3];
                int s4 = sS[wave][i + 4];
                int s5 = sS[wave][i + 5];
                int s6 = sS[wave][i + 6];
                int s7 = sS[wave][i + 7];
                ushort4 q0 = ((const ushort4*)(h1b + (size_t)s0 * 256))[lane];
                ushort4 q1 = ((const ushort4*)(h1b + (size_t)s1 * 256))[lane];
                ushort4 q2 = ((const ushort4*)(h1b + (size_t)s2 * 256))[lane];
                ushort4 q3 = ((const ushort4*)(h1b + (size_t)s3 * 256))[lane];
                ushort4 q4 = ((const ushort4*)(h1b + (size_t)s4 * 256))[lane];
                ushort4 q5 = ((const ushort4*)(h1b + (size_t)s5 * 256))[lane];
                ushort4 q6 = ((const ushort4*)(h1b + (size_t)s6 * 256))[lane];
                ushort4 q7 = ((const ushort4*)(h1b + (size_t)s7 * 256))[lane];
                float e0 = eS[wave][4 * i + head];
                float e1 = eS[wave][4 * (i + 1) + head];
                float e2 = eS[wave][4 * (i + 2) + head];
                float e3 = eS[wave][4 * (i + 3) + head];
                float e4 = eS[wave][4 * (i + 4) + head];
                float e5 = eS[wave][4 * (i + 5) + head];
                float e6 = eS[wave][4 * (i + 6) + head];
                float e7 = eS[wave][4 * (i + 7) + head];
                a0 += e0 * bf2f(q0.x) + e1 * bf2f(q1.x) + e2 * bf2f(q2.x) + e3 * bf2f(q3.x)
                    + e4 * bf2f(q4.x) + e5 * bf2f(q5.x) + e6 * bf2f(q6.x) + e7 * bf2f(q7.x);
                a1 += e0 * bf2f(q0.y) + e1 * bf2f(q1.y) + e2 * bf2f(q2.y) + e3 * bf2f(q3.y)
                    + e4 * bf2f(q4.y) + e5 * bf2f(q5.y) + e6 * bf2f(q6.y) + e7 * bf2f(q7.y);
                a2 += e0 * bf2f(q0.z) + e1 * bf2f(q1.z) + e2 * bf2f(q2.z) + e3 * bf2f(q3.z)
                    + e4 * bf2f(q4.z) + e5 * bf2f(q5.z) + e6 * bf2f(q6.z) + e7 * bf2f(q7.z);
                a3 += e0 * bf2f(q0.w) + e1 * bf2f(q1.w) + e2 * bf2f(q2.w) + e3 * bf2f(q3.w)
                    + e4 * bf2f(q4.w) + e5 * bf2f(q5.w) + e6 * bf2f(q6.w) + e7 * bf2f(q7.w);
                den += e0 + e1 + e2 + e3 + e4 + e5 + e6 + e7;
            }
            for (; i + 4 <= m; i += 4) {
                int s0 = sS[wave][i];
                int s1 = sS[wave][i + 1];
                int s2 = sS[wave][i + 2];
                int s3 = sS[wave][i + 3];
                ushort4 q0 = ((const ushort4*)(h1b + (size_t)s0 * 256))[lane];
                ushort4 q1 = ((const ushort4*)(h1b + (size_t)s1 * 256))[lane];
                ushort4 q2 = ((const ushort4*)(h1b + (size_t)s2 * 256))[lane];
                ushort4 q3 = ((const ushort4*)(h1b + (size_t)s3 * 256))[lane];
                float e0 = eS[wave][4 * i + head];
                float e1 = eS[wave][4 * (i + 1) + head];
                float e2 = eS[wave][4 * (i + 2) + head];
                float e3 = eS[wave][4 * (i + 3) + head];
                a0 += e0 * bf2f(q0.x) + e1 * bf2f(q1.x) + e2 * bf2f(q2.x) + e3 * bf2f(q3.x);
                a1 += e0 * bf2f(q0.y) + e1 * bf2f(q1.y) + e2 * bf2f(q2.y) + e3 * bf2f(q3.y);
                a2 += e0 * bf2f(q0.z) + e1 * bf2f(q1.z) + e2 * bf2f(q2.z) + e3 * bf2f(q3.z);
                a3 += e0 * bf2f(q0.w) + e1 * bf2f(q1.w) + e2 * bf2f(q2.w) + e3 * bf2f(q3.w);
                den += e0 + e1 + e2 + e3;
            }
            for (; i < m; ++i) {
                int s = sS[wave][i];
                float eh = eS[wave][4 * i + head];
                ushort4 q = ((const ushort4*)(h1b + (size_t)s * 256))[lane];
                a0 += eh * bf2f(q.x); a1 += eh * bf2f(q.y);
                a2 += eh * bf2f(q.z); a3 += eh * bf2f(q.w);
                den += eh;
            }
        }
        float inv = 1.f / (den + 1e-16f);
        float t0 = a0 * inv, t1 = a1 * inv, t2 = a2 * inv, t3 = a3 * inv;
        t0 += __shfl_xor(t0, 16, 64); t0 += __shfl_xor(t0, 32, 64);
        t1 += __shfl_xor(t1, 16, 64); t1 += __shfl_xor(t1, 32, 64);
        t2 += __shfl_xor(t2, 16, 64); t2 += __shfl_xor(t2, 32, 64);
        t3 += __shfl_xor(t3, 16, 64); t3 += __shfl_xor(t3, 32, 64);
        if (lane < 16) {
            ushort4 xo;
            xo.x = f2bf(eluf(0.25f * t0 + b1v.x));
            xo.y = f2bf(eluf(0.25f * t1 + b1v.y));
            xo.z = f2bf(eluf(0.25f * t2 + b1v.z));
            xo.w = f2bf(eluf(0.25f * t3 + b1v.w));
            ((ushort4*)(x2b + (size_t)n * 64))[lane] = xo;
        }
    }
}

// K4b: MFMA GEMM2 (h2 = x2 @ W2) + layer-2 scores.
__global__ void __launch_bounds__(256)
k4b_gemm2(const unsigned short* __restrict__ x2b, const unsigned short* __restrict__ w2tb,
          const float* __restrict__ attS2, const float* __restrict__ attD2,
          unsigned short* __restrict__ h2b, float* __restrict__ a_src2,
          float* __restrict__ a_dst2, int n_nodes) {
    __shared__ float psS[4][16], pdS[4][16];
    const int wave = threadIdx.x >> 6, lane = threadIdx.x & 63;
    const int quad = lane >> 4, l16 = lane & 15;
    const int c = wave * 16 + l16;
    const s8v b0 = *(const s8v*)(w2tb + c * 64 + quad * 8);
    const s8v b1f = *(const s8v*)(w2tb + c * 64 + 32 + quad * 8);
    const float attS_c = attS2[c], attD_c = attD2[c];
    const int base = blockIdx.x * 16;
    int arow = base + l16; if (arow >= n_nodes) arow = n_nodes - 1;
    const s8v a0 = *(const s8v*)(x2b + (size_t)arow * 64 + quad * 8);
    const s8v a1f = *(const s8v*)(x2b + (size_t)arow * 64 + 32 + quad * 8);
    f4v acc = {0.f, 0.f, 0.f, 0.f};
    acc = __builtin_amdgcn_mfma_f32_16x16x32_bf16(a0, b0, acc, 0, 0, 0);
    acc = __builtin_amdgcn_mfma_f32_16x16x32_bf16(a1f, b1f, acc, 0, 0, 0);
    float pS[4], pD[4];
#pragma unroll
    for (int r = 0; r < 4; ++r) {
        int node = base + quad * 4 + r;
        if (node < n_nodes) h2b[(size_t)node * 64 + c] = f2bf(acc[r]);
        pS[r] = acc[r] * attS_c;
        pD[r] = acc[r] * attD_c;
    }
#pragma unroll
    for (int mask = 1; mask < 16; mask <<= 1) {
#pragma unroll
        for (int r = 0; r < 4; ++r) {
            pS[r] += __shfl_xor(pS[r], mask, 64);
            pD[r] += __shfl_xor(pD[r], mask, 64);
        }
    }
    if (l16 == 0) {
#pragma unroll
        for (int r = 0; r < 4; ++r) {
            psS[wave][quad * 4 + r] = pS[r];
            pdS[wave][quad * 4 + r] = pD[r];
        }
    }
    __syncthreads();
    if (threadIdx.x < 16) {
        int node = base + threadIdx.x;
        if (node < n_nodes) {
            a_src2[node] = psS[0][threadIdx.x] + psS[1][threadIdx.x] +
                           psS[2][threadIdx.x] + psS[3][threadIdx.x];
            a_dst2[node] = pdS[0][threadIdx.x] + pdS[1][threadIdx.x] +
                           pdS[2][threadIdx.x] + pdS[3][threadIdx.x];
        }
    }
}

// ---------------- Layer 2 ----------------

// K8: fused layer-2 softmax-gather + self message + b2 + ELU -> out.
__global__ void __launch_bounds__(256, 4)
k8_agg2(const int* __restrict__ off, const int* __restrict__ csr_src,
        const unsigned short* __restrict__ h2b,
        const float* __restrict__ a_src2, const float* __restrict__ a_dst2,
        const float* __restrict__ b2, float* __restrict__ out, int n_nodes) {
    __shared__ float b2s[64];
    __shared__ int   sS[4][64];
    __shared__ float eS[4][64];
    if (threadIdx.x < 64) b2s[threadIdx.x] = b2[threadIdx.x];
    __syncthreads();
    const int wave = threadIdx.x >> 6, lane = threadIdx.x & 63;
    for (int n = blockIdx.x * 4 + wave; n < n_nodes; n += gridDim.x * 4) {
        int beg = off[n], end = off[n + 1];
        float adn = a_dst2[n];
        float se = expf(leaky02(a_src2[n] + adn));
        float den = se;
        float acc = se * bf2f(h2b[(size_t)n * 64 + lane]);
        for (int base = beg; base < end; base += 64) {
            int m = end - base; if (m > 64) m = 64;
            if (lane < m) {
                int s = csr_src[base + lane];
                sS[wave][lane] = s;
                eS[wave][lane] = expf(leaky02(a_src2[s] + adn));
            }
            int i = 0;
            for (; i + 8 <= m; i += 8) {
                int s0 = sS[wave][i];
                int s1 = sS[wave][i + 1];
                int s2 = sS[wave][i + 2];
                int s3 = sS[wave][i + 3];
                int s4 = sS[wave][i + 4];
                int s5 = sS[wave][i + 5];
                int s6 = sS[wave][i + 6];
                int s7 = sS[wave][i + 7];
                float q0 = bf2f(h2b[(size_t)s0 * 64 + lane]);
                float q1 = bf2f(h2b[(size_t)s1 * 64 + lane]);
                float q2 = bf2f(h2b[(size_t)s2 * 64 + lane]);
                float q3 = bf2f(h2b[(size_t)s3 * 64 + lane]);
                float q4 = bf2f(h2b[(size_t)s4 * 64 + lane]);
                float q5 = bf2f(h2b[(size_t)s5 * 64 + lane]);
                float q6 = bf2f(h2b[(size_t)s6 * 64 + lane]);
                float q7 = bf2f(h2b[(size_t)s7 * 64 + lane]);
                float e0 = eS[wave][i];
                float e1 = eS[wave][i + 1];
                float e2 = eS[wave][i + 2];
                float e3 = eS[wave][i + 3];
                float e4 = eS[wave][i + 4];
                float e5 = eS[wave][i + 5];
                float e6 = eS[wave][i + 6];
                float e7 = eS[wave][i + 7];
                acc += e0 * q0 + e1 * q1 + e2 * q2 + e3 * q3
                     + e4 * q4 + e5 * q5 + e6 * q6 + e7 * q7;
                den += e0 + e1 + e2 + e3 + e4 + e5 + e6 + e7;
            }
            for (; i + 4 <= m; i += 4) {
                int s0 = sS[wave][i];
                int s1 = sS[wave][i + 1];
                int s2 = sS[wave][i + 2];
                int s3 = sS[wave][i + 3];
                float q0 = bf2f(h2b[(size_t)s0 * 64 + lane]);
                float q1 = bf2f(h2b[(size_t)s1 * 64 + lane]);
                float q2 = bf2f(h2b[(size_t)s2 * 64 + lane]);
                float q3 = bf2f(h2b[(size_t)s3 * 64 + lane]);
                float e0 = eS[wave][i];
                float e1 = eS[wave][i + 1];
                float e2 = eS[wave][i + 2];
                float e3 = eS[wave][i + 3];
                acc += e0 * q0 + e1 * q1 + e2 * q2 + e3 * q3;
                den += e0 + e1 + e2 + e3;
            }
            for (; i < m; ++i) {
                int s = sS[wave][i];
                float eh = eS[wave][i];
                acc += eh * bf2f(h2b[(size_t)s * 64 + lane]);
                den += eh;
            }
        }
        out[(size_t)n * 64 + lane] = eluf(acc / (den + 1e-16f) + b2s[lane]);
    }
}

extern "C" void kernel_launch(void* const* d_in, const int* in_sizes, int n_in,
                              void* d_out, int out_size, void* d_ws, size_t ws_size,
                              hipStream_t stream) {
    const float* x   = (const float*)d_in[0];
    const int*   ei  = (const int*)d_in[1];
    const float* W1  = (const float*)d_in[2];
    const float* as1 = (const float*)d_in[3];
    const float* ad1 = (const float*)d_in[4];
    const float* b1  = (const float*)d_in[5];
    const float* W2  = (const float*)d_in[6];
    const float* as2 = (const float*)d_in[7];
    const float* ad2 = (const float*)d_in[8];
    const float* b2  = (const float*)d_in[9];
    float* out = (float*)d_out;

    const int n = in_sizes[0] / 16;   // 50000
    const int e = in_sizes[1] / 2;    // 400000
    const int* src = ei;
    const int* dst = ei + e;
    const int nb = (n + 255) / 256;

    float* ws = (float*)d_ws;
    size_t o = 0;
    unsigned short* h1b = (unsigned short*)(ws + o); o += (size_t)n * 128;  // [N,256] bf16
    float4* csr_ex  = (float4*)(ws + o); o += (size_t)e * 4;
    unsigned short* x2b = (unsigned short*)(ws + o); o += (size_t)n * 32;   // [N,64] bf16
    unsigned short* w2tb = (unsigned short*)(ws + o); o += 2048;            // [64,64] bf16
    unsigned short* w1tb = (unsigned short*)(ws + o); o += 4096;            // [256,32] bf16
    float*  a_src1  = ws + o; o += (size_t)n * 4;
    float*  a_dst1  = ws + o; o += (size_t)n * 4;
    unsigned short* h2b = (unsigned short*)(ws + o); o += (size_t)n * 32;   // [N,64] bf16
    float*  a_src2  = ws + o; o += (size_t)n;
    float*  a_dst2  = ws + o; o += (size_t)n;
    int*    csr_src = (int*)(ws + o); o += (size_t)e;
    int*    rank    = (int*)(ws + o); o += (size_t)e;
    int*    deg     = (int*)(ws + o); o += (size_t)n;
    int*    off     = (int*)(ws + o); o += (size_t)(n + 4);
    int*    bsum    = (int*)(ws + o); o += 256;
    int*    bofs    = (int*)(ws + o); o += 256;

    hipMemsetAsync(deg, 0, (size_t)n * sizeof(int), stream);

    // Prep + CSR build (structure only)
    k_prep<<<32, 256, 0, stream>>>(W1, W2, w1tb, w2tb);
    k_deg<<<(e + 255) / 256, 256, 0, stream>>>(dst, deg, rank, e);
    k_scan_bsums<<<nb, 256, 0, stream>>>(deg, bsum, n);
    k_scan_bofs<<<1, 256, 0, stream>>>(bsum, bofs, nb);
    k_scan_final<<<nb, 256, 0, stream>>>(deg, bofs, off, n, e);

    // Layer 1
    k1m_gemm1<<<(n + 15) / 16, 256, 0, stream>>>(x, w1tb, as1, ad1, h1b, a_src1, a_dst1, n);
    k3_scatter<<<(e + 255) / 256, 256, 0, stream>>>(src, dst, a_src1, a_dst1, off, rank,
                                                    csr_src, csr_ex, e);
    k4a_agg1<<<(n + 3) / 4, 256, 0, stream>>>(off, csr_src, csr_ex, h1b, a_src1, a_dst1,
                                              b1, x2b, n);
    k4b_gemm2<<<(n + 15) / 16, 256, 0, stream>>>(x2b, w2tb, as2, ad2, h2b, a_src2, a_dst2, n);

    // Layer 2
    k8_agg2<<<(n + 3) / 4, 256, 0, stream>>>(off, csr_src, h2b, a_src2, a_dst2, b2, out, n);
}

// Round 13
// 202.632 us; speedup vs baseline: 2.3369x; 1.0059x over previous
//
#include <hip/hip_runtime.h>
#include <math.h>

// ---------------------------------------------------------------------------
// 2-layer GAT encoder. CSR-by-dst gather aggregation (atomic-free).
// Round-13 changes:
//  * k8 restructured: 4 edge-groups x 16 lanes, lane owns 4 consecutive
//    channels (ushort4 8B gathers, 4x fewer load insts, 16 edges in flight
//    per wave). Group partials merged with shfl_xor(16/32); float4 output.
//  * launch_bounds (256,4) -> (256,6) on k4a/k8: VGPR budget 85 >= the ~64
//    these kernels use, occupancy cap 16 -> 24 waves/CU.
// ---------------------------------------------------------------------------

typedef __attribute__((ext_vector_type(8))) short s8v;   // 8 bf16 (4 VGPRs)
typedef __attribute__((ext_vector_type(4))) float f4v;   // 4 fp32 acc

__device__ __forceinline__ float leaky02(float x) { return x > 0.f ? x : 0.2f * x; }
__device__ __forceinline__ float eluf(float x) { return x > 0.f ? x : expm1f(x); }
__device__ __forceinline__ unsigned short f2bf(float f) {
    unsigned u = __float_as_uint(f);
    u += 0x7FFFu + ((u >> 16) & 1u);
    return (unsigned short)(u >> 16);
}
__device__ __forceinline__ float bf2f(unsigned short h) {
    return __uint_as_float((unsigned)h << 16);
}

// ---------------- CSR construction ----------------

__global__ void k_deg(const int* __restrict__ dst, int* __restrict__ deg,
                      int* __restrict__ rank, int e_cnt) {
    int e = blockIdx.x * blockDim.x + threadIdx.x;
    if (e < e_cnt) rank[e] = atomicAdd(&deg[dst[e]], 1);
}

__global__ void k_scan_bsums(const int* __restrict__ deg, int* __restrict__ bsum, int n) {
    __shared__ int part[4];
    int i = blockIdx.x * 256 + threadIdx.x;
    int v = (i < n) ? deg[i] : 0;
    int w = v;
#pragma unroll
    for (int off = 32; off; off >>= 1) w += __shfl_xor(w, off, 64);
    if ((threadIdx.x & 63) == 0) part[threadIdx.x >> 6] = w;
    __syncthreads();
    if (threadIdx.x == 0) bsum[blockIdx.x] = part[0] + part[1] + part[2] + part[3];
}

__global__ void k_scan_bofs(const int* __restrict__ bsum, int* __restrict__ bofs, int nb) {
    __shared__ int s[256];
    int t = threadIdx.x;
    int v = (t < nb) ? bsum[t] : 0;
    s[t] = v;
    __syncthreads();
#pragma unroll
    for (int d = 1; d < 256; d <<= 1) {
        int add = (t >= d) ? s[t - d] : 0;
        __syncthreads();
        s[t] += add;
        __syncthreads();
    }
    bofs[t] = s[t] - v;  // exclusive
}

__global__ void k_scan_final(const int* __restrict__ deg, const int* __restrict__ bofs,
                             int* __restrict__ off, int n, int e_cnt) {
    __shared__ int s[256];
    int t = threadIdx.x;
    int i = blockIdx.x * 256 + t;
    int v = (i < n) ? deg[i] : 0;
    s[t] = v;
    __syncthreads();
#pragma unroll
    for (int d = 1; d < 256; d <<= 1) {
        int add = (t >= d) ? s[t - d] : 0;
        __syncthreads();
        s[t] += add;
        __syncthreads();
    }
    int o = bofs[blockIdx.x] + s[t] - v;
    if (i < n) off[i] = o;
    if (i == 0) off[n] = e_cnt;
}

// Prep: W1T bf16 [256][32] (K zero-padded 16->32), W2T bf16 [64][64].
__global__ void k_prep(const float* __restrict__ W1, const float* __restrict__ W2,
                       unsigned short* __restrict__ w1tb, unsigned short* __restrict__ w2tb) {
    int i = blockIdx.x * 256 + threadIdx.x;
    if (i < 4096) {
        int c = i >> 6, k = i & 63;
        w2tb[c * 64 + k] = f2bf(W2[k * 64 + c]);
    }
    if (i < 8192) {
        int c = i >> 5, k = i & 31;
        w1tb[c * 32 + k] = (k < 16) ? f2bf(W1[k * 256 + c]) : (unsigned short)0;
    }
}

// ---------------- Layer 1 ----------------

// K1m: MFMA GEMM1: h1b[N,256] bf16 + per-head scores a_src1/a_dst1.
__global__ void __launch_bounds__(256)
k1m_gemm1(const float* __restrict__ x, const unsigned short* __restrict__ w1tb,
          const float* __restrict__ attS, const float* __restrict__ attD,
          unsigned short* __restrict__ h1b, float* __restrict__ a_src1,
          float* __restrict__ a_dst1, int n_nodes) {
    const int wave = threadIdx.x >> 6, lane = threadIdx.x & 63;
    const int quad = lane >> 4, l16 = lane & 15;
    const int base = blockIdx.x * 16;
    s8v a = {0, 0, 0, 0, 0, 0, 0, 0};
    if (quad < 2) {
        int arow = base + l16; if (arow >= n_nodes) arow = n_nodes - 1;
        const float4* xr = (const float4*)(x + (size_t)arow * 16 + quad * 8);
        float4 x0 = xr[0], x1 = xr[1];
        a[0] = (short)f2bf(x0.x); a[1] = (short)f2bf(x0.y);
        a[2] = (short)f2bf(x0.z); a[3] = (short)f2bf(x0.w);
        a[4] = (short)f2bf(x1.x); a[5] = (short)f2bf(x1.y);
        a[6] = (short)f2bf(x1.z); a[7] = (short)f2bf(x1.w);
    }
    float pS[4] = {0.f, 0.f, 0.f, 0.f}, pD[4] = {0.f, 0.f, 0.f, 0.f};
#pragma unroll
    for (int i = 0; i < 4; ++i) {
        int c = wave * 64 + i * 16 + l16;
        s8v b = *(const s8v*)(w1tb + c * 32 + quad * 8);
        f4v acc = {0.f, 0.f, 0.f, 0.f};
        acc = __builtin_amdgcn_mfma_f32_16x16x32_bf16(a, b, acc, 0, 0, 0);
        float aS = attS[c], aD = attD[c];
#pragma unroll
        for (int r = 0; r < 4; ++r) {
            int node = base + quad * 4 + r;
            if (node < n_nodes) h1b[(size_t)node * 256 + c] = f2bf(acc[r]);
            pS[r] += acc[r] * aS;
            pD[r] += acc[r] * aD;
        }
    }
#pragma unroll
    for (int mask = 1; mask < 16; mask <<= 1) {
#pragma unroll
        for (int r = 0; r < 4; ++r) {
            pS[r] += __shfl_xor(pS[r], mask, 64);
            pD[r] += __shfl_xor(pD[r], mask, 64);
        }
    }
    if (l16 == 0) {
#pragma unroll
        for (int r = 0; r < 4; ++r) {
            int node = base + quad * 4 + r;
            if (node < n_nodes) {
                a_src1[node * 4 + wave] = pS[r];
                a_dst1[node * 4 + wave] = pD[r];
            }
        }
    }
}

// K3: per-edge exp (4 heads) + atomic-free scatter into CSR slot off[d]+rank[e].
__global__ void k3_scatter(const int* __restrict__ src, const int* __restrict__ dst,
                           const float* __restrict__ a_src1, const float* __restrict__ a_dst1,
                           const int* __restrict__ off, const int* __restrict__ rank,
                           int* __restrict__ csr_src, float4* __restrict__ csr_ex, int e_cnt) {
    int e = blockIdx.x * blockDim.x + threadIdx.x;
    if (e >= e_cnt) return;
    int s = src[e], d = dst[e];
    float4 as = *(const float4*)(a_src1 + (size_t)s * 4);
    float4 ad = *(const float4*)(a_dst1 + (size_t)d * 4);
    float4 ex;
    ex.x = expf(leaky02(as.x + ad.x));
    ex.y = expf(leaky02(as.y + ad.y));
    ex.z = expf(leaky02(as.z + ad.z));
    ex.w = expf(leaky02(as.w + ad.w));
    int pos = off[d] + rank[e];
    csr_src[pos] = s;
    csr_ex[pos] = ex;
}

// K4a: layer-1 softmax-gather + head-mean + b1 + ELU -> x2b [N,64] bf16.
__global__ void __launch_bounds__(256, 6)
k4a_agg1(const int* __restrict__ off, const int* __restrict__ csr_src,
         const float4* __restrict__ csr_ex, const unsigned short* __restrict__ h1b,
         const float* __restrict__ a_src1, const float* __restrict__ a_dst1,
         const float* __restrict__ b1, unsigned short* __restrict__ x2b, int n_nodes) {
    __shared__ int   sS[4][16];   // per-wave chunk src ids
    __shared__ float eS[4][64];   // per-wave chunk exp4, [edge*4 + head]
    const int wave = threadIdx.x >> 6, lane = threadIdx.x & 63;
    const int head = lane >> 4;
    const float4 b1v = ((const float4*)b1)[lane & 15];
    for (int n = blockIdx.x * 4 + wave; n < n_nodes; n += gridDim.x * 4) {
        int beg = off[n], end = off[n + 1];
        float4 as = *(const float4*)(a_src1 + (size_t)n * 4);
        float4 ad = *(const float4*)(a_dst1 + (size_t)n * 4);
        float adh = head == 0 ? ad.x : head == 1 ? ad.y : head == 2 ? ad.z : ad.w;
        float ash = head == 0 ? as.x : head == 1 ? as.y : head == 2 ? as.z : as.w;
        float se = expf(leaky02(ash + adh));
        ushort4 qs = ((const ushort4*)(h1b + (size_t)n * 256))[lane];
        float den = se;
        float a0 = se * bf2f(qs.x), a1 = se * bf2f(qs.y);
        float a2 = se * bf2f(qs.z), a3 = se * bf2f(qs.w);
        for (int base = beg; base < end; base += 16) {
            int m = end - base; if (m > 16) m = 16;
            if (lane < m) {
                sS[wave][lane] = csr_src[base + lane];
                ((float4*)eS[wave])[lane] = csr_ex[base + lane];
            }
            int i = 0;
            for (; i + 8 <= m; i += 8) {
                int s0 = sS[wave][i];
                int s1 = sS[wave][i + 1];
                int s2 = sS[wave][i + 2];
                int s3 = sS[wave][i + 3];
                int s4 = sS[wave][i + 4];
                int s5 = sS[wave][i + 5];
                int s6 = sS[wave][i + 6];
                int s7 = sS[wave][i + 7];
                ushort4 q0 = ((const ushort4*)(h1b + (size_t)s0 * 256))[lane];
                ushort4 q1 = ((const ushort4*)(h1b + (size_t)s1 * 256))[lane];
                ushort4 q2 = ((const ushort4*)(h1b + (size_t)s2 * 256))[lane];
                ushort4 q3 = ((const ushort4*)(h1b + (size_t)s3 * 256))[lane];
                ushort4 q4 = ((const ushort4*)(h1b + (size_t)s4 * 256))[lane];
                ushort4 q5 = ((const ushort4*)(h1b + (size_t)s5 * 256))[lane];
                ushort4 q6 = ((const ushort4*)(h1b + (size_t)s6 * 256))[lane];
                ushort4 q7 = ((const ushort4*)(h1b + (size_t)s7 * 256))[lane];
                float e0 = eS[wave][4 * i + head];
                float e1 = eS[wave][4 * (i + 1) + head];
                float e2 = eS[wave][4 * (i + 2) + head];
                float e3 = eS[wave][4 * (i + 3) + head];
                float e4 = eS[wave][4 * (i + 4) + head];
                float e5 = eS[wave][4 * (i + 5) + head];
                float e6 = eS[wave][4 * (i + 6) + head];
                float e7 = eS[wave][4 * (i + 7) + head];
                a0 += e0 * bf2f(q0.x) + e1 * bf2f(q1.x) + e2 * bf2f(q2.x) + e3 * bf2f(q3.x)
                    + e4 * bf2f(q4.x) + e5 * bf2f(q5.x) + e6 * bf2f(q6.x) + e7 * bf2f(q7.x);
                a1 += e0 * bf2f(q0.y) + e1 * bf2f(q1.y) + e2 * bf2f(q2.y) + e3 * bf2f(q3.y)
                    + e4 * bf2f(q4.y) + e5 * bf2f(q5.y) + e6 * bf2f(q6.y) + e7 * bf2f(q7.y);
                a2 += e0 * bf2f(q0.z) + e1 * bf2f(q1.z) + e2 * bf2f(q2.z) + e3 * bf2f(q3.z)
                    + e4 * bf2f(q4.z) + e5 * bf2f(q5.z) + e6 * bf2f(q6.z) + e7 * bf2f(q7.z);
                a3 += e0 * bf2f(q0.w) + e1 * bf2f(q1.w) + e2 * bf2f(q2.w) + e3 * bf2f(q3.w)
                    + e4 * bf2f(q4.w) + e5 * bf2f(q5.w) + e6 * bf2f(q6.w) + e7 * bf2f(q7.w);
                den += e0 + e1 + e2 + e3 + e4 + e5 + e6 + e7;
            }
            for (; i + 4 <= m; i += 4) {
                int s0 = sS[wave][i];
                int s1 = sS[wave][i + 1];
                int s2 = sS[wave][i + 2];
                int s3 = sS[wave][i + 3];
                ushort4 q0 = ((const ushort4*)(h1b + (size_t)s0 * 256))[lane];
                ushort4 q1 = ((const ushort4*)(h1b + (size_t)s1 * 256))[lane];
                ushort4 q2 = ((const ushort4*)(h1b + (size_t)s2 * 256))[lane];
                ushort4 q3 = ((const ushort4*)(h1b + (size_t)s3 * 256))[lane];
                float e0 = eS[wave][4 * i + head];
                float e1 = eS[wave][4 * (i + 1) + head];
                float e2 = eS[wave][4 * (i + 2) + head];
                float e3 = eS[wave][4 * (i + 3) + head];
                a0 += e0 * bf2f(q0.x) + e1 * bf2f(q1.x) + e2 * bf2f(q2.x) + e3 * bf2f(q3.x);
                a1 += e0 * bf2f(q0.y) + e1 * bf2f(q1.y) + e2 * bf2f(q2.y) + e3 * bf2f(q3.y);
                a2 += e0 * bf2f(q0.z) + e1 * bf2f(q1.z) + e2 * bf2f(q2.z) + e3 * bf2f(q3.z);
                a3 += e0 * bf2f(q0.w) + e1 * bf2f(q1.w) + e2 * bf2f(q2.w) + e3 * bf2f(q3.w);
                den += e0 + e1 + e2 + e3;
            }
            for (; i < m; ++i) {
                int s = sS[wave][i];
                float eh = eS[wave][4 * i + head];
                ushort4 q = ((const ushort4*)(h1b + (size_t)s * 256))[lane];
                a0 += eh * bf2f(q.x); a1 += eh * bf2f(q.y);
                a2 += eh * bf2f(q.z); a3 += eh * bf2f(q.w);
                den += eh;
            }
        }
        float inv = 1.f / (den + 1e-16f);
        float t0 = a0 * inv, t1 = a1 * inv, t2 = a2 * inv, t3 = a3 * inv;
        t0 += __shfl_xor(t0, 16, 64); t0 += __shfl_xor(t0, 32, 64);
        t1 += __shfl_xor(t1, 16, 64); t1 += __shfl_xor(t1, 32, 64);
        t2 += __shfl_xor(t2, 16, 64); t2 += __shfl_xor(t2, 32, 64);
        t3 += __shfl_xor(t3, 16, 64); t3 += __shfl_xor(t3, 32, 64);
        if (lane < 16) {
            ushort4 xo;
            xo.x = f2bf(eluf(0.25f * t0 + b1v.x));
            xo.y = f2bf(eluf(0.25f * t1 + b1v.y));
            xo.z = f2bf(eluf(0.25f * t2 + b1v.z));
            xo.w = f2bf(eluf(0.25f * t3 + b1v.w));
            ((ushort4*)(x2b + (size_t)n * 64))[lane] = xo;
        }
    }
}

// K4b: MFMA GEMM2 (h2 = x2 @ W2) + layer-2 scores.
__global__ void __launch_bounds__(256)
k4b_gemm2(const unsigned short* __restrict__ x2b, const unsigned short* __restrict__ w2tb,
          const float* __restrict__ attS2, const float* __restrict__ attD2,
          unsigned short* __restrict__ h2b, float* __restrict__ a_src2,
          float* __restrict__ a_dst2, int n_nodes) {
    __shared__ float psS[4][16], pdS[4][16];
    const int wave = threadIdx.x >> 6, lane = threadIdx.x & 63;
    const int quad = lane >> 4, l16 = lane & 15;
    const int c = wave * 16 + l16;
    const s8v b0 = *(const s8v*)(w2tb + c * 64 + quad * 8);
    const s8v b1f = *(const s8v*)(w2tb + c * 64 + 32 + quad * 8);
    const float attS_c = attS2[c], attD_c = attD2[c];
    const int base = blockIdx.x * 16;
    int arow = base + l16; if (arow >= n_nodes) arow = n_nodes - 1;
    const s8v a0 = *(const s8v*)(x2b + (size_t)arow * 64 + quad * 8);
    const s8v a1f = *(const s8v*)(x2b + (size_t)arow * 64 + 32 + quad * 8);
    f4v acc = {0.f, 0.f, 0.f, 0.f};
    acc = __builtin_amdgcn_mfma_f32_16x16x32_bf16(a0, b0, acc, 0, 0, 0);
    acc = __builtin_amdgcn_mfma_f32_16x16x32_bf16(a1f, b1f, acc, 0, 0, 0);
    float pS[4], pD[4];
#pragma unroll
    for (int r = 0; r < 4; ++r) {
        int node = base + quad * 4 + r;
        if (node < n_nodes) h2b[(size_t)node * 64 + c] = f2bf(acc[r]);
        pS[r] = acc[r] * attS_c;
        pD[r] = acc[r] * attD_c;
    }
#pragma unroll
    for (int mask = 1; mask < 16; mask <<= 1) {
#pragma unroll
        for (int r = 0; r < 4; ++r) {
            pS[r] += __shfl_xor(pS[r], mask, 64);
            pD[r] += __shfl_xor(pD[r], mask, 64);
        }
    }
    if (l16 == 0) {
#pragma unroll
        for (int r = 0; r < 4; ++r) {
            psS[wave][quad * 4 + r] = pS[r];
            pdS[wave][quad * 4 + r] = pD[r];
        }
    }
    __syncthreads();
    if (threadIdx.x < 16) {
        int node = base + threadIdx.x;
        if (node < n_nodes) {
            a_src2[node] = psS[0][threadIdx.x] + psS[1][threadIdx.x] +
                           psS[2][threadIdx.x] + psS[3][threadIdx.x];
            a_dst2[node] = pdS[0][threadIdx.x] + pdS[1][threadIdx.x] +
                           pdS[2][threadIdx.x] + pdS[3][threadIdx.x];
        }
    }
}

// ---------------- Layer 2 ----------------

// K8: layer-2 softmax-gather. 4 edge-groups x 16 lanes; lane owns channels
// 4*l16..4*l16+3 of its group's edge (ushort4 8B gathers, 16 edges in
// flight/wave). Group partials merged via shfl_xor(16/32); float4 output.
__global__ void __launch_bounds__(256, 6)
k8_agg2(const int* __restrict__ off, const int* __restrict__ csr_src,
        const unsigned short* __restrict__ h2b,
        const float* __restrict__ a_src2, const float* __restrict__ a_dst2,
        const float* __restrict__ b2, float* __restrict__ out, int n_nodes) {
    __shared__ int   sS[4][64];
    __shared__ float eS[4][64];
    const int wave = threadIdx.x >> 6, lane = threadIdx.x & 63;
    const int g = lane >> 4, l16 = lane & 15;
    const float4 b2v = ((const float4*)b2)[l16];
    for (int n = blockIdx.x * 4 + wave; n < n_nodes; n += gridDim.x * 4) {
        int beg = off[n], end = off[n + 1];
        float adn = a_dst2[n];
        float se = expf(leaky02(a_src2[n] + adn));
        ushort4 qs = ((const ushort4*)(h2b + (size_t)n * 64))[l16];
        float w0 = (g == 0) ? se : 0.f;   // self term only in group 0
        float a0 = w0 * bf2f(qs.x), a1 = w0 * bf2f(qs.y);
        float a2 = w0 * bf2f(qs.z), a3 = w0 * bf2f(qs.w);
        float den = w0;
        for (int base = beg; base < end; base += 64) {
            int m = end - base; if (m > 64) m = 64;
            if (lane < m) {
                int s = csr_src[base + lane];
                sS[wave][lane] = s;
                eS[wave][lane] = expf(leaky02(a_src2[s] + adn));
            }
            int i = g;
            for (; i + 12 < m; i += 16) {
                int s0 = sS[wave][i];
                int s1 = sS[wave][i + 4];
                int s2 = sS[wave][i + 8];
                int s3 = sS[wave][i + 12];
                ushort4 q0 = ((const ushort4*)(h2b + (size_t)s0 * 64))[l16];
                ushort4 q1 = ((const ushort4*)(h2b + (size_t)s1 * 64))[l16];
                ushort4 q2 = ((const ushort4*)(h2b + (size_t)s2 * 64))[l16];
                ushort4 q3 = ((const ushort4*)(h2b + (size_t)s3 * 64))[l16];
                float e0 = eS[wave][i];
                float e1 = eS[wave][i + 4];
                float e2 = eS[wave][i + 8];
                float e3 = eS[wave][i + 12];
                a0 += e0 * bf2f(q0.x) + e1 * bf2f(q1.x) + e2 * bf2f(q2.x) + e3 * bf2f(q3.x);
                a1 += e0 * bf2f(q0.y) + e1 * bf2f(q1.y) + e2 * bf2f(q2.y) + e3 * bf2f(q3.y);
                a2 += e0 * bf2f(q0.z) + e1 * bf2f(q1.z) + e2 * bf2f(q2.z) + e3 * bf2f(q3.z);
                a3 += e0 * bf2f(q0.w) + e1 * bf2f(q1.w) + e2 * bf2f(q2.w) + e3 * bf2f(q3.w);
                den += e0 + e1 + e2 + e3;
            }
            for (; i < m; i += 4) {
                int s = sS[wave][i];
                float eh = eS[wave][i];
                ushort4 q = ((const ushort4*)(h2b + (size_t)s * 64))[l16];
                a0 += eh * bf2f(q.x); a1 += eh * bf2f(q.y);
                a2 += eh * bf2f(q.z); a3 += eh * bf2f(q.w);
                den += eh;
            }
        }
        // merge the 4 groups: lanes {l, l^16, l^32, l^48} share a channel slot
        a0 += __shfl_xor(a0, 16, 64); a0 += __shfl_xor(a0, 32, 64);
        a1 += __shfl_xor(a1, 16, 64); a1 += __shfl_xor(a1, 32, 64);
        a2 += __shfl_xor(a2, 16, 64); a2 += __shfl_xor(a2, 32, 64);
        a3 += __shfl_xor(a3, 16, 64); a3 += __shfl_xor(a3, 32, 64);
        den += __shfl_xor(den, 16, 64); den += __shfl_xor(den, 32, 64);
        if (lane < 16) {
            float inv = 1.f / (den + 1e-16f);
            float4 ov;
            ov.x = eluf(a0 * inv + b2v.x);
            ov.y = eluf(a1 * inv + b2v.y);
            ov.z = eluf(a2 * inv + b2v.z);
            ov.w = eluf(a3 * inv + b2v.w);
            ((float4*)(out + (size_t)n * 64))[l16] = ov;
        }
    }
}

extern "C" void kernel_launch(void* const* d_in, const int* in_sizes, int n_in,
                              void* d_out, int out_size, void* d_ws, size_t ws_size,
                              hipStream_t stream) {
    const float* x   = (const float*)d_in[0];
    const int*   ei  = (const int*)d_in[1];
    const float* W1  = (const float*)d_in[2];
    const float* as1 = (const float*)d_in[3];
    const float* ad1 = (const float*)d_in[4];
    const float* b1  = (const float*)d_in[5];
    const float* W2  = (const float*)d_in[6];
    const float* as2 = (const float*)d_in[7];
    const float* ad2 = (const float*)d_in[8];
    const float* b2  = (const float*)d_in[9];
    float* out = (float*)d_out;

    const int n = in_sizes[0] / 16;   // 50000
    const int e = in_sizes[1] / 2;    // 400000
    const int* src = ei;
    const int* dst = ei + e;
    const int nb = (n + 255) / 256;

    float* ws = (float*)d_ws;
    size_t o = 0;
    unsigned short* h1b = (unsigned short*)(ws + o); o += (size_t)n * 128;  // [N,256] bf16
    float4* csr_ex  = (float4*)(ws + o); o += (size_t)e * 4;
    unsigned short* x2b = (unsigned short*)(ws + o); o += (size_t)n * 32;   // [N,64] bf16
    unsigned short* w2tb = (unsigned short*)(ws + o); o += 2048;            // [64,64] bf16
    unsigned short* w1tb = (unsigned short*)(ws + o); o += 4096;            // [256,32] bf16
    float*  a_src1  = ws + o; o += (size_t)n * 4;
    float*  a_dst1  = ws + o; o += (size_t)n * 4;
    unsigned short* h2b = (unsigned short*)(ws + o); o += (size_t)n * 32;   // [N,64] bf16
    float*  a_src2  = ws + o; o += (size_t)n;
    float*  a_dst2  = ws + o; o += (size_t)n;
    int*    csr_src = (int*)(ws + o); o += (size_t)e;
    int*    rank    = (int*)(ws + o); o += (size_t)e;
    int*    deg     = (int*)(ws + o); o += (size_t)n;
    int*    off     = (int*)(ws + o); o += (size_t)(n + 4);
    int*    bsum    = (int*)(ws + o); o += 256;
    int*    bofs    = (int*)(ws + o); o += 256;

    hipMemsetAsync(deg, 0, (size_t)n * sizeof(int), stream);

    // Prep + CSR build (structure only)
    k_prep<<<32, 256, 0, stream>>>(W1, W2, w1tb, w2tb);
    k_deg<<<(e + 255) / 256, 256, 0, stream>>>(dst, deg, rank, e);
    k_scan_bsums<<<nb, 256, 0, stream>>>(deg, bsum, n);
    k_scan_bofs<<<1, 256, 0, stream>>>(bsum, bofs, nb);
    k_scan_final<<<nb, 256, 0, stream>>>(deg, bofs, off, n, e);

    // Layer 1
    k1m_gemm1<<<(n + 15) / 16, 256, 0, stream>>>(x, w1tb, as1, ad1, h1b, a_src1, a_dst1, n);
    k3_scatter<<<(e + 255) / 256, 256, 0, stream>>>(src, dst, a_src1, a_dst1, off, rank,
                                                    csr_src, csr_ex, e);
    k4a_agg1<<<(n + 3) / 4, 256, 0, stream>>>(off, csr_src, csr_ex, h1b, a_src1, a_dst1,
                                              b1, x2b, n);
    k4b_gemm2<<<(n + 15) / 16, 256, 0, stream>>>(x2b, w2tb, as2, ad2, h2b, a_src2, a_dst2, n);

    // Layer 2
    k8_agg2<<<(n + 3) / 4, 256, 0, stream>>>(off, csr_src, h2b, a_src2, a_dst2, b2, out, n);
}

// Round 14
// 200.660 us; speedup vs baseline: 2.3599x; 1.0098x over previous
//
#include <hip/hip_runtime.h>
#include <math.h>

// ---------------------------------------------------------------------------
// 2-layer GAT encoder. CSR-by-dst gather aggregation (atomic-free).
// Round-14 change (launch-count consolidation; hot kernels unchanged):
//  * k_prep merged into k_deg (blocks 0..31 also build W1T/W2T bf16).
//  * k_scan_bofs merged into k_scan_final (each block computes its own
//    bsum prefix with a 256-wide LDS reduction over nb<=256 entries).
//  11+memset launches -> 9+memset.
// ---------------------------------------------------------------------------

typedef __attribute__((ext_vector_type(8))) short s8v;   // 8 bf16 (4 VGPRs)
typedef __attribute__((ext_vector_type(4))) float f4v;   // 4 fp32 acc

__device__ __forceinline__ float leaky02(float x) { return x > 0.f ? x : 0.2f * x; }
__device__ __forceinline__ float eluf(float x) { return x > 0.f ? x : expm1f(x); }
__device__ __forceinline__ unsigned short f2bf(float f) {
    unsigned u = __float_as_uint(f);
    u += 0x7FFFu + ((u >> 16) & 1u);
    return (unsigned short)(u >> 16);
}
__device__ __forceinline__ float bf2f(unsigned short h) {
    return __uint_as_float((unsigned)h << 16);
}

// ---------------- CSR construction + weight prep ----------------

// deg histogram + per-edge rank; blocks 0..31 additionally prep W1T/W2T bf16.
__global__ void k_deg_prep(const int* __restrict__ dst, int* __restrict__ deg,
                           int* __restrict__ rank, int e_cnt,
                           const float* __restrict__ W1, const float* __restrict__ W2,
                           unsigned short* __restrict__ w1tb, unsigned short* __restrict__ w2tb) {
    int i = blockIdx.x * 256 + threadIdx.x;
    if (i < 4096) {
        int c = i >> 6, k = i & 63;
        w2tb[c * 64 + k] = f2bf(W2[k * 64 + c]);
    }
    if (i < 8192) {
        int c = i >> 5, k = i & 31;
        w1tb[c * 32 + k] = (k < 16) ? f2bf(W1[k * 256 + c]) : (unsigned short)0;
    }
    if (i < e_cnt) rank[i] = atomicAdd(&deg[dst[i]], 1);
}

__global__ void k_scan_bsums(const int* __restrict__ deg, int* __restrict__ bsum, int n) {
    __shared__ int part[4];
    int i = blockIdx.x * 256 + threadIdx.x;
    int v = (i < n) ? deg[i] : 0;
    int w = v;
#pragma unroll
    for (int off = 32; off; off >>= 1) w += __shfl_xor(w, off, 64);
    if ((threadIdx.x & 63) == 0) part[threadIdx.x >> 6] = w;
    __syncthreads();
    if (threadIdx.x == 0) bsum[blockIdx.x] = part[0] + part[1] + part[2] + part[3];
}

// Merged bofs+final: each block computes its own bsum prefix (nb<=256) via
// LDS reduction, then adds its local exclusive scan of deg.
__global__ void k_scan_final(const int* __restrict__ deg, const int* __restrict__ bsum,
                             int* __restrict__ off, int n, int e_cnt, int nb) {
    __shared__ int pre[256];
    __shared__ int s[256];
    int t = threadIdx.x;
    // prefix over block sums: sum of bsum[j] for j < blockIdx.x
    pre[t] = (t < nb && t < (int)blockIdx.x) ? bsum[t] : 0;
    __syncthreads();
#pragma unroll
    for (int d = 128; d; d >>= 1) {
        if (t < d) pre[t] += pre[t + d];
        __syncthreads();
    }
    int bofs = pre[0];
    int i = blockIdx.x * 256 + t;
    int v = (i < n) ? deg[i] : 0;
    s[t] = v;
    __syncthreads();
#pragma unroll
    for (int d = 1; d < 256; d <<= 1) {
        int add = (t >= d) ? s[t - d] : 0;
        __syncthreads();
        s[t] += add;
        __syncthreads();
    }
    int o = bofs + s[t] - v;
    if (i < n) off[i] = o;
    if (i == 0) off[n] = e_cnt;
}

// ---------------- Layer 1 ----------------

// K1m: MFMA GEMM1: h1b[N,256] bf16 + per-head scores a_src1/a_dst1.
__global__ void __launch_bounds__(256)
k1m_gemm1(const float* __restrict__ x, const unsigned short* __restrict__ w1tb,
          const float* __restrict__ attS, const float* __restrict__ attD,
          unsigned short* __restrict__ h1b, float* __restrict__ a_src1,
          float* __restrict__ a_dst1, int n_nodes) {
    const int wave = threadIdx.x >> 6, lane = threadIdx.x & 63;
    const int quad = lane >> 4, l16 = lane & 15;
    const int base = blockIdx.x * 16;
    s8v a = {0, 0, 0, 0, 0, 0, 0, 0};
    if (quad < 2) {
        int arow = base + l16; if (arow >= n_nodes) arow = n_nodes - 1;
        const float4* xr = (const float4*)(x + (size_t)arow * 16 + quad * 8);
        float4 x0 = xr[0], x1 = xr[1];
        a[0] = (short)f2bf(x0.x); a[1] = (short)f2bf(x0.y);
        a[2] = (short)f2bf(x0.z); a[3] = (short)f2bf(x0.w);
        a[4] = (short)f2bf(x1.x); a[5] = (short)f2bf(x1.y);
        a[6] = (short)f2bf(x1.z); a[7] = (short)f2bf(x1.w);
    }
    float pS[4] = {0.f, 0.f, 0.f, 0.f}, pD[4] = {0.f, 0.f, 0.f, 0.f};
#pragma unroll
    for (int i = 0; i < 4; ++i) {
        int c = wave * 64 + i * 16 + l16;
        s8v b = *(const s8v*)(w1tb + c * 32 + quad * 8);
        f4v acc = {0.f, 0.f, 0.f, 0.f};
        acc = __builtin_amdgcn_mfma_f32_16x16x32_bf16(a, b, acc, 0, 0, 0);
        float aS = attS[c], aD = attD[c];
#pragma unroll
        for (int r = 0; r < 4; ++r) {
            int node = base + quad * 4 + r;
            if (node < n_nodes) h1b[(size_t)node * 256 + c] = f2bf(acc[r]);
            pS[r] += acc[r] * aS;
            pD[r] += acc[r] * aD;
        }
    }
#pragma unroll
    for (int mask = 1; mask < 16; mask <<= 1) {
#pragma unroll
        for (int r = 0; r < 4; ++r) {
            pS[r] += __shfl_xor(pS[r], mask, 64);
            pD[r] += __shfl_xor(pD[r], mask, 64);
        }
    }
    if (l16 == 0) {
#pragma unroll
        for (int r = 0; r < 4; ++r) {
            int node = base + quad * 4 + r;
            if (node < n_nodes) {
                a_src1[node * 4 + wave] = pS[r];
                a_dst1[node * 4 + wave] = pD[r];
            }
        }
    }
}

// K3: per-edge exp (4 heads) + atomic-free scatter into CSR slot off[d]+rank[e].
__global__ void k3_scatter(const int* __restrict__ src, const int* __restrict__ dst,
                           const float* __restrict__ a_src1, const float* __restrict__ a_dst1,
                           const int* __restrict__ off, const int* __restrict__ rank,
                           int* __restrict__ csr_src, float4* __restrict__ csr_ex, int e_cnt) {
    int e = blockIdx.x * blockDim.x + threadIdx.x;
    if (e >= e_cnt) return;
    int s = src[e], d = dst[e];
    float4 as = *(const float4*)(a_src1 + (size_t)s * 4);
    float4 ad = *(const float4*)(a_dst1 + (size_t)d * 4);
    float4 ex;
    ex.x = expf(leaky02(as.x + ad.x));
    ex.y = expf(leaky02(as.y + ad.y));
    ex.z = expf(leaky02(as.z + ad.z));
    ex.w = expf(leaky02(as.w + ad.w));
    int pos = off[d] + rank[e];
    csr_src[pos] = s;
    csr_ex[pos] = ex;
}

// K4a: layer-1 softmax-gather + head-mean + b1 + ELU -> x2b [N,64] bf16.
__global__ void __launch_bounds__(256, 6)
k4a_agg1(const int* __restrict__ off, const int* __restrict__ csr_src,
         const float4* __restrict__ csr_ex, const unsigned short* __restrict__ h1b,
         const float* __restrict__ a_src1, const float* __restrict__ a_dst1,
         const float* __restrict__ b1, unsigned short* __restrict__ x2b, int n_nodes) {
    __shared__ int   sS[4][16];   // per-wave chunk src ids
    __shared__ float eS[4][64];   // per-wave chunk exp4, [edge*4 + head]
    const int wave = threadIdx.x >> 6, lane = threadIdx.x & 63;
    const int head = lane >> 4;
    const float4 b1v = ((const float4*)b1)[lane & 15];
    for (int n = blockIdx.x * 4 + wave; n < n_nodes; n += gridDim.x * 4) {
        int beg = off[n], end = off[n + 1];
        float4 as = *(const float4*)(a_src1 + (size_t)n * 4);
        float4 ad = *(const float4*)(a_dst1 + (size_t)n * 4);
        float adh = head == 0 ? ad.x : head == 1 ? ad.y : head == 2 ? ad.z : ad.w;
        float ash = head == 0 ? as.x : head == 1 ? as.y : head == 2 ? as.z : as.w;
        float se = expf(leaky02(ash + adh));
        ushort4 qs = ((const ushort4*)(h1b + (size_t)n * 256))[lane];
        float den = se;
        float a0 = se * bf2f(qs.x), a1 = se * bf2f(qs.y);
        float a2 = se * bf2f(qs.z), a3 = se * bf2f(qs.w);
        for (int base = beg; base < end; base += 16) {
            int m = end - base; if (m > 16) m = 16;
            if (lane < m) {
                sS[wave][lane] = csr_src[base + lane];
                ((float4*)eS[wave])[lane] = csr_ex[base + lane];
            }
            int i = 0;
            for (; i + 8 <= m; i += 8) {
                int s0 = sS[wave][i];
                int s1 = sS[wave][i + 1];
                int s2 = sS[wave][i + 2];
                int s3 = sS[wave][i + 3];
                int s4 = sS[wave][i + 4];
                int s5 = sS[wave][i + 5];
                int s6 = sS[wave][i + 6];
                int s7 = sS[wave][i + 7];
                ushort4 q0 = ((const ushort4*)(h1b + (size_t)s0 * 256))[lane];
                ushort4 q1 = ((const ushort4*)(h1b + (size_t)s1 * 256))[lane];
                ushort4 q2 = ((const ushort4*)(h1b + (size_t)s2 * 256))[lane];
                ushort4 q3 = ((const ushort4*)(h1b + (size_t)s3 * 256))[lane];
                ushort4 q4 = ((const ushort4*)(h1b + (size_t)s4 * 256))[lane];
                ushort4 q5 = ((const ushort4*)(h1b + (size_t)s5 * 256))[lane];
                ushort4 q6 = ((const ushort4*)(h1b + (size_t)s6 * 256))[lane];
                ushort4 q7 = ((const ushort4*)(h1b + (size_t)s7 * 256))[lane];
                float e0 = eS[wave][4 * i + head];
                float e1 = eS[wave][4 * (i + 1) + head];
                float e2 = eS[wave][4 * (i + 2) + head];
                float e3 = eS[wave][4 * (i + 3) + head];
                float e4 = eS[wave][4 * (i + 4) + head];
                float e5 = eS[wave][4 * (i + 5) + head];
                float e6 = eS[wave][4 * (i + 6) + head];
                float e7 = eS[wave][4 * (i + 7) + head];
                a0 += e0 * bf2f(q0.x) + e1 * bf2f(q1.x) + e2 * bf2f(q2.x) + e3 * bf2f(q3.x)
                    + e4 * bf2f(q4.x) + e5 * bf2f(q5.x) + e6 * bf2f(q6.x) + e7 * bf2f(q7.x);
                a1 += e0 * bf2f(q0.y) + e1 * bf2f(q1.y) + e2 * bf2f(q2.y) + e3 * bf2f(q3.y)
                    + e4 * bf2f(q4.y) + e5 * bf2f(q5.y) + e6 * bf2f(q6.y) + e7 * bf2f(q7.y);
                a2 += e0 * bf2f(q0.z) + e1 * bf2f(q1.z) + e2 * bf2f(q2.z) + e3 * bf2f(q3.z)
                    + e4 * bf2f(q4.z) + e5 * bf2f(q5.z) + e6 * bf2f(q6.z) + e7 * bf2f(q7.z);
                a3 += e0 * bf2f(q0.w) + e1 * bf2f(q1.w) + e2 * bf2f(q2.w) + e3 * bf2f(q3.w)
                    + e4 * bf2f(q4.w) + e5 * bf2f(q5.w) + e6 * bf2f(q6.w) + e7 * bf2f(q7.w);
                den += e0 + e1 + e2 + e3 + e4 + e5 + e6 + e7;
            }
            for (; i + 4 <= m; i += 4) {
                int s0 = sS[wave][i];
                int s1 = sS[wave][i + 1];
                int s2 = sS[wave][i + 2];
                int s3 = sS[wave][i + 3];
                ushort4 q0 = ((const ushort4*)(h1b + (size_t)s0 * 256))[lane];
                ushort4 q1 = ((const ushort4*)(h1b + (size_t)s1 * 256))[lane];
                ushort4 q2 = ((const ushort4*)(h1b + (size_t)s2 * 256))[lane];
                ushort4 q3 = ((const ushort4*)(h1b + (size_t)s3 * 256))[lane];
                float e0 = eS[wave][4 * i + head];
                float e1 = eS[wave][4 * (i + 1) + head];
                float e2 = eS[wave][4 * (i + 2) + head];
                float e3 = eS[wave][4 * (i + 3) + head];
                a0 += e0 * bf2f(q0.x) + e1 * bf2f(q1.x) + e2 * bf2f(q2.x) + e3 * bf2f(q3.x);
                a1 += e0 * bf2f(q0.y) + e1 * bf2f(q1.y) + e2 * bf2f(q2.y) + e3 * bf2f(q3.y);
                a2 += e0 * bf2f(q0.z) + e1 * bf2f(q1.z) + e2 * bf2f(q2.z) + e3 * bf2f(q3.z);
                a3 += e0 * bf2f(q0.w) + e1 * bf2f(q1.w) + e2 * bf2f(q2.w) + e3 * bf2f(q3.w);
                den += e0 + e1 + e2 + e3;
            }
            for (; i < m; ++i) {
                int s = sS[wave][i];
                float eh = eS[wave][4 * i + head];
                ushort4 q = ((const ushort4*)(h1b + (size_t)s * 256))[lane];
                a0 += eh * bf2f(q.x); a1 += eh * bf2f(q.y);
                a2 += eh * bf2f(q.z); a3 += eh * bf2f(q.w);
                den += eh;
            }
        }
        float inv = 1.f / (den + 1e-16f);
        float t0 = a0 * inv, t1 = a1 * inv, t2 = a2 * inv, t3 = a3 * inv;
        t0 += __shfl_xor(t0, 16, 64); t0 += __shfl_xor(t0, 32, 64);
        t1 += __shfl_xor(t1, 16, 64); t1 += __shfl_xor(t1, 32, 64);
        t2 += __shfl_xor(t2, 16, 64); t2 += __shfl_xor(t2, 32, 64);
        t3 += __shfl_xor(t3, 16, 64); t3 += __shfl_xor(t3, 32, 64);
        if (lane < 16) {
            ushort4 xo;
            xo.x = f2bf(eluf(0.25f * t0 + b1v.x));
            xo.y = f2bf(eluf(0.25f * t1 + b1v.y));
            xo.z = f2bf(eluf(0.25f * t2 + b1v.z));
            xo.w = f2bf(eluf(0.25f * t3 + b1v.w));
            ((ushort4*)(x2b + (size_t)n * 64))[lane] = xo;
        }
    }
}

// K4b: MFMA GEMM2 (h2 = x2 @ W2) + layer-2 scores.
__global__ void __launch_bounds__(256)
k4b_gemm2(const unsigned short* __restrict__ x2b, const unsigned short* __restrict__ w2tb,
          const float* __restrict__ attS2, const float* __restrict__ attD2,
          unsigned short* __restrict__ h2b, float* __restrict__ a_src2,
          float* __restrict__ a_dst2, int n_nodes) {
    __shared__ float psS[4][16], pdS[4][16];
    const int wave = threadIdx.x >> 6, lane = threadIdx.x & 63;
    const int quad = lane >> 4, l16 = lane & 15;
    const int c = wave * 16 + l16;
    const s8v b0 = *(const s8v*)(w2tb + c * 64 + quad * 8);
    const s8v b1f = *(const s8v*)(w2tb + c * 64 + 32 + quad * 8);
    const float attS_c = attS2[c], attD_c = attD2[c];
    const int base = blockIdx.x * 16;
    int arow = base + l16; if (arow >= n_nodes) arow = n_nodes - 1;
    const s8v a0 = *(const s8v*)(x2b + (size_t)arow * 64 + quad * 8);
    const s8v a1f = *(const s8v*)(x2b + (size_t)arow * 64 + 32 + quad * 8);
    f4v acc = {0.f, 0.f, 0.f, 0.f};
    acc = __builtin_amdgcn_mfma_f32_16x16x32_bf16(a0, b0, acc, 0, 0, 0);
    acc = __builtin_amdgcn_mfma_f32_16x16x32_bf16(a1f, b1f, acc, 0, 0, 0);
    float pS[4], pD[4];
#pragma unroll
    for (int r = 0; r < 4; ++r) {
        int node = base + quad * 4 + r;
        if (node < n_nodes) h2b[(size_t)node * 64 + c] = f2bf(acc[r]);
        pS[r] = acc[r] * attS_c;
        pD[r] = acc[r] * attD_c;
    }
#pragma unroll
    for (int mask = 1; mask < 16; mask <<= 1) {
#pragma unroll
        for (int r = 0; r < 4; ++r) {
            pS[r] += __shfl_xor(pS[r], mask, 64);
            pD[r] += __shfl_xor(pD[r], mask, 64);
        }
    }
    if (l16 == 0) {
#pragma unroll
        for (int r = 0; r < 4; ++r) {
            psS[wave][quad * 4 + r] = pS[r];
            pdS[wave][quad * 4 + r] = pD[r];
        }
    }
    __syncthreads();
    if (threadIdx.x < 16) {
        int node = base + threadIdx.x;
        if (node < n_nodes) {
            a_src2[node] = psS[0][threadIdx.x] + psS[1][threadIdx.x] +
                           psS[2][threadIdx.x] + psS[3][threadIdx.x];
            a_dst2[node] = pdS[0][threadIdx.x] + pdS[1][threadIdx.x] +
                           pdS[2][threadIdx.x] + pdS[3][threadIdx.x];
        }
    }
}

// ---------------- Layer 2 ----------------

// K8: layer-2 softmax-gather, 4 edge-groups x 16 lanes (ushort4 gathers).
__global__ void __launch_bounds__(256, 6)
k8_agg2(const int* __restrict__ off, const int* __restrict__ csr_src,
        const unsigned short* __restrict__ h2b,
        const float* __restrict__ a_src2, const float* __restrict__ a_dst2,
        const float* __restrict__ b2, float* __restrict__ out, int n_nodes) {
    __shared__ int   sS[4][64];
    __shared__ float eS[4][64];
    const int wave = threadIdx.x >> 6, lane = threadIdx.x & 63;
    const int g = lane >> 4, l16 = lane & 15;
    const float4 b2v = ((const float4*)b2)[l16];
    for (int n = blockIdx.x * 4 + wave; n < n_nodes; n += gridDim.x * 4) {
        int beg = off[n], end = off[n + 1];
        float adn = a_dst2[n];
        float se = expf(leaky02(a_src2[n] + adn));
        ushort4 qs = ((const ushort4*)(h2b + (size_t)n * 64))[l16];
        float w0 = (g == 0) ? se : 0.f;   // self term only in group 0
        float a0 = w0 * bf2f(qs.x), a1 = w0 * bf2f(qs.y);
        float a2 = w0 * bf2f(qs.z), a3 = w0 * bf2f(qs.w);
        float den = w0;
        for (int base = beg; base < end; base += 64) {
            int m = end - base; if (m > 64) m = 64;
            if (lane < m) {
                int s = csr_src[base + lane];
                sS[wave][lane] = s;
                eS[wave][lane] = expf(leaky02(a_src2[s] + adn));
            }
            int i = g;
            for (; i + 12 < m; i += 16) {
                int s0 = sS[wave][i];
                int s1 = sS[wave][i + 4];
                int s2 = sS[wave][i + 8];
                int s3 = sS[wave][i + 12];
                ushort4 q0 = ((const ushort4*)(h2b + (size_t)s0 * 64))[l16];
                ushort4 q1 = ((const ushort4*)(h2b + (size_t)s1 * 64))[l16];
                ushort4 q2 = ((const ushort4*)(h2b + (size_t)s2 * 64))[l16];
                ushort4 q3 = ((const ushort4*)(h2b + (size_t)s3 * 64))[l16];
                float e0 = eS[wave][i];
                float e1 = eS[wave][i + 4];
                float e2 = eS[wave][i + 8];
                float e3 = eS[wave][i + 12];
                a0 += e0 * bf2f(q0.x) + e1 * bf2f(q1.x) + e2 * bf2f(q2.x) + e3 * bf2f(q3.x);
                a1 += e0 * bf2f(q0.y) + e1 * bf2f(q1.y) + e2 * bf2f(q2.y) + e3 * bf2f(q3.y);
                a2 += e0 * bf2f(q0.z) + e1 * bf2f(q1.z) + e2 * bf2f(q2.z) + e3 * bf2f(q3.z);
                a3 += e0 * bf2f(q0.w) + e1 * bf2f(q1.w) + e2 * bf2f(q2.w) + e3 * bf2f(q3.w);
                den += e0 + e1 + e2 + e3;
            }
            for (; i < m; i += 4) {
                int s = sS[wave][i];
                float eh = eS[wave][i];
                ushort4 q = ((const ushort4*)(h2b + (size_t)s * 64))[l16];
                a0 += eh * bf2f(q.x); a1 += eh * bf2f(q.y);
                a2 += eh * bf2f(q.z); a3 += eh * bf2f(q.w);
                den += eh;
            }
        }
        a0 += __shfl_xor(a0, 16, 64); a0 += __shfl_xor(a0, 32, 64);
        a1 += __shfl_xor(a1, 16, 64); a1 += __shfl_xor(a1, 32, 64);
        a2 += __shfl_xor(a2, 16, 64); a2 += __shfl_xor(a2, 32, 64);
        a3 += __shfl_xor(a3, 16, 64); a3 += __shfl_xor(a3, 32, 64);
        den += __shfl_xor(den, 16, 64); den += __shfl_xor(den, 32, 64);
        if (lane < 16) {
            float inv = 1.f / (den + 1e-16f);
            float4 ov;
            ov.x = eluf(a0 * inv + b2v.x);
            ov.y = eluf(a1 * inv + b2v.y);
            ov.z = eluf(a2 * inv + b2v.z);
            ov.w = eluf(a3 * inv + b2v.w);
            ((float4*)(out + (size_t)n * 64))[l16] = ov;
        }
    }
}

extern "C" void kernel_launch(void* const* d_in, const int* in_sizes, int n_in,
                              void* d_out, int out_size, void* d_ws, size_t ws_size,
                              hipStream_t stream) {
    const float* x   = (const float*)d_in[0];
    const int*   ei  = (const int*)d_in[1];
    const float* W1  = (const float*)d_in[2];
    const float* as1 = (const float*)d_in[3];
    const float* ad1 = (const float*)d_in[4];
    const float* b1  = (const float*)d_in[5];
    const float* W2  = (const float*)d_in[6];
    const float* as2 = (const float*)d_in[7];
    const float* ad2 = (const float*)d_in[8];
    const float* b2  = (const float*)d_in[9];
    float* out = (float*)d_out;

    const int n = in_sizes[0] / 16;   // 50000
    const int e = in_sizes[1] / 2;    // 400000
    const int* src = ei;
    const int* dst = ei + e;
    const int nb = (n + 255) / 256;   // 196

    float* ws = (float*)d_ws;
    size_t o = 0;
    unsigned short* h1b = (unsigned short*)(ws + o); o += (size_t)n * 128;  // [N,256] bf16
    float4* csr_ex  = (float4*)(ws + o); o += (size_t)e * 4;
    unsigned short* x2b = (unsigned short*)(ws + o); o += (size_t)n * 32;   // [N,64] bf16
    unsigned short* w2tb = (unsigned short*)(ws + o); o += 2048;            // [64,64] bf16
    unsigned short* w1tb = (unsigned short*)(ws + o); o += 4096;            // [256,32] bf16
    float*  a_src1  = ws + o; o += (size_t)n * 4;
    float*  a_dst1  = ws + o; o += (size_t)n * 4;
    unsigned short* h2b = (unsigned short*)(ws + o); o += (size_t)n * 32;   // [N,64] bf16
    float*  a_src2  = ws + o; o += (size_t)n;
    float*  a_dst2  = ws + o; o += (size_t)n;
    int*    csr_src = (int*)(ws + o); o += (size_t)e;
    int*    rank    = (int*)(ws + o); o += (size_t)e;
    int*    deg     = (int*)(ws + o); o += (size_t)n;
    int*    off     = (int*)(ws + o); o += (size_t)(n + 4);
    int*    bsum    = (int*)(ws + o); o += 256;

    hipMemsetAsync(deg, 0, (size_t)n * sizeof(int), stream);

    // CSR build + weight prep (structure only)
    k_deg_prep<<<(e + 255) / 256, 256, 0, stream>>>(dst, deg, rank, e, W1, W2, w1tb, w2tb);
    k_scan_bsums<<<nb, 256, 0, stream>>>(deg, bsum, n);
    k_scan_final<<<nb, 256, 0, stream>>>(deg, bsum, off, n, e, nb);

    // Layer 1
    k1m_gemm1<<<(n + 15) / 16, 256, 0, stream>>>(x, w1tb, as1, ad1, h1b, a_src1, a_dst1, n);
    k3_scatter<<<(e + 255) / 256, 256, 0, stream>>>(src, dst, a_src1, a_dst1, off, rank,
                                                    csr_src, csr_ex, e);
    k4a_agg1<<<(n + 3) / 4, 256, 0, stream>>>(off, csr_src, csr_ex, h1b, a_src1, a_dst1,
                                              b1, x2b, n);
    k4b_gemm2<<<(n + 15) / 16, 256, 0, stream>>>(x2b, w2tb, as2, ad2, h2b, a_src2, a_dst2, n);

    // Layer 2
    k8_agg2<<<(n + 3) / 4, 256, 0, stream>>>(off, csr_src, h2b, a_src2, a_dst2, b2, out, n);
}

// Round 15
// 182.339 us; speedup vs baseline: 2.5970x; 1.1005x over previous
//
#include <hip/hip_runtime.h>
#include <math.h>

// ---------------------------------------------------------------------------
// 2-layer GAT encoder. CSR-by-dst gather aggregation (atomic-free).
// Round-15 change (algebraic restructure of layer 1):
//  * Aggregation commutes with W1: aggregate raw 16-dim x (bf16, 32 B/edge,
//    1.6 MB L2-resident) instead of 512 B h1 rows, then apply W1 once per
//    node. h1b is never materialized. Scores a_src1/a_dst1 = x·(W1@attS_h)
//    via tiny k1s kernel. Post-aggregation: one fused MFMA kernel (k5_mlp)
//    does xagg@Wcat (+b1,ELU) -> LDS -> @W2 (+layer-2 scores).
// ---------------------------------------------------------------------------

typedef __attribute__((ext_vector_type(8))) short s8v;   // 8 bf16 (4 VGPRs)
typedef __attribute__((ext_vector_type(4))) float f4v;   // 4 fp32 acc

__device__ __forceinline__ float leaky02(float x) { return x > 0.f ? x : 0.2f * x; }
__device__ __forceinline__ float eluf(float x) { return x > 0.f ? x : expm1f(x); }
__device__ __forceinline__ unsigned short f2bf(float f) {
    unsigned u = __float_as_uint(f);
    u += 0x7FFFu + ((u >> 16) & 1u);
    return (unsigned short)(u >> 16);
}
__device__ __forceinline__ float bf2f(unsigned short h) {
    return __uint_as_float((unsigned)h << 16);
}

// ---------------- CSR construction + prep ----------------

// deg histogram + per-edge rank; low blocks also cast x->bf16 and build
// WcatT (0.25*W1 reshaped, bf16) and W2T (bf16).
__global__ void k_deg_prep(const int* __restrict__ dst, int* __restrict__ deg,
                           int* __restrict__ rank, int e_cnt,
                           const float* __restrict__ x, const float* __restrict__ W1,
                           const float* __restrict__ W2,
                           unsigned short* __restrict__ xb,
                           unsigned short* __restrict__ w1catT,
                           unsigned short* __restrict__ w2tb, int n16) {
    int i = blockIdx.x * 256 + threadIdx.x;
    if (i < 4096) {
        int c = i >> 6, k = i & 63;
        w2tb[c * 64 + k] = f2bf(W2[k * 64 + c]);
        int r = i & 63;                 // r = h*16 + k2
        int h = r >> 4, k2 = r & 15;
        w1catT[c * 64 + r] = f2bf(0.25f * W1[k2 * 256 + h * 64 + c]);
    }
    if (i < n16) xb[i] = f2bf(x[i]);
    if (i < e_cnt) rank[i] = atomicAdd(&deg[dst[i]], 1);
}

__global__ void k_scan_bsums(const int* __restrict__ deg, int* __restrict__ bsum, int n) {
    __shared__ int part[4];
    int i = blockIdx.x * 256 + threadIdx.x;
    int v = (i < n) ? deg[i] : 0;
    int w = v;
#pragma unroll
    for (int off = 32; off; off >>= 1) w += __shfl_xor(w, off, 64);
    if ((threadIdx.x & 63) == 0) part[threadIdx.x >> 6] = w;
    __syncthreads();
    if (threadIdx.x == 0) bsum[blockIdx.x] = part[0] + part[1] + part[2] + part[3];
}

__global__ void k_scan_final(const int* __restrict__ deg, const int* __restrict__ bsum,
                             int* __restrict__ off, int n, int e_cnt, int nb) {
    __shared__ int pre[256];
    __shared__ int s[256];
    int t = threadIdx.x;
    pre[t] = (t < nb && t < (int)blockIdx.x) ? bsum[t] : 0;
    __syncthreads();
#pragma unroll
    for (int d = 128; d; d >>= 1) {
        if (t < d) pre[t] += pre[t + d];
        __syncthreads();
    }
    int bofs = pre[0];
    int i = blockIdx.x * 256 + t;
    int v = (i < n) ? deg[i] : 0;
    s[t] = v;
    __syncthreads();
#pragma unroll
    for (int d = 1; d < 256; d <<= 1) {
        int add = (t >= d) ? s[t - d] : 0;
        __syncthreads();
        s[t] += add;
        __syncthreads();
    }
    int o = bofs + s[t] - v;
    if (i < n) off[i] = o;
    if (i == 0) off[n] = e_cnt;
}

// ---------------- Layer 1 ----------------

// K1s: per-(node,head) scores: a_src1[n,h] = x[n]·wS_h, wS_h = W1@attS_h.
// wS/wD computed per block (tiny redundant work, removes a dependency).
__global__ void k1s_scores(const float* __restrict__ x, const float* __restrict__ W1,
                           const float* __restrict__ attS, const float* __restrict__ attD,
                           float* __restrict__ a_src1, float* __restrict__ a_dst1,
                           int n_nodes) {
    __shared__ float wS[64], wD[64];
    int t = threadIdx.x;
    if (t < 64) {
        int h = t >> 4, k = t & 15;
        float s = 0.f, d = 0.f;
        for (int c = 0; c < 64; ++c) {
            float w = W1[k * 256 + h * 64 + c];
            s += w * attS[h * 64 + c];
            d += w * attD[h * 64 + c];
        }
        wS[t] = s; wD[t] = d;
    }
    __syncthreads();
    int i = blockIdx.x * 256 + t;     // i = n*4 + h
    if (i >= n_nodes * 4) return;
    int n = i >> 2, h = i & 3;
    const float4* xr = (const float4*)(x + (size_t)n * 16);
    const float* ws = wS + h * 16;
    const float* wd = wD + h * 16;
    float s = 0.f, d = 0.f;
#pragma unroll
    for (int q = 0; q < 4; ++q) {
        float4 xv = xr[q];
        s += xv.x * ws[4 * q] + xv.y * ws[4 * q + 1] + xv.z * ws[4 * q + 2] + xv.w * ws[4 * q + 3];
        d += xv.x * wd[4 * q] + xv.y * wd[4 * q + 1] + xv.z * wd[4 * q + 2] + xv.w * wd[4 * q + 3];
    }
    a_src1[i] = s;
    a_dst1[i] = d;
}

// K3: per-edge exp (4 heads) + atomic-free scatter into CSR slot off[d]+rank[e].
__global__ void k3_scatter(const int* __restrict__ src, const int* __restrict__ dst,
                           const float* __restrict__ a_src1, const float* __restrict__ a_dst1,
                           const int* __restrict__ off, const int* __restrict__ rank,
                           int* __restrict__ csr_src, float4* __restrict__ csr_ex, int e_cnt) {
    int e = blockIdx.x * blockDim.x + threadIdx.x;
    if (e >= e_cnt) return;
    int s = src[e], d = dst[e];
    float4 as = *(const float4*)(a_src1 + (size_t)s * 4);
    float4 ad = *(const float4*)(a_dst1 + (size_t)d * 4);
    float4 ex;
    ex.x = expf(leaky02(as.x + ad.x));
    ex.y = expf(leaky02(as.y + ad.y));
    ex.z = expf(leaky02(as.z + ad.z));
    ex.w = expf(leaky02(as.w + ad.w));
    int pos = off[d] + rank[e];
    csr_src[pos] = s;
    csr_ex[pos] = ex;
}

// K4a: aggregate raw x vectors: xagg[n][h*16+k] = (se*x[n][k] +
// sum_e ex[e][h]*x[src_e][k]) / den[h]. Lane = (head, k). Gather = 2B/lane
// from the 1.6 MB L2-resident xb array.
__global__ void __launch_bounds__(256, 6)
k4a_xagg(const int* __restrict__ off, const int* __restrict__ csr_src,
         const float4* __restrict__ csr_ex, const unsigned short* __restrict__ xb,
         const float* __restrict__ a_src1, const float* __restrict__ a_dst1,
         unsigned short* __restrict__ xaggb, int n_nodes) {
    __shared__ int   sS[4][16];
    __shared__ float eS[4][64];   // [edge*4 + head]
    const int wave = threadIdx.x >> 6, lane = threadIdx.x & 63;
    const int head = lane >> 4, k = lane & 15;
    for (int n = blockIdx.x * 4 + wave; n < n_nodes; n += gridDim.x * 4) {
        int beg = off[n], end = off[n + 1];
        float se = expf(leaky02(a_src1[n * 4 + head] + a_dst1[n * 4 + head]));
        float den = se;
        float agg = se * bf2f(xb[(size_t)n * 16 + k]);
        for (int base = beg; base < end; base += 16) {
            int m = end - base; if (m > 16) m = 16;
            if (lane < m) {
                sS[wave][lane] = csr_src[base + lane];
                ((float4*)eS[wave])[lane] = csr_ex[base + lane];
            }
            int i = 0;
            for (; i + 8 <= m; i += 8) {
                int s0 = sS[wave][i];     float e0 = eS[wave][4 * i + head];
                int s1 = sS[wave][i + 1]; float e1 = eS[wave][4 * (i + 1) + head];
                int s2 = sS[wave][i + 2]; float e2 = eS[wave][4 * (i + 2) + head];
                int s3 = sS[wave][i + 3]; float e3 = eS[wave][4 * (i + 3) + head];
                int s4 = sS[wave][i + 4]; float e4 = eS[wave][4 * (i + 4) + head];
                int s5 = sS[wave][i + 5]; float e5 = eS[wave][4 * (i + 5) + head];
                int s6 = sS[wave][i + 6]; float e6 = eS[wave][4 * (i + 6) + head];
                int s7 = sS[wave][i + 7]; float e7 = eS[wave][4 * (i + 7) + head];
                float v0 = bf2f(xb[(size_t)s0 * 16 + k]);
                float v1 = bf2f(xb[(size_t)s1 * 16 + k]);
                float v2 = bf2f(xb[(size_t)s2 * 16 + k]);
                float v3 = bf2f(xb[(size_t)s3 * 16 + k]);
                float v4 = bf2f(xb[(size_t)s4 * 16 + k]);
                float v5 = bf2f(xb[(size_t)s5 * 16 + k]);
                float v6 = bf2f(xb[(size_t)s6 * 16 + k]);
                float v7 = bf2f(xb[(size_t)s7 * 16 + k]);
                agg += e0 * v0 + e1 * v1 + e2 * v2 + e3 * v3
                     + e4 * v4 + e5 * v5 + e6 * v6 + e7 * v7;
                den += e0 + e1 + e2 + e3 + e4 + e5 + e6 + e7;
            }
            for (; i < m; ++i) {
                int s = sS[wave][i];
                float eh = eS[wave][4 * i + head];
                agg += eh * bf2f(xb[(size_t)s * 16 + k]);
                den += eh;
            }
        }
        xaggb[(size_t)n * 64 + lane] = f2bf(agg / (den + 1e-16f));
    }
}

// K5: fused MLP: x2 = ELU(xagg @ Wcat + b1) (MFMA1) -> LDS ->
//     h2 = x2 @ W2 (MFMA2) + layer-2 scores. Block = 16 nodes.
__global__ void __launch_bounds__(256)
k5_mlp(const unsigned short* __restrict__ xaggb, const unsigned short* __restrict__ w1catT,
       const unsigned short* __restrict__ w2tb, const float* __restrict__ b1,
       const float* __restrict__ attS2, const float* __restrict__ attD2,
       unsigned short* __restrict__ h2b, float* __restrict__ a_src2,
       float* __restrict__ a_dst2, int n_nodes) {
    __shared__ unsigned short x2s[16 * 72];   // stride 72 (16B-aligned rows)
    __shared__ float psS[4][16], pdS[4][16];
    const int wave = threadIdx.x >> 6, lane = threadIdx.x & 63;
    const int quad = lane >> 4, l16 = lane & 15;
    const int c = wave * 16 + l16;
    const int base = blockIdx.x * 16;
    int arow = base + l16; if (arow >= n_nodes) arow = n_nodes - 1;
    // MFMA1: x2pre = xagg @ Wcat  (r = h*16+k ordering matches xaggb layout)
    const s8v a0 = *(const s8v*)(xaggb + (size_t)arow * 64 + quad * 8);
    const s8v a1f = *(const s8v*)(xaggb + (size_t)arow * 64 + 32 + quad * 8);
    const s8v c0 = *(const s8v*)(w1catT + c * 64 + quad * 8);
    const s8v c1 = *(const s8v*)(w1catT + c * 64 + 32 + quad * 8);
    f4v acc = {0.f, 0.f, 0.f, 0.f};
    acc = __builtin_amdgcn_mfma_f32_16x16x32_bf16(a0, c0, acc, 0, 0, 0);
    acc = __builtin_amdgcn_mfma_f32_16x16x32_bf16(a1f, c1, acc, 0, 0, 0);
    float b1c = b1[c];
#pragma unroll
    for (int r = 0; r < 4; ++r)
        x2s[(quad * 4 + r) * 72 + c] = f2bf(eluf(acc[r] + b1c));
    __syncthreads();
    // MFMA2: h2 = x2 @ W2
    const s8v b0 = *(const s8v*)(w2tb + c * 64 + quad * 8);
    const s8v b1v = *(const s8v*)(w2tb + c * 64 + 32 + quad * 8);
    const s8v a2_0 = *(const s8v*)(x2s + l16 * 72 + quad * 8);
    const s8v a2_1 = *(const s8v*)(x2s + l16 * 72 + 32 + quad * 8);
    f4v acc2 = {0.f, 0.f, 0.f, 0.f};
    acc2 = __builtin_amdgcn_mfma_f32_16x16x32_bf16(a2_0, b0, acc2, 0, 0, 0);
    acc2 = __builtin_amdgcn_mfma_f32_16x16x32_bf16(a2_1, b1v, acc2, 0, 0, 0);
    const float attS_c = attS2[c], attD_c = attD2[c];
    float pS[4], pD[4];
#pragma unroll
    for (int r = 0; r < 4; ++r) {
        int node = base + quad * 4 + r;
        if (node < n_nodes) h2b[(size_t)node * 64 + c] = f2bf(acc2[r]);
        pS[r] = acc2[r] * attS_c;
        pD[r] = acc2[r] * attD_c;
    }
#pragma unroll
    for (int mask = 1; mask < 16; mask <<= 1) {
#pragma unroll
        for (int r = 0; r < 4; ++r) {
            pS[r] += __shfl_xor(pS[r], mask, 64);
            pD[r] += __shfl_xor(pD[r], mask, 64);
        }
    }
    if (l16 == 0) {
#pragma unroll
        for (int r = 0; r < 4; ++r) {
            psS[wave][quad * 4 + r] = pS[r];
            pdS[wave][quad * 4 + r] = pD[r];
        }
    }
    __syncthreads();
    if (threadIdx.x < 16) {
        int node = base + threadIdx.x;
        if (node < n_nodes) {
            a_src2[node] = psS[0][threadIdx.x] + psS[1][threadIdx.x] +
                           psS[2][threadIdx.x] + psS[3][threadIdx.x];
            a_dst2[node] = pdS[0][threadIdx.x] + pdS[1][threadIdx.x] +
                           pdS[2][threadIdx.x] + pdS[3][threadIdx.x];
        }
    }
}

// ---------------- Layer 2 ----------------

// K8: layer-2 softmax-gather, 4 edge-groups x 16 lanes (ushort4 gathers).
__global__ void __launch_bounds__(256, 6)
k8_agg2(const int* __restrict__ off, const int* __restrict__ csr_src,
        const unsigned short* __restrict__ h2b,
        const float* __restrict__ a_src2, const float* __restrict__ a_dst2,
        const float* __restrict__ b2, float* __restrict__ out, int n_nodes) {
    __shared__ int   sS[4][64];
    __shared__ float eS[4][64];
    const int wave = threadIdx.x >> 6, lane = threadIdx.x & 63;
    const int g = lane >> 4, l16 = lane & 15;
    const float4 b2v = ((const float4*)b2)[l16];
    for (int n = blockIdx.x * 4 + wave; n < n_nodes; n += gridDim.x * 4) {
        int beg = off[n], end = off[n + 1];
        float adn = a_dst2[n];
        float se = expf(leaky02(a_src2[n] + adn));
        ushort4 qs = ((const ushort4*)(h2b + (size_t)n * 64))[l16];
        float w0 = (g == 0) ? se : 0.f;   // self term only in group 0
        float a0 = w0 * bf2f(qs.x), a1 = w0 * bf2f(qs.y);
        float a2 = w0 * bf2f(qs.z), a3 = w0 * bf2f(qs.w);
        float den = w0;
        for (int base = beg; base < end; base += 64) {
            int m = end - base; if (m > 64) m = 64;
            if (lane < m) {
                int s = csr_src[base + lane];
                sS[wave][lane] = s;
                eS[wave][lane] = expf(leaky02(a_src2[s] + adn));
            }
            int i = g;
            for (; i + 12 < m; i += 16) {
                int s0 = sS[wave][i];
                int s1 = sS[wave][i + 4];
                int s2 = sS[wave][i + 8];
                int s3 = sS[wave][i + 12];
                ushort4 q0 = ((const ushort4*)(h2b + (size_t)s0 * 64))[l16];
                ushort4 q1 = ((const ushort4*)(h2b + (size_t)s1 * 64))[l16];
                ushort4 q2 = ((const ushort4*)(h2b + (size_t)s2 * 64))[l16];
                ushort4 q3 = ((const ushort4*)(h2b + (size_t)s3 * 64))[l16];
                float e0 = eS[wave][i];
                float e1 = eS[wave][i + 4];
                float e2 = eS[wave][i + 8];
                float e3 = eS[wave][i + 12];
                a0 += e0 * bf2f(q0.x) + e1 * bf2f(q1.x) + e2 * bf2f(q2.x) + e3 * bf2f(q3.x);
                a1 += e0 * bf2f(q0.y) + e1 * bf2f(q1.y) + e2 * bf2f(q2.y) + e3 * bf2f(q3.y);
                a2 += e0 * bf2f(q0.z) + e1 * bf2f(q1.z) + e2 * bf2f(q2.z) + e3 * bf2f(q3.z);
                a3 += e0 * bf2f(q0.w) + e1 * bf2f(q1.w) + e2 * bf2f(q2.w) + e3 * bf2f(q3.w);
                den += e0 + e1 + e2 + e3;
            }
            for (; i < m; i += 4) {
                int s = sS[wave][i];
                float eh = eS[wave][i];
                ushort4 q = ((const ushort4*)(h2b + (size_t)s * 64))[l16];
                a0 += eh * bf2f(q.x); a1 += eh * bf2f(q.y);
                a2 += eh * bf2f(q.z); a3 += eh * bf2f(q.w);
                den += eh;
            }
        }
        a0 += __shfl_xor(a0, 16, 64); a0 += __shfl_xor(a0, 32, 64);
        a1 += __shfl_xor(a1, 16, 64); a1 += __shfl_xor(a1, 32, 64);
        a2 += __shfl_xor(a2, 16, 64); a2 += __shfl_xor(a2, 32, 64);
        a3 += __shfl_xor(a3, 16, 64); a3 += __shfl_xor(a3, 32, 64);
        den += __shfl_xor(den, 16, 64); den += __shfl_xor(den, 32, 64);
        if (lane < 16) {
            float inv = 1.f / (den + 1e-16f);
            float4 ov;
            ov.x = eluf(a0 * inv + b2v.x);
            ov.y = eluf(a1 * inv + b2v.y);
            ov.z = eluf(a2 * inv + b2v.z);
            ov.w = eluf(a3 * inv + b2v.w);
            ((float4*)(out + (size_t)n * 64))[l16] = ov;
        }
    }
}

extern "C" void kernel_launch(void* const* d_in, const int* in_sizes, int n_in,
                              void* d_out, int out_size, void* d_ws, size_t ws_size,
                              hipStream_t stream) {
    const float* x   = (const float*)d_in[0];
    const int*   ei  = (const int*)d_in[1];
    const float* W1  = (const float*)d_in[2];
    const float* as1 = (const float*)d_in[3];
    const float* ad1 = (const float*)d_in[4];
    const float* b1  = (const float*)d_in[5];
    const float* W2  = (const float*)d_in[6];
    const float* as2 = (const float*)d_in[7];
    const float* ad2 = (const float*)d_in[8];
    const float* b2  = (const float*)d_in[9];
    float* out = (float*)d_out;

    const int n = in_sizes[0] / 16;   // 50000
    const int e = in_sizes[1] / 2;    // 400000
    const int* src = ei;
    const int* dst = ei + e;
    const int nb = (n + 255) / 256;   // 196

    float* ws = (float*)d_ws;
    size_t o = 0;
    float4* csr_ex  = (float4*)(ws + o); o += (size_t)e * 4;
    unsigned short* xb    = (unsigned short*)(ws + o); o += (size_t)n * 8;   // [N,16] bf16
    unsigned short* xaggb = (unsigned short*)(ws + o); o += (size_t)n * 32;  // [N,64] bf16
    unsigned short* w2tb   = (unsigned short*)(ws + o); o += 2048;           // [64,64] bf16
    unsigned short* w1catT = (unsigned short*)(ws + o); o += 2048;           // [64,64] bf16
    float*  a_src1  = ws + o; o += (size_t)n * 4;
    float*  a_dst1  = ws + o; o += (size_t)n * 4;
    unsigned short* h2b = (unsigned short*)(ws + o); o += (size_t)n * 32;    // [N,64] bf16
    float*  a_src2  = ws + o; o += (size_t)n;
    float*  a_dst2  = ws + o; o += (size_t)n;
    int*    csr_src = (int*)(ws + o); o += (size_t)e;
    int*    rank    = (int*)(ws + o); o += (size_t)e;
    int*    deg     = (int*)(ws + o); o += (size_t)n;
    int*    off     = (int*)(ws + o); o += (size_t)(n + 4);
    int*    bsum    = (int*)(ws + o); o += 256;

    hipMemsetAsync(deg, 0, (size_t)n * sizeof(int), stream);

    // CSR build + prep (covers max(e, n*16) = 800k threads)
    const int prep_threads = (n * 16 > e) ? n * 16 : e;
    k_deg_prep<<<(prep_threads + 255) / 256, 256, 0, stream>>>(
        dst, deg, rank, e, x, W1, W2, xb, w1catT, w2tb, n * 16);
    k1s_scores<<<(n * 4 + 255) / 256, 256, 0, stream>>>(x, W1, as1, ad1, a_src1, a_dst1, n);
    k_scan_bsums<<<nb, 256, 0, stream>>>(deg, bsum, n);
    k_scan_final<<<nb, 256, 0, stream>>>(deg, bsum, off, n, e, nb);

    // Layer 1
    k3_scatter<<<(e + 255) / 256, 256, 0, stream>>>(src, dst, a_src1, a_dst1, off, rank,
                                                    csr_src, csr_ex, e);
    k4a_xagg<<<(n + 3) / 4, 256, 0, stream>>>(off, csr_src, csr_ex, xb, a_src1, a_dst1,
                                              xaggb, n);
    k5_mlp<<<(n + 15) / 16, 256, 0, stream>>>(xaggb, w1catT, w2tb, b1, as2, ad2,
                                              h2b, a_src2, a_dst2, n);

    // Layer 2
    k8_agg2<<<(n + 3) / 4, 256, 0, stream>>>(off, csr_src, h2b, a_src2, a_dst2, b2, out, n);
}

// Round 16
// 176.852 us; speedup vs baseline: 2.6776x; 1.0310x over previous
//
#include <hip/hip_runtime.h>
#include <math.h>

// ---------------------------------------------------------------------------
// 2-layer GAT encoder. CSR-by-dst gather aggregation (atomic-free).
// Round-16 change (chain fusion; inner loops unchanged):
//  * k4a_xagg + k5_mlp fused into k45: block = 16 nodes; phase 1 aggregates
//    raw x per node into an LDS tile (stride-72 rows); phase 2 runs the
//    MFMA MLP (xagg@Wcat +b1,ELU -> @W2 + layer-2 scores) from LDS.
//    xaggb global round-trip eliminated.
//  * k1s_scores folded into k_deg_prep (block-uniform guard).
//  9+memset -> 6+memset launches.
// ---------------------------------------------------------------------------

typedef __attribute__((ext_vector_type(8))) short s8v;   // 8 bf16 (4 VGPRs)
typedef __attribute__((ext_vector_type(4))) float f4v;   // 4 fp32 acc

__device__ __forceinline__ float leaky02(float x) { return x > 0.f ? x : 0.2f * x; }
__device__ __forceinline__ float eluf(float x) { return x > 0.f ? x : expm1f(x); }
__device__ __forceinline__ unsigned short f2bf(float f) {
    unsigned u = __float_as_uint(f);
    u += 0x7FFFu + ((u >> 16) & 1u);
    return (unsigned short)(u >> 16);
}
__device__ __forceinline__ float bf2f(unsigned short h) {
    return __uint_as_float((unsigned)h << 16);
}

// ---------------- CSR construction + prep + layer-1 scores ----------------

__global__ void k_deg_prep(const int* __restrict__ dst, int* __restrict__ deg,
                           int* __restrict__ rank, int e_cnt,
                           const float* __restrict__ x, const float* __restrict__ W1,
                           const float* __restrict__ W2,
                           const float* __restrict__ attS, const float* __restrict__ attD,
                           unsigned short* __restrict__ xb,
                           unsigned short* __restrict__ w1catT,
                           unsigned short* __restrict__ w2tb,
                           float* __restrict__ a_src1, float* __restrict__ a_dst1,
                           int n16, int n4) {
    __shared__ float wS[64], wD[64];
    int t = threadIdx.x;
    int i = blockIdx.x * 256 + t;
    if (i < 4096) {
        int c = i >> 6, k = i & 63;
        w2tb[c * 64 + k] = f2bf(W2[k * 64 + c]);
        int r = i & 63;                 // r = h*16 + k2
        int h = r >> 4, k2 = r & 15;
        w1catT[c * 64 + r] = f2bf(0.25f * W1[k2 * 256 + h * 64 + c]);
    }
    if (i < n16) xb[i] = f2bf(x[i]);
    if (i < e_cnt) rank[i] = atomicAdd(&deg[dst[i]], 1);
    // layer-1 scores (block-uniform guard so __syncthreads is safe)
    if ((int)blockIdx.x * 256 < n4) {
        if (t < 64) {
            int h = t >> 4, k = t & 15;
            float s = 0.f, d = 0.f;
            for (int c = 0; c < 64; ++c) {
                float w = W1[k * 256 + h * 64 + c];
                s += w * attS[h * 64 + c];
                d += w * attD[h * 64 + c];
            }
            wS[t] = s; wD[t] = d;
        }
        __syncthreads();
        if (i < n4) {
            int n = i >> 2, h = i & 3;
            const float4* xr = (const float4*)(x + (size_t)n * 16);
            const float* ws = wS + h * 16;
            const float* wd = wD + h * 16;
            float s = 0.f, d = 0.f;
#pragma unroll
            for (int q = 0; q < 4; ++q) {
                float4 xv = xr[q];
                s += xv.x * ws[4 * q] + xv.y * ws[4 * q + 1] + xv.z * ws[4 * q + 2] + xv.w * ws[4 * q + 3];
                d += xv.x * wd[4 * q] + xv.y * wd[4 * q + 1] + xv.z * wd[4 * q + 2] + xv.w * wd[4 * q + 3];
            }
            a_src1[i] = s;
            a_dst1[i] = d;
        }
    }
}

__global__ void k_scan_bsums(const int* __restrict__ deg, int* __restrict__ bsum, int n) {
    __shared__ int part[4];
    int i = blockIdx.x * 256 + threadIdx.x;
    int v = (i < n) ? deg[i] : 0;
    int w = v;
#pragma unroll
    for (int off = 32; off; off >>= 1) w += __shfl_xor(w, off, 64);
    if ((threadIdx.x & 63) == 0) part[threadIdx.x >> 6] = w;
    __syncthreads();
    if (threadIdx.x == 0) bsum[blockIdx.x] = part[0] + part[1] + part[2] + part[3];
}

__global__ void k_scan_final(const int* __restrict__ deg, const int* __restrict__ bsum,
                             int* __restrict__ off, int n, int e_cnt, int nb) {
    __shared__ int pre[256];
    __shared__ int s[256];
    int t = threadIdx.x;
    pre[t] = (t < nb && t < (int)blockIdx.x) ? bsum[t] : 0;
    __syncthreads();
#pragma unroll
    for (int d = 128; d; d >>= 1) {
        if (t < d) pre[t] += pre[t + d];
        __syncthreads();
    }
    int bofs = pre[0];
    int i = blockIdx.x * 256 + t;
    int v = (i < n) ? deg[i] : 0;
    s[t] = v;
    __syncthreads();
#pragma unroll
    for (int d = 1; d < 256; d <<= 1) {
        int add = (t >= d) ? s[t - d] : 0;
        __syncthreads();
        s[t] += add;
        __syncthreads();
    }
    int o = bofs + s[t] - v;
    if (i < n) off[i] = o;
    if (i == 0) off[n] = e_cnt;
}

// K3: per-edge exp (4 heads) + atomic-free scatter into CSR slot off[d]+rank[e].
__global__ void k3_scatter(const int* __restrict__ src, const int* __restrict__ dst,
                           const float* __restrict__ a_src1, const float* __restrict__ a_dst1,
                           const int* __restrict__ off, const int* __restrict__ rank,
                           int* __restrict__ csr_src, float4* __restrict__ csr_ex, int e_cnt) {
    int e = blockIdx.x * blockDim.x + threadIdx.x;
    if (e >= e_cnt) return;
    int s = src[e], d = dst[e];
    float4 as = *(const float4*)(a_src1 + (size_t)s * 4);
    float4 ad = *(const float4*)(a_dst1 + (size_t)d * 4);
    float4 ex;
    ex.x = expf(leaky02(as.x + ad.x));
    ex.y = expf(leaky02(as.y + ad.y));
    ex.z = expf(leaky02(as.z + ad.z));
    ex.w = expf(leaky02(as.w + ad.w));
    int pos = off[d] + rank[e];
    csr_src[pos] = s;
    csr_ex[pos] = ex;
}

// K45: fused layer-1 aggregation + MLP. Block = 16 nodes.
// Phase 1: wave w aggregates nodes base+4w..base+4w+3 (lane = head*16+k)
//          into LDS tile xaggS (stride-72 rows, bf16).
// Phase 2: MFMA1 (xagg@Wcat +b1, ELU) -> x2s LDS -> MFMA2 (@W2) + scores.
__global__ void __launch_bounds__(256)
k45_agg_mlp(const int* __restrict__ off, const int* __restrict__ csr_src,
            const float4* __restrict__ csr_ex, const unsigned short* __restrict__ xb,
            const float* __restrict__ a_src1, const float* __restrict__ a_dst1,
            const unsigned short* __restrict__ w1catT, const unsigned short* __restrict__ w2tb,
            const float* __restrict__ b1, const float* __restrict__ attS2,
            const float* __restrict__ attD2, unsigned short* __restrict__ h2b,
            float* __restrict__ a_src2, float* __restrict__ a_dst2, int n_nodes) {
    __shared__ unsigned short xaggS[16 * 72];
    __shared__ unsigned short x2s[16 * 72];
    __shared__ int   sS[4][16];
    __shared__ float eS[4][64];   // [edge*4 + head]
    __shared__ float psS[4][16], pdS[4][16];
    const int wave = threadIdx.x >> 6, lane = threadIdx.x & 63;
    const int head = lane >> 4, k = lane & 15;
    const int base = blockIdx.x * 16;
    // ---- phase 1: aggregate raw x for 4 nodes per wave ----
#pragma unroll 1
    for (int r = 0; r < 4; ++r) {
        int n = base + wave * 4 + r;
        float agg = 0.f, den = 1e-16f;
        if (n < n_nodes) {
            int beg = off[n], end = off[n + 1];
            float se = expf(leaky02(a_src1[n * 4 + head] + a_dst1[n * 4 + head]));
            den += se;
            agg = se * bf2f(xb[(size_t)n * 16 + k]);
            for (int cb = beg; cb < end; cb += 16) {
                int m = end - cb; if (m > 16) m = 16;
                if (lane < m) {
                    sS[wave][lane] = csr_src[cb + lane];
                    ((float4*)eS[wave])[lane] = csr_ex[cb + lane];
                }
                int i = 0;
                for (; i + 8 <= m; i += 8) {
                    int s0 = sS[wave][i];     float e0 = eS[wave][4 * i + head];
                    int s1 = sS[wave][i + 1]; float e1 = eS[wave][4 * (i + 1) + head];
                    int s2 = sS[wave][i + 2]; float e2 = eS[wave][4 * (i + 2) + head];
                    int s3 = sS[wave][i + 3]; float e3 = eS[wave][4 * (i + 3) + head];
                    int s4 = sS[wave][i + 4]; float e4 = eS[wave][4 * (i + 4) + head];
                    int s5 = sS[wave][i + 5]; float e5 = eS[wave][4 * (i + 5) + head];
                    int s6 = sS[wave][i + 6]; float e6 = eS[wave][4 * (i + 6) + head];
                    int s7 = sS[wave][i + 7]; float e7 = eS[wave][4 * (i + 7) + head];
                    float v0 = bf2f(xb[(size_t)s0 * 16 + k]);
                    float v1 = bf2f(xb[(size_t)s1 * 16 + k]);
                    float v2 = bf2f(xb[(size_t)s2 * 16 + k]);
                    float v3 = bf2f(xb[(size_t)s3 * 16 + k]);
                    float v4 = bf2f(xb[(size_t)s4 * 16 + k]);
                    float v5 = bf2f(xb[(size_t)s5 * 16 + k]);
                    float v6 = bf2f(xb[(size_t)s6 * 16 + k]);
                    float v7 = bf2f(xb[(size_t)s7 * 16 + k]);
                    agg += e0 * v0 + e1 * v1 + e2 * v2 + e3 * v3
                         + e4 * v4 + e5 * v5 + e6 * v6 + e7 * v7;
                    den += e0 + e1 + e2 + e3 + e4 + e5 + e6 + e7;
                }
                for (; i < m; ++i) {
                    int s = sS[wave][i];
                    float eh = eS[wave][4 * i + head];
                    agg += eh * bf2f(xb[(size_t)s * 16 + k]);
                    den += eh;
                }
            }
        }
        xaggS[(wave * 4 + r) * 72 + lane] = f2bf(agg / den);
    }
    __syncthreads();
    // ---- phase 2: MFMA MLP ----
    const int quad = lane >> 4, l16 = lane & 15;
    const int c = wave * 16 + l16;
    const s8v a0 = *(const s8v*)(xaggS + l16 * 72 + quad * 8);
    const s8v a1f = *(const s8v*)(xaggS + l16 * 72 + 32 + quad * 8);
    const s8v c0 = *(const s8v*)(w1catT + c * 64 + quad * 8);
    const s8v c1 = *(const s8v*)(w1catT + c * 64 + 32 + quad * 8);
    f4v acc = {0.f, 0.f, 0.f, 0.f};
    acc = __builtin_amdgcn_mfma_f32_16x16x32_bf16(a0, c0, acc, 0, 0, 0);
    acc = __builtin_amdgcn_mfma_f32_16x16x32_bf16(a1f, c1, acc, 0, 0, 0);
    float b1c = b1[c];
#pragma unroll
    for (int r = 0; r < 4; ++r)
        x2s[(quad * 4 + r) * 72 + c] = f2bf(eluf(acc[r] + b1c));
    __syncthreads();
    const s8v b0 = *(const s8v*)(w2tb + c * 64 + quad * 8);
    const s8v b1v = *(const s8v*)(w2tb + c * 64 + 32 + quad * 8);
    const s8v a2_0 = *(const s8v*)(x2s + l16 * 72 + quad * 8);
    const s8v a2_1 = *(const s8v*)(x2s + l16 * 72 + 32 + quad * 8);
    f4v acc2 = {0.f, 0.f, 0.f, 0.f};
    acc2 = __builtin_amdgcn_mfma_f32_16x16x32_bf16(a2_0, b0, acc2, 0, 0, 0);
    acc2 = __builtin_amdgcn_mfma_f32_16x16x32_bf16(a2_1, b1v, acc2, 0, 0, 0);
    const float attS_c = attS2[c], attD_c = attD2[c];
    float pS[4], pD[4];
#pragma unroll
    for (int r = 0; r < 4; ++r) {
        int node = base + quad * 4 + r;
        if (node < n_nodes) h2b[(size_t)node * 64 + c] = f2bf(acc2[r]);
        pS[r] = acc2[r] * attS_c;
        pD[r] = acc2[r] * attD_c;
    }
#pragma unroll
    for (int mask = 1; mask < 16; mask <<= 1) {
#pragma unroll
        for (int r = 0; r < 4; ++r) {
            pS[r] += __shfl_xor(pS[r], mask, 64);
            pD[r] += __shfl_xor(pD[r], mask, 64);
        }
    }
    if (l16 == 0) {
#pragma unroll
        for (int r = 0; r < 4; ++r) {
            psS[wave][quad * 4 + r] = pS[r];
            pdS[wave][quad * 4 + r] = pD[r];
        }
    }
    __syncthreads();
    if (threadIdx.x < 16) {
        int node = base + threadIdx.x;
        if (node < n_nodes) {
            a_src2[node] = psS[0][threadIdx.x] + psS[1][threadIdx.x] +
                           psS[2][threadIdx.x] + psS[3][threadIdx.x];
            a_dst2[node] = pdS[0][threadIdx.x] + pdS[1][threadIdx.x] +
                           pdS[2][threadIdx.x] + pdS[3][threadIdx.x];
        }
    }
}

// ---------------- Layer 2 ----------------

// K8: layer-2 softmax-gather, 4 edge-groups x 16 lanes (ushort4 gathers).
__global__ void __launch_bounds__(256, 6)
k8_agg2(const int* __restrict__ off, const int* __restrict__ csr_src,
        const unsigned short* __restrict__ h2b,
        const float* __restrict__ a_src2, const float* __restrict__ a_dst2,
        const float* __restrict__ b2, float* __restrict__ out, int n_nodes) {
    __shared__ int   sS[4][64];
    __shared__ float eS[4][64];
    const int wave = threadIdx.x >> 6, lane = threadIdx.x & 63;
    const int g = lane >> 4, l16 = lane & 15;
    const float4 b2v = ((const float4*)b2)[l16];
    for (int n = blockIdx.x * 4 + wave; n < n_nodes; n += gridDim.x * 4) {
        int beg = off[n], end = off[n + 1];
        float adn = a_dst2[n];
        float se = expf(leaky02(a_src2[n] + adn));
        ushort4 qs = ((const ushort4*)(h2b + (size_t)n * 64))[l16];
        float w0 = (g == 0) ? se : 0.f;   // self term only in group 0
        float a0 = w0 * bf2f(qs.x), a1 = w0 * bf2f(qs.y);
        float a2 = w0 * bf2f(qs.z), a3 = w0 * bf2f(qs.w);
        float den = w0;
        for (int base = beg; base < end; base += 64) {
            int m = end - base; if (m > 64) m = 64;
            if (lane < m) {
                int s = csr_src[base + lane];
                sS[wave][lane] = s;
                eS[wave][lane] = expf(leaky02(a_src2[s] + adn));
            }
            int i = g;
            for (; i + 12 < m; i += 16) {
                int s0 = sS[wave][i];
                int s1 = sS[wave][i + 4];
                int s2 = sS[wave][i + 8];
                int s3 = sS[wave][i + 12];
                ushort4 q0 = ((const ushort4*)(h2b + (size_t)s0 * 64))[l16];
                ushort4 q1 = ((const ushort4*)(h2b + (size_t)s1 * 64))[l16];
                ushort4 q2 = ((const ushort4*)(h2b + (size_t)s2 * 64))[l16];
                ushort4 q3 = ((const ushort4*)(h2b + (size_t)s3 * 64))[l16];
                float e0 = eS[wave][i];
                float e1 = eS[wave][i + 4];
                float e2 = eS[wave][i + 8];
                float e3 = eS[wave][i + 12];
                a0 += e0 * bf2f(q0.x) + e1 * bf2f(q1.x) + e2 * bf2f(q2.x) + e3 * bf2f(q3.x);
                a1 += e0 * bf2f(q0.y) + e1 * bf2f(q1.y) + e2 * bf2f(q2.y) + e3 * bf2f(q3.y);
                a2 += e0 * bf2f(q0.z) + e1 * bf2f(q1.z) + e2 * bf2f(q2.z) + e3 * bf2f(q3.z);
                a3 += e0 * bf2f(q0.w) + e1 * bf2f(q1.w) + e2 * bf2f(q2.w) + e3 * bf2f(q3.w);
                den += e0 + e1 + e2 + e3;
            }
            for (; i < m; i += 4) {
                int s = sS[wave][i];
                float eh = eS[wave][i];
                ushort4 q = ((const ushort4*)(h2b + (size_t)s * 64))[l16];
                a0 += eh * bf2f(q.x); a1 += eh * bf2f(q.y);
                a2 += eh * bf2f(q.z); a3 += eh * bf2f(q.w);
                den += eh;
            }
        }
        a0 += __shfl_xor(a0, 16, 64); a0 += __shfl_xor(a0, 32, 64);
        a1 += __shfl_xor(a1, 16, 64); a1 += __shfl_xor(a1, 32, 64);
        a2 += __shfl_xor(a2, 16, 64); a2 += __shfl_xor(a2, 32, 64);
        a3 += __shfl_xor(a3, 16, 64); a3 += __shfl_xor(a3, 32, 64);
        den += __shfl_xor(den, 16, 64); den += __shfl_xor(den, 32, 64);
        if (lane < 16) {
            float inv = 1.f / (den + 1e-16f);
            float4 ov;
            ov.x = eluf(a0 * inv + b2v.x);
            ov.y = eluf(a1 * inv + b2v.y);
            ov.z = eluf(a2 * inv + b2v.z);
            ov.w = eluf(a3 * inv + b2v.w);
            ((float4*)(out + (size_t)n * 64))[l16] = ov;
        }
    }
}

extern "C" void kernel_launch(void* const* d_in, const int* in_sizes, int n_in,
                              void* d_out, int out_size, void* d_ws, size_t ws_size,
                              hipStream_t stream) {
    const float* x   = (const float*)d_in[0];
    const int*   ei  = (const int*)d_in[1];
    const float* W1  = (const float*)d_in[2];
    const float* as1 = (const float*)d_in[3];
    const float* ad1 = (const float*)d_in[4];
    const float* b1  = (const float*)d_in[5];
    const float* W2  = (const float*)d_in[6];
    const float* as2 = (const float*)d_in[7];
    const float* ad2 = (const float*)d_in[8];
    const float* b2  = (const float*)d_in[9];
    float* out = (float*)d_out;

    const int n = in_sizes[0] / 16;   // 50000
    const int e = in_sizes[1] / 2;    // 400000
    const int* src = ei;
    const int* dst = ei + e;
    const int nb = (n + 255) / 256;   // 196

    float* ws = (float*)d_ws;
    size_t o = 0;
    float4* csr_ex  = (float4*)(ws + o); o += (size_t)e * 4;
    unsigned short* xb    = (unsigned short*)(ws + o); o += (size_t)n * 8;   // [N,16] bf16
    unsigned short* w2tb   = (unsigned short*)(ws + o); o += 2048;           // [64,64] bf16
    unsigned short* w1catT = (unsigned short*)(ws + o); o += 2048;           // [64,64] bf16
    float*  a_src1  = ws + o; o += (size_t)n * 4;
    float*  a_dst1  = ws + o; o += (size_t)n * 4;
    unsigned short* h2b = (unsigned short*)(ws + o); o += (size_t)n * 32;    // [N,64] bf16
    float*  a_src2  = ws + o; o += (size_t)n;
    float*  a_dst2  = ws + o; o += (size_t)n;
    int*    csr_src = (int*)(ws + o); o += (size_t)e;
    int*    rank    = (int*)(ws + o); o += (size_t)e;
    int*    deg     = (int*)(ws + o); o += (size_t)n;
    int*    off     = (int*)(ws + o); o += (size_t)(n + 4);
    int*    bsum    = (int*)(ws + o); o += 256;

    hipMemsetAsync(deg, 0, (size_t)n * sizeof(int), stream);

    // CSR build + prep + layer-1 scores (covers max(e, n*16) = 800k threads)
    const int prep_threads = (n * 16 > e) ? n * 16 : e;
    k_deg_prep<<<(prep_threads + 255) / 256, 256, 0, stream>>>(
        dst, deg, rank, e, x, W1, W2, as1, ad1, xb, w1catT, w2tb,
        a_src1, a_dst1, n * 16, n * 4);
    k_scan_bsums<<<nb, 256, 0, stream>>>(deg, bsum, n);
    k_scan_final<<<nb, 256, 0, stream>>>(deg, bsum, off, n, e, nb);

    // Layer 1 (+ fused MLP producing layer-2 inputs)
    k3_scatter<<<(e + 255) / 256, 256, 0, stream>>>(src, dst, a_src1, a_dst1, off, rank,
                                                    csr_src, csr_ex, e);
    k45_agg_mlp<<<(n + 15) / 16, 256, 0, stream>>>(off, csr_src, csr_ex, xb,
                                                   a_src1, a_dst1, w1catT, w2tb, b1,
                                                   as2, ad2, h2b, a_src2, a_dst2, n);

    // Layer 2
    k8_agg2<<<(n + 3) / 4, 256, 0, stream>>>(off, csr_src, h2b, a_src2, a_dst2, b2, out, n);
}